// Round 1
// baseline (1189.247 us; speedup 1.0000x reference)
//
#include <hip/hip_runtime.h>
#include <math.h>

typedef unsigned short u16;
typedef __attribute__((ext_vector_type(8))) short short8;
typedef __attribute__((ext_vector_type(4))) float floatx4;

#define DEV __device__ __forceinline__

DEV u16 f2bs(float f){ union{float f; unsigned u;} v; v.f=f; unsigned r = v.u + 0x7fffu + ((v.u>>16)&1u); return (u16)(r>>16); }
DEV float bs2f(u16 u){ union{float f; unsigned u;} v; v.u = ((unsigned)u)<<16; return v.f; }

#define GLL16(G,L) __builtin_amdgcn_global_load_lds((__attribute__((address_space(1))) const void*)(G), (__attribute__((address_space(3))) void*)(L), 16, 0, 0)

enum { EP_BF16=0, EP_SCORES=1, EP_PV=2, EP_F32RES=3, EP_GELU=4 };

// C[m][n] = sum_k A[m][k]*B[n][k]  (B^T layout), bf16 in, fp32 acc.
// MODE-specific epilogues; LORA adds t[m][0:16] @ lb[0:16][n].
template<int BM,int BN,int WM,int WN,int MODE,bool LORA>
__global__ __launch_bounds__(256) void gemm_bt(
    const u16* __restrict__ A, int lda,
    const u16* __restrict__ B, int ldb,
    int K,
    u16* __restrict__ obf, float* __restrict__ of32, int ldc,
    const float* __restrict__ bias,
    const float* __restrict__ t, int tld,
    const float* __restrict__ lb, int lbld,
    const float* __restrict__ resid,
    const float* __restrict__ mask)
{
  constexpr int NWM = BM/WM, NWN = BN/WN, NW = NWM*NWN;
  constexpr int FM = WM/16, FN = WN/16;
  static_assert(NW*64 == 256, "block must be 256 threads");
  __shared__ union { u16 ab[(BM+BN)*32]; float tl[(BM+BN)*16]; } sm;

  const int tid = threadIdx.x;
  const int lane = tid & 63, wave = tid >> 6;
  const int wr = wave / NWN, wc = wave % NWN;
  const int row16 = lane & 15, kgrp = lane >> 4;
  const int bm0 = blockIdx.y * BM, bn0 = blockIdx.x * BN;
  const int z = blockIdx.z;

  long aoff = 0, boff = 0, coff = 0;
  if constexpr (MODE==EP_SCORES){
    int zb = z>>4, zh = z&15;
    aoff = (long)zb*512*3072 + (long)zh*64;
    boff = aoff + 1024;                 // K section of qkv
    coff = (long)z*512*512;
  } else if constexpr (MODE==EP_PV){
    aoff = (long)z*512*512;             // P matrix per head
    boff = (long)z*64*512;              // Vt per head
    coff = (long)(z>>4)*512*1024 + (long)(z&15)*64;
  }
  const u16* Ab = A + aoff + (long)bm0*lda;
  const u16* Bb = B + boff + (long)bn0*ldb;

  floatx4 acc[FM][FN];
  #pragma unroll
  for (int i=0;i<FM;i++)
    #pragma unroll
    for (int j=0;j<FN;j++)
      acc[i][j] = (floatx4){0.f,0.f,0.f,0.f};

  char* lds = (char*)&sm.ab[0];
  const int nKT = K >> 5;
  for (int kt=0; kt<nKT; ++kt){
    const u16* Ak = Ab + kt*32;
    const u16* Bk = Bb + kt*32;
    // stage A tile [BM][32] and B tile [BN][32] (linear LDS, 16B/lane)
    #pragma unroll
    for (int c0=0; c0<BM/16; c0+=NW){
      int c = c0 + wave;
      GLL16(Ak + (long)(c*16 + (lane>>2))*lda + (lane&3)*8, lds + c*1024);
    }
    #pragma unroll
    for (int c0=0; c0<BN/16; c0+=NW){
      int c = c0 + wave;
      GLL16(Bk + (long)(c*16 + (lane>>2))*ldb + (lane&3)*8, lds + BM*64 + c*1024);
    }
    __syncthreads();
    short8 af[FM], bfr[FN];
    #pragma unroll
    for (int mi=0;mi<FM;mi++)
      af[mi] = *(const short8*)&sm.ab[(wr*WM + mi*16 + row16)*32 + kgrp*8];
    #pragma unroll
    for (int ni=0;ni<FN;ni++)
      bfr[ni] = *(const short8*)&sm.ab[BM*32 + (wc*WN + ni*16 + row16)*32 + kgrp*8];
    #pragma unroll
    for (int mi=0;mi<FM;mi++)
      #pragma unroll
      for (int ni=0;ni<FN;ni++)
        acc[mi][ni] = __builtin_amdgcn_mfma_f32_16x16x32_bf16(af[mi], bfr[ni], acc[mi][ni], 0, 0, 0);
    __syncthreads();
  }

  int tsel = 0;
  if constexpr (LORA){
    if (tld == 48) tsel = (bn0 >> 10) * 16;   // QKV concat: pick t column block
    const float* trow = t + (long)bm0*tld + tsel;
    for (int i=tid; i<BM*16; i+=256) sm.tl[i] = trow[(long)(i>>4)*tld + (i&15)];
    const float* lbb = lb + bn0;
    for (int i=tid; i<16*BN; i+=256) sm.tl[BM*16 + i] = lbb[(long)(i/BN)*lbld + (i%BN)];
    __syncthreads();
  }

  #pragma unroll
  for (int mi=0;mi<FM;mi++){
    #pragma unroll
    for (int r=0;r<4;r++){
      const int ml = wr*WM + mi*16 + kgrp*4 + r;
      const long mg = bm0 + ml;
      #pragma unroll
      for (int ni=0;ni<FN;ni++){
        const int nl = wc*WN + ni*16 + row16;
        const int ng = bn0 + nl;
        float v = acc[mi][ni][r];
        if constexpr (MODE==EP_SCORES){
          v = v*0.125f + mask[(long)(z>>4)*512 + ng];
          obf[coff + mg*ldc + ng] = f2bs(v);
        } else if constexpr (MODE==EP_PV){
          obf[coff + mg*ldc + ng] = f2bs(v);
        } else {
          v += bias[ng];
          if constexpr (LORA){
            float lv = 0.f;
            #pragma unroll
            for (int j=0;j<16;j++) lv += sm.tl[ml*16 + j] * sm.tl[BM*16 + j*BN + nl];
            v += lv;
          }
          if constexpr (MODE==EP_F32RES){
            v += resid[mg*ldc + ng];
            of32[mg*ldc + ng] = v;
          } else if constexpr (MODE==EP_GELU){
            v = 0.5f*v*(1.f + erff(v*0.70710678118654752f));
            obf[mg*ldc + ng] = f2bs(v);
          } else {
            obf[mg*ldc + ng] = f2bs(v);
          }
        }
      }
    }
  }
}

// ---- conversion / concat: fp32 -> bf16 weights & x, concat qkv w/b/lb ----
__global__ __launch_bounds__(256) void convert_k(
  const float* __restrict__ x,
  const float* __restrict__ wq, const float* __restrict__ wk, const float* __restrict__ wv,
  const float* __restrict__ wo, const float* __restrict__ wup, const float* __restrict__ wdn,
  const float* __restrict__ bq, const float* __restrict__ bk, const float* __restrict__ bv,
  const float* __restrict__ lbq, const float* __restrict__ lbk, const float* __restrict__ lbv,
  u16* __restrict__ xb, u16* __restrict__ wqkv, u16* __restrict__ wob,
  u16* __restrict__ wupb, u16* __restrict__ wdnb,
  float* __restrict__ biascat, float* __restrict__ lbcat)
{
  const long NX = 4194304, NW = 1048576;
  const long total = NX + 3*NW + NW + NX + NX + 3072 + 49152;
  for (long i = (long)blockIdx.x*256 + threadIdx.x; i < total; i += (long)gridDim.x*256){
    long j = i;
    if (j < NX){ xb[j] = f2bs(x[j]); continue; }
    j -= NX;
    if (j < 3*NW){
      int p = (int)(j >> 20);
      const float* w = p==0 ? wq : (p==1 ? wk : wv);
      wqkv[j] = f2bs(w[j & (NW-1)]); continue;
    }
    j -= 3*NW;
    if (j < NW){ wob[j] = f2bs(wo[j]); continue; }
    j -= NW;
    if (j < NX){ wupb[j] = f2bs(wup[j]); continue; }
    j -= NX;
    if (j < NX){ wdnb[j] = f2bs(wdn[j]); continue; }
    j -= NX;
    if (j < 3072){
      int p = (int)(j >> 10);
      const float* bb = p==0 ? bq : (p==1 ? bk : bv);
      biascat[j] = bb[j & 1023]; continue;
    }
    j -= 3072;
    {
      long r = j / 3072, c = j % 3072;
      int p = (int)(c >> 10);
      const float* l = p==0 ? lbq : (p==1 ? lbk : lbv);
      lbcat[j] = l[r*1024 + (c & 1023)];
    }
  }
}

// ---- LoRA stage 1: t[m][r] = sum_k A[m][k] * la[k][r], 4 rows per block ----
template<typename TA>
__global__ __launch_bounds__(256) void lora_t_k(
    const void* __restrict__ Av, int lda,
    const float* __restrict__ la, int K,
    float* __restrict__ t, int tld, int tcol)
{
  const TA* A = (const TA*)Av;
  const int m0 = blockIdx.x * 4;
  const int r = threadIdx.x & 15, ch = threadIdx.x >> 4;   // 16 chunks
  const int kper = K >> 4;
  float p0=0.f, p1=0.f, p2=0.f, p3=0.f;
  const TA* a0 = A + (long)m0*lda;
  for (int kk = ch*kper; kk < (ch+1)*kper; ++kk){
    float w = la[(long)kk*16 + r];
    float v0, v1, v2, v3;
    if constexpr (sizeof(TA)==2){
      v0 = bs2f(((const u16*)a0)[kk]);
      v1 = bs2f(((const u16*)a0)[(long)lda + kk]);
      v2 = bs2f(((const u16*)a0)[2L*lda + kk]);
      v3 = bs2f(((const u16*)a0)[3L*lda + kk]);
    } else {
      v0 = ((const float*)a0)[kk];
      v1 = ((const float*)a0)[(long)lda + kk];
      v2 = ((const float*)a0)[2L*lda + kk];
      v3 = ((const float*)a0)[3L*lda + kk];
    }
    p0 += v0*w; p1 += v1*w; p2 += v2*w; p3 += v3*w;
  }
  __shared__ float part[16][4][16];
  part[ch][0][r]=p0; part[ch][1][r]=p1; part[ch][2][r]=p2; part[ch][3][r]=p3;
  __syncthreads();
  if (threadIdx.x < 64){
    int i = threadIdx.x >> 4, rr = threadIdx.x & 15;
    float s = 0.f;
    #pragma unroll
    for (int c=0;c<16;c++) s += part[c][i][rr];
    t[(long)(m0+i)*tld + tcol + rr] = s;
  }
}

// ---- V transpose: vt[(b*16+h)*64 + d][s] = qkv[(b*512+s)*3072 + 2048 + h*64 + d] ----
__global__ __launch_bounds__(256) void transpose_v(const u16* __restrict__ qkv, u16* __restrict__ vt){
  const int st = blockIdx.x;     // s tile (0..7)
  const int z = blockIdx.y;      // b*16+h
  const int b = z >> 4, h = z & 15;
  __shared__ u16 tile[64][68];
  const int t = threadIdx.x;
  const int q16 = t & 15, g16 = t >> 4;
  const u16* src = qkv + ((long)(b*512 + st*64))*3072 + 2048 + h*64;
  #pragma unroll
  for (int i=0;i<4;i++){
    int s_l = i*16 + g16;
    const u16* pp = src + (long)s_l*3072 + q16*4;
    #pragma unroll
    for (int jj=0;jj<4;jj++) tile[s_l][q16*4+jj] = pp[jj];
  }
  __syncthreads();
  u16* dst = vt + (long)z*64*512 + st*64;
  #pragma unroll
  for (int i=0;i<4;i++){
    int d_l = i*16 + g16;
    int s_l = q16*4;
    unsigned long long v = (unsigned long long)tile[s_l][d_l]
      | ((unsigned long long)tile[s_l+1][d_l] << 16)
      | ((unsigned long long)tile[s_l+2][d_l] << 32)
      | ((unsigned long long)tile[s_l+3][d_l] << 48);
    *(unsigned long long*)(dst + (long)d_l*512 + s_l) = v;
  }
}

// ---- softmax in place over rows of 512 bf16 ----
__global__ __launch_bounds__(256) void softmax_k(u16* __restrict__ sc){
  const long row = blockIdx.x;
  u16* p = sc + row*512;
  const int t = threadIdx.x;
  float a = bs2f(p[t]), b = bs2f(p[t+256]);
  const int lane = t & 63, w = t >> 6;
  __shared__ float red[4];
  float m = fmaxf(a, b);
  #pragma unroll
  for (int o=32;o;o>>=1) m = fmaxf(m, __shfl_down(m, o));
  if (!lane) red[w] = m;
  __syncthreads();
  const float M = fmaxf(fmaxf(red[0],red[1]), fmaxf(red[2],red[3]));
  __syncthreads();
  float ea = expf(a - M), eb = expf(b - M);
  float s = ea + eb;
  #pragma unroll
  for (int o=32;o;o>>=1) s += __shfl_down(s, o);
  if (!lane) red[w] = s;
  __syncthreads();
  const float inv = 1.f / (red[0]+red[1]+red[2]+red[3]);
  p[t] = f2bs(ea*inv); p[t+256] = f2bs(eb*inv);
}

// ---- LayerNorm over rows of 1024 fp32; optional fp32 + bf16 outputs ----
__global__ __launch_bounds__(256) void ln_k(
    const float* __restrict__ in, float* __restrict__ outf, u16* __restrict__ outb,
    const float* __restrict__ gam, const float* __restrict__ bet)
{
  const long row = blockIdx.x;
  const float4 v = ((const float4*)(in + row*1024))[threadIdx.x];
  float s = v.x+v.y+v.z+v.w;
  float q = v.x*v.x + v.y*v.y + v.z*v.z + v.w*v.w;
  const int lane = threadIdx.x & 63, w = threadIdx.x >> 6;
  __shared__ float rs[4], rq[4];
  #pragma unroll
  for (int o=32;o;o>>=1){ s += __shfl_down(s,o); q += __shfl_down(q,o); }
  if (!lane){ rs[w]=s; rq[w]=q; }
  __syncthreads();
  const float S = rs[0]+rs[1]+rs[2]+rs[3];
  const float Q = rq[0]+rq[1]+rq[2]+rq[3];
  const float mu = S*(1.f/1024.f);
  const float var = Q*(1.f/1024.f) - mu*mu;
  const float rstd = rsqrtf(var + 1e-5f);
  const float4 g = ((const float4*)gam)[threadIdx.x];
  const float4 b = ((const float4*)bet)[threadIdx.x];
  float4 o;
  o.x = (v.x-mu)*rstd*g.x + b.x;
  o.y = (v.y-mu)*rstd*g.y + b.y;
  o.z = (v.z-mu)*rstd*g.z + b.z;
  o.w = (v.w-mu)*rstd*g.w + b.w;
  if (outf) ((float4*)(outf + row*1024))[threadIdx.x] = o;
  if (outb){
    uint2 u;
    u.x = (unsigned)f2bs(o.x) | ((unsigned)f2bs(o.y) << 16);
    u.y = (unsigned)f2bs(o.z) | ((unsigned)f2bs(o.w) << 16);
    ((uint2*)(outb + row*1024))[threadIdx.x] = u;
  }
}

extern "C" void kernel_launch(void* const* d_in, const int* in_sizes, int n_in,
                              void* d_out, int out_size, void* d_ws, size_t ws_size,
                              hipStream_t stream) {
  const float* x      = (const float*)d_in[0];
  const float* mask   = (const float*)d_in[1];
  const float* w_q    = (const float*)d_in[2];
  const float* b_q    = (const float*)d_in[3];
  const float* la_q   = (const float*)d_in[4];
  const float* lb_q   = (const float*)d_in[5];
  const float* w_k    = (const float*)d_in[6];
  const float* b_k    = (const float*)d_in[7];
  const float* la_k   = (const float*)d_in[8];
  const float* lb_k   = (const float*)d_in[9];
  const float* w_v    = (const float*)d_in[10];
  const float* b_v    = (const float*)d_in[11];
  const float* la_v   = (const float*)d_in[12];
  const float* lb_v   = (const float*)d_in[13];
  const float* w_o    = (const float*)d_in[14];
  const float* b_o    = (const float*)d_in[15];
  const float* la_o   = (const float*)d_in[16];
  const float* lb_o   = (const float*)d_in[17];
  const float* nw1    = (const float*)d_in[18];
  const float* nb1    = (const float*)d_in[19];
  const float* w_up   = (const float*)d_in[20];
  const float* b_up   = (const float*)d_in[21];
  const float* la_up  = (const float*)d_in[22];
  const float* lb_up  = (const float*)d_in[23];
  const float* w_dn   = (const float*)d_in[24];
  const float* b_dn   = (const float*)d_in[25];
  const float* la_dn  = (const float*)d_in[26];
  const float* lb_dn  = (const float*)d_in[27];
  const float* nw2    = (const float*)d_in[28];
  const float* nb2    = (const float*)d_in[29];
  float* out = (float*)d_out;

  char* ws = (char*)d_ws;
  size_t used = 0;
  auto alloc = [&](size_t bytes) -> char* {
    char* p = ws + used;
    used += (bytes + 255) & ~(size_t)255;
    return p;
  };
  u16*   xb      = (u16*)  alloc(4194304*2);
  u16*   wqkv    = (u16*)  alloc(3145728*2);
  u16*   wob     = (u16*)  alloc(1048576*2);
  u16*   wupb    = (u16*)  alloc(4194304*2);
  u16*   wdnb    = (u16*)  alloc(4194304*2);
  float* biascat = (float*)alloc(3072*4);
  float* lbcat   = (float*)alloc(49152*4);
  float* t_all   = (float*)alloc(4096*48*4);
  u16*   qkv     = (u16*)  alloc((size_t)4096*3072*2);
  u16*   vt      = (u16*)  alloc((size_t)128*64*512*2);
  u16*   scores  = (u16*)  alloc((size_t)128*512*512*2);
  u16*   attn_o  = (u16*)  alloc(4194304*2);
  float* t_o     = (float*)alloc(4096*16*4);
  float* o_final = (float*)alloc((size_t)4194304*4);
  float* x_med   = (float*)alloc((size_t)4194304*4);
  u16*   x_med_b = (u16*)  alloc(4194304*2);
  float* t_up    = (float*)alloc(4096*16*4);
  u16*   fn      = (u16*)  alloc((size_t)4096*4096*2);
  float* t_dn    = (float*)alloc(4096*16*4);
  if (used > ws_size) return;  // workspace too small -> clean validation failure

  // 1. convert + concat
  convert_k<<<4096, 256, 0, stream>>>(x, w_q, w_k, w_v, w_o, w_up, w_dn,
                                      b_q, b_k, b_v, lb_q, lb_k, lb_v,
                                      xb, wqkv, wob, wupb, wdnb, biascat, lbcat);
  // 2. LoRA stage-1 for q,k,v (A = x fp32)
  lora_t_k<float><<<1024, 256, 0, stream>>>(x, 1024, la_q, 1024, t_all, 48, 0);
  lora_t_k<float><<<1024, 256, 0, stream>>>(x, 1024, la_k, 1024, t_all, 48, 16);
  lora_t_k<float><<<1024, 256, 0, stream>>>(x, 1024, la_v, 1024, t_all, 48, 32);
  // 3. fused QKV GEMM -> qkv [4096, 3072] bf16
  gemm_bt<128,128,64,64,EP_BF16,true><<<dim3(24,32,1), 256, 0, stream>>>(
      xb, 1024, wqkv, 1024, 1024, qkv, nullptr, 3072,
      biascat, t_all, 48, lbcat, 3072, nullptr, nullptr);
  // 4. V transpose -> vt [128][64][512]
  transpose_v<<<dim3(8,128), 256, 0, stream>>>(qkv, vt);
  // 5. scores = Q K^T / 8 + mask  (bf16, per head)
  gemm_bt<128,128,64,64,EP_SCORES,false><<<dim3(4,4,128), 256, 0, stream>>>(
      qkv, 3072, qkv, 3072, 64, scores, nullptr, 512,
      nullptr, nullptr, 16, nullptr, 0, nullptr, mask);
  // 6. softmax rows in place
  softmax_k<<<65536, 256, 0, stream>>>(scores);
  // 7. attn_o = P @ V   -> [4096,1024] bf16 (B,S,H*HD layout)
  gemm_bt<128,64,32,64,EP_PV,false><<<dim3(1,4,128), 256, 0, stream>>>(
      scores, 512, vt, 512, 512, attn_o, nullptr, 1024,
      nullptr, nullptr, 16, nullptr, 0, nullptr, nullptr);
  // 8. LoRA stage-1 for O (A = attn_o bf16)
  lora_t_k<u16><<<1024, 256, 0, stream>>>(attn_o, 1024, la_o, 1024, t_o, 16, 0);
  // 9. O projection + bias + lora + residual(x) -> o_final fp32
  gemm_bt<128,128,64,64,EP_F32RES,true><<<dim3(8,32,1), 256, 0, stream>>>(
      attn_o, 1024, wob, 1024, 1024, nullptr, o_final, 1024,
      b_o, t_o, 16, lb_o, 1024, x, nullptr);
  // 10. LN1 -> x_med fp32 + bf16
  ln_k<<<4096, 256, 0, stream>>>(o_final, x_med, x_med_b, nw1, nb1);
  // 11. LoRA stage-1 for up (A = x_med fp32)
  lora_t_k<float><<<1024, 256, 0, stream>>>(x_med, 1024, la_up, 1024, t_up, 16, 0);
  // 12. up GEMM + bias + lora + GELU -> fn bf16 [4096,4096]
  gemm_bt<128,128,64,64,EP_GELU,true><<<dim3(32,32,1), 256, 0, stream>>>(
      x_med_b, 1024, wupb, 1024, 1024, fn, nullptr, 4096,
      b_up, t_up, 16, lb_up, 4096, nullptr, nullptr);
  // 13. LoRA stage-1 for down (A = fn bf16, K=4096)
  lora_t_k<u16><<<1024, 256, 0, stream>>>(fn, 4096, la_dn, 4096, t_dn, 16, 0);
  // 14. down GEMM + bias + lora + residual(x_med) -> d_out fp32
  gemm_bt<128,128,64,64,EP_F32RES,true><<<dim3(8,32,1), 256, 0, stream>>>(
      fn, 4096, wdnb, 4096, 4096, nullptr, out, 1024,
      b_dn, t_dn, 16, lb_dn, 1024, x_med, nullptr);
  // 15. LN2 in place on d_out
  ln_k<<<4096, 256, 0, stream>>>(out, out, nullptr, nw2, nb2);
}

// Round 2
// 567.674 us; speedup vs baseline: 2.0949x; 2.0949x over previous
//
#include <hip/hip_runtime.h>
#include <math.h>

typedef unsigned short u16;
typedef __attribute__((ext_vector_type(8))) short short8;
typedef __attribute__((ext_vector_type(4))) float floatx4;

#define DEV __device__ __forceinline__

DEV u16 f2bs(float f){ union{float f; unsigned u;} v; v.f=f; unsigned r = v.u + 0x7fffu + ((v.u>>16)&1u); return (u16)(r>>16); }
DEV float bs2f(u16 u){ union{float f; unsigned u;} v; v.u = ((unsigned)u)<<16; return v.f; }

#define GLL16(G,L) __builtin_amdgcn_global_load_lds((__attribute__((address_space(1))) const void*)(G), (__attribute__((address_space(3))) void*)(L), 16, 0, 0)

enum { EP_BF16=0, EP_SCORES=1, EP_PV=2, EP_F32RES=3, EP_GELU=4 };

// C[m][n] = sum_k A[m][k]*B[n][k]  (B^T layout), bf16 in, fp32 acc.
// LORA: one extra K=32 MFMA step over (t[M][32] , lbt[N][32]) bf16 tiles
// (cols 16..31 are zero) -> adds t @ lb^T rank-16 term on the matrix pipe.
template<int BM,int BN,int WM,int WN,int MODE,bool LORA>
__global__ __launch_bounds__(256) void gemm_bt(
    const u16* __restrict__ A, int lda,
    const u16* __restrict__ B, int ldb,
    int K,
    u16* __restrict__ obf, float* __restrict__ of32, int ldc,
    const float* __restrict__ bias,
    const u16* __restrict__ tA, int tlda,
    const u16* __restrict__ lbB,
    const float* __restrict__ resid,
    const float* __restrict__ mask)
{
  constexpr int NWM = BM/WM, NWN = BN/WN, NW = NWM*NWN;
  constexpr int FM = WM/16, FN = WN/16;
  static_assert(NW*64 == 256, "block must be 256 threads");
  __shared__ u16 ab[(BM+BN)*32];

  const int tid = threadIdx.x;
  const int lane = tid & 63, wave = tid >> 6;
  const int wr = wave / NWN, wc = wave % NWN;
  const int row16 = lane & 15, kgrp = lane >> 4;
  const int bm0 = blockIdx.y * BM, bn0 = blockIdx.x * BN;
  const int z = blockIdx.z;

  long aoff = 0, boff = 0, coff = 0;
  if constexpr (MODE==EP_SCORES){
    int zb = z>>4, zh = z&15;
    aoff = (long)zb*512*3072 + (long)zh*64;
    boff = aoff + 1024;                 // K section of qkv
    coff = (long)z*512*512;
  } else if constexpr (MODE==EP_PV){
    aoff = (long)z*512*512;             // P matrix per head
    boff = (long)z*64*512;              // Vt per head
    coff = (long)(z>>4)*512*1024 + (long)(z&15)*64;
  }
  const u16* Ab = A + aoff + (long)bm0*lda;
  const u16* Bb = B + boff + (long)bn0*ldb;
  const int tsel = (LORA && tlda==96) ? ((bn0>>10)*32) : 0;

  floatx4 acc[FM][FN];
  #pragma unroll
  for (int i=0;i<FM;i++)
    #pragma unroll
    for (int j=0;j<FN;j++)
      acc[i][j] = (floatx4){0.f,0.f,0.f,0.f};

  char* lds = (char*)&ab[0];
  const int nKT = K >> 5;
  const int nIT = nKT + (LORA ? 1 : 0);
  for (int kt=0; kt<nIT; ++kt){
    const u16 *Ak, *Bk; int la_, lb_;
    if (!LORA || kt < nKT){ Ak = Ab + kt*32; la_ = lda; Bk = Bb + kt*32; lb_ = ldb; }
    else { Ak = tA + (long)bm0*tlda + tsel; la_ = tlda; Bk = lbB + (long)bn0*32; lb_ = 32; }
    // stage A tile [BM][32] and B tile [BN][32] (linear LDS, 16B/lane)
    #pragma unroll
    for (int c0=0; c0<BM/16; c0+=NW){
      int c = c0 + wave;
      GLL16(Ak + (long)(c*16 + (lane>>2))*la_ + (lane&3)*8, lds + c*1024);
    }
    #pragma unroll
    for (int c0=0; c0<BN/16; c0+=NW){
      int c = c0 + wave;
      GLL16(Bk + (long)(c*16 + (lane>>2))*lb_ + (lane&3)*8, lds + BM*64 + c*1024);
    }
    __syncthreads();
    short8 af[FM], bfr[FN];
    #pragma unroll
    for (int mi=0;mi<FM;mi++)
      af[mi] = *(const short8*)&ab[(wr*WM + mi*16 + row16)*32 + kgrp*8];
    #pragma unroll
    for (int ni=0;ni<FN;ni++)
      bfr[ni] = *(const short8*)&ab[BM*32 + (wc*WN + ni*16 + row16)*32 + kgrp*8];
    #pragma unroll
    for (int mi=0;mi<FM;mi++)
      #pragma unroll
      for (int ni=0;ni<FN;ni++)
        acc[mi][ni] = __builtin_amdgcn_mfma_f32_16x16x32_bf16(af[mi], bfr[ni], acc[mi][ni], 0, 0, 0);
    __syncthreads();
  }

  #pragma unroll
  for (int mi=0;mi<FM;mi++){
    #pragma unroll
    for (int r=0;r<4;r++){
      const int ml = wr*WM + mi*16 + kgrp*4 + r;
      const long mg = bm0 + ml;
      #pragma unroll
      for (int ni=0;ni<FN;ni++){
        const int nl = wc*WN + ni*16 + row16;
        const int ng = bn0 + nl;
        float v = acc[mi][ni][r];
        if constexpr (MODE==EP_SCORES){
          v = v*0.125f + mask[(long)(z>>4)*512 + ng];
          obf[coff + mg*ldc + ng] = f2bs(v);
        } else if constexpr (MODE==EP_PV){
          obf[coff + mg*ldc + ng] = f2bs(v);
        } else {
          v += bias[ng];
          if constexpr (MODE==EP_F32RES){
            v += resid[mg*ldc + ng];
            of32[mg*ldc + ng] = v;
          } else if constexpr (MODE==EP_GELU){
            v = 0.5f*v*(1.f + erff(v*0.70710678118654752f));
            obf[mg*ldc + ng] = f2bs(v);
          } else {
            obf[mg*ldc + ng] = f2bs(v);
          }
        }
      }
    }
  }
}

// ---- bulk fp32 -> bf16 conversion (x, wqkv concat, wo, wup, wdn), float4 wide ----
__global__ __launch_bounds__(256) void convert_bulk(
  const float* __restrict__ x,
  const float* __restrict__ wq, const float* __restrict__ wk, const float* __restrict__ wv,
  const float* __restrict__ wo, const float* __restrict__ wup, const float* __restrict__ wdn,
  u16* __restrict__ xb, u16* __restrict__ wqkv, u16* __restrict__ wob,
  u16* __restrict__ wupb, u16* __restrict__ wdnb)
{
  const long NX = 4194304, NWt = 1048576;
  const long T4 = (NX + 3*NWt + NWt + NX + NX) >> 2;
  for (long i4 = (long)blockIdx.x*256 + threadIdx.x; i4 < T4; i4 += (long)gridDim.x*256){
    long j = i4 << 2;
    const float* src; u16* dst; long soff, doff;
    if (j < NX){ src=x; dst=xb; soff=j; doff=j; }
    else { j -= NX;
      if (j < 3*NWt){ int p=(int)(j>>20); src = p==0?wq:(p==1?wk:wv); dst=wqkv; soff = j & (NWt-1); doff = j; }
      else { j -= 3*NWt;
        if (j < NWt){ src=wo; dst=wob; soff=j; doff=j; }
        else { j -= NWt;
          if (j < NX){ src=wup; dst=wupb; soff=j; doff=j; }
          else { j -= NX; src=wdn; dst=wdnb; soff=j; doff=j; }
        }
      }
    }
    const float4 v = *(const float4*)(src + soff);
    ushort4 o;
    o.x = f2bs(v.x); o.y = f2bs(v.y); o.z = f2bs(v.z); o.w = f2bs(v.w);
    *(ushort4*)(dst + doff) = o;
  }
}

// ---- small conversions: bias concat + lb^T bf16 tiles padded to 32 cols ----
__global__ __launch_bounds__(256) void convert_small(
  const float* __restrict__ bq, const float* __restrict__ bk, const float* __restrict__ bv,
  const float* __restrict__ lbq, const float* __restrict__ lbk, const float* __restrict__ lbv,
  const float* __restrict__ lbo, const float* __restrict__ lbup, const float* __restrict__ lbdn,
  float* __restrict__ biascat, u16* __restrict__ lbtqkv, u16* __restrict__ lbto,
  u16* __restrict__ lbtup, u16* __restrict__ lbtdn)
{
  long i = (long)blockIdx.x*256 + threadIdx.x;
  if (i < 3072){ int p=(int)(i>>10); biascat[i] = (p==0?bq:(p==1?bk:bv))[i&1023]; return; }
  i -= 3072;
  if (i < 49152){ int k=(int)(i/3072), n=(int)(i%3072); int p=n>>10;
    const float* l = p==0?lbq:(p==1?lbk:lbv);
    lbtqkv[n*32+k] = f2bs(l[k*1024 + (n&1023)]); lbtqkv[n*32+16+k] = 0; return; }
  i -= 49152;
  if (i < 16384){ int k=(int)(i>>10), n=(int)(i&1023);
    lbto[n*32+k] = f2bs(lbo[k*1024+n]); lbto[n*32+16+k] = 0; return; }
  i -= 16384;
  if (i < 65536){ int k=(int)(i>>12), n=(int)(i&4095);
    lbtup[n*32+k] = f2bs(lbup[k*4096+n]); lbtup[n*32+16+k] = 0; return; }
  i -= 65536;
  if (i < 16384){ int k=(int)(i>>10), n=(int)(i&1023);
    lbtdn[n*32+k] = f2bs(lbdn[k*1024+n]); lbtdn[n*32+16+k] = 0; }
}

// ---- LoRA stage 1: t[m][r] = sum_k A[m][k]*la[k][r] -> bf16, cols 16..31 zeroed ----
template<typename TA>
__global__ __launch_bounds__(256) void lora_t_k(
    const void* __restrict__ Av, int lda,
    const float* __restrict__ la, int K,
    u16* __restrict__ t, int tld, int tcol)
{
  const TA* A = (const TA*)Av;
  const int m0 = blockIdx.x * 4;
  const int r = threadIdx.x & 15, ch = threadIdx.x >> 4;   // 16 chunks
  const int kper = K >> 4;
  float p0=0.f, p1=0.f, p2=0.f, p3=0.f;
  const TA* a0 = A + (long)m0*lda;
  for (int kk = ch*kper; kk < (ch+1)*kper; ++kk){
    float w = la[(long)kk*16 + r];
    float v0, v1, v2, v3;
    if constexpr (sizeof(TA)==2){
      v0 = bs2f(((const u16*)a0)[kk]);
      v1 = bs2f(((const u16*)a0)[(long)lda + kk]);
      v2 = bs2f(((const u16*)a0)[2L*lda + kk]);
      v3 = bs2f(((const u16*)a0)[3L*lda + kk]);
    } else {
      v0 = ((const float*)a0)[kk];
      v1 = ((const float*)a0)[(long)lda + kk];
      v2 = ((const float*)a0)[2L*lda + kk];
      v3 = ((const float*)a0)[3L*lda + kk];
    }
    p0 += v0*w; p1 += v1*w; p2 += v2*w; p3 += v3*w;
  }
  __shared__ float part[16][4][16];
  part[ch][0][r]=p0; part[ch][1][r]=p1; part[ch][2][r]=p2; part[ch][3][r]=p3;
  __syncthreads();
  if (threadIdx.x < 64){
    int i = threadIdx.x >> 4, rr = threadIdx.x & 15;
    float s = 0.f;
    #pragma unroll
    for (int c=0;c<16;c++) s += part[c][i][rr];
    u16* dst = t + (long)(m0+i)*tld + tcol;
    dst[rr] = f2bs(s);
    dst[16+rr] = 0;
  }
}

// ---- V transpose: vt[(b*16+h)*64 + d][s] = qkv[(b*512+s)*3072 + 2048 + h*64 + d] ----
__global__ __launch_bounds__(256) void transpose_v(const u16* __restrict__ qkv, u16* __restrict__ vt){
  const int st = blockIdx.x;     // s tile (0..7)
  const int z = blockIdx.y;      // b*16+h
  const int b = z >> 4, h = z & 15;
  __shared__ u16 tile[64][68];
  const int t = threadIdx.x;
  const int q16 = t & 15, g16 = t >> 4;
  const u16* src = qkv + ((long)(b*512 + st*64))*3072 + 2048 + h*64;
  #pragma unroll
  for (int i=0;i<4;i++){
    int s_l = i*16 + g16;
    const u16* pp = src + (long)s_l*3072 + q16*4;
    #pragma unroll
    for (int jj=0;jj<4;jj++) tile[s_l][q16*4+jj] = pp[jj];
  }
  __syncthreads();
  u16* dst = vt + (long)z*64*512 + st*64;
  #pragma unroll
  for (int i=0;i<4;i++){
    int d_l = i*16 + g16;
    int s_l = q16*4;
    unsigned long long v = (unsigned long long)tile[s_l][d_l]
      | ((unsigned long long)tile[s_l+1][d_l] << 16)
      | ((unsigned long long)tile[s_l+2][d_l] << 32)
      | ((unsigned long long)tile[s_l+3][d_l] << 48);
    *(unsigned long long*)(dst + (long)d_l*512 + s_l) = v;
  }
}

// ---- softmax in place over rows of 512 bf16, packed 2-wide ----
__global__ __launch_bounds__(256) void softmax_k(u16* __restrict__ sc){
  const long row = blockIdx.x;
  unsigned* p = (unsigned*)(sc + row*512);
  const int t = threadIdx.x;
  const unsigned u = p[t];
  float a = bs2f((u16)(u & 0xffff)), b = bs2f((u16)(u >> 16));
  const int lane = t & 63, w = t >> 6;
  __shared__ float red[4];
  float m = fmaxf(a, b);
  #pragma unroll
  for (int o=32;o;o>>=1) m = fmaxf(m, __shfl_down(m, o));
  if (!lane) red[w] = m;
  __syncthreads();
  const float M = fmaxf(fmaxf(red[0],red[1]), fmaxf(red[2],red[3]));
  __syncthreads();
  float ea = expf(a - M), eb = expf(b - M);
  float s = ea + eb;
  #pragma unroll
  for (int o=32;o;o>>=1) s += __shfl_down(s, o);
  if (!lane) red[w] = s;
  __syncthreads();
  const float inv = 1.f / (red[0]+red[1]+red[2]+red[3]);
  p[t] = (unsigned)f2bs(ea*inv) | ((unsigned)f2bs(eb*inv) << 16);
}

// ---- LayerNorm over rows of 1024 fp32; optional fp32 + bf16 outputs ----
__global__ __launch_bounds__(256) void ln_k(
    const float* __restrict__ in, float* __restrict__ outf, u16* __restrict__ outb,
    const float* __restrict__ gam, const float* __restrict__ bet)
{
  const long row = blockIdx.x;
  const float4 v = ((const float4*)(in + row*1024))[threadIdx.x];
  float s = v.x+v.y+v.z+v.w;
  float q = v.x*v.x + v.y*v.y + v.z*v.z + v.w*v.w;
  const int lane = threadIdx.x & 63, w = threadIdx.x >> 6;
  __shared__ float rs[4], rq[4];
  #pragma unroll
  for (int o=32;o;o>>=1){ s += __shfl_down(s,o); q += __shfl_down(q,o); }
  if (!lane){ rs[w]=s; rq[w]=q; }
  __syncthreads();
  const float S = rs[0]+rs[1]+rs[2]+rs[3];
  const float Q = rq[0]+rq[1]+rq[2]+rq[3];
  const float mu = S*(1.f/1024.f);
  const float var = Q*(1.f/1024.f) - mu*mu;
  const float rstd = rsqrtf(var + 1e-5f);
  const float4 g = ((const float4*)gam)[threadIdx.x];
  const float4 b = ((const float4*)bet)[threadIdx.x];
  float4 o;
  o.x = (v.x-mu)*rstd*g.x + b.x;
  o.y = (v.y-mu)*rstd*g.y + b.y;
  o.z = (v.z-mu)*rstd*g.z + b.z;
  o.w = (v.w-mu)*rstd*g.w + b.w;
  if (outf) ((float4*)(outf + row*1024))[threadIdx.x] = o;
  if (outb){
    uint2 u;
    u.x = (unsigned)f2bs(o.x) | ((unsigned)f2bs(o.y) << 16);
    u.y = (unsigned)f2bs(o.z) | ((unsigned)f2bs(o.w) << 16);
    ((uint2*)(outb + row*1024))[threadIdx.x] = u;
  }
}

extern "C" void kernel_launch(void* const* d_in, const int* in_sizes, int n_in,
                              void* d_out, int out_size, void* d_ws, size_t ws_size,
                              hipStream_t stream) {
  const float* x      = (const float*)d_in[0];
  const float* mask   = (const float*)d_in[1];
  const float* w_q    = (const float*)d_in[2];
  const float* b_q    = (const float*)d_in[3];
  const float* la_q   = (const float*)d_in[4];
  const float* lb_q   = (const float*)d_in[5];
  const float* w_k    = (const float*)d_in[6];
  const float* b_k    = (const float*)d_in[7];
  const float* la_k   = (const float*)d_in[8];
  const float* lb_k   = (const float*)d_in[9];
  const float* w_v    = (const float*)d_in[10];
  const float* b_v    = (const float*)d_in[11];
  const float* la_v   = (const float*)d_in[12];
  const float* lb_v   = (const float*)d_in[13];
  const float* w_o    = (const float*)d_in[14];
  const float* b_o    = (const float*)d_in[15];
  const float* la_o   = (const float*)d_in[16];
  const float* lb_o   = (const float*)d_in[17];
  const float* nw1    = (const float*)d_in[18];
  const float* nb1    = (const float*)d_in[19];
  const float* w_up   = (const float*)d_in[20];
  const float* b_up   = (const float*)d_in[21];
  const float* la_up  = (const float*)d_in[22];
  const float* lb_up  = (const float*)d_in[23];
  const float* w_dn   = (const float*)d_in[24];
  const float* b_dn   = (const float*)d_in[25];
  const float* la_dn  = (const float*)d_in[26];
  const float* lb_dn  = (const float*)d_in[27];
  const float* nw2    = (const float*)d_in[28];
  const float* nb2    = (const float*)d_in[29];
  float* out = (float*)d_out;

  char* ws = (char*)d_ws;
  size_t used = 0;
  auto alloc = [&](size_t bytes) -> char* {
    char* p = ws + used;
    used += (bytes + 255) & ~(size_t)255;
    return p;
  };
  u16*   xb      = (u16*)  alloc(4194304*2);
  u16*   wqkv    = (u16*)  alloc(3145728*2);
  u16*   wob     = (u16*)  alloc(1048576*2);
  u16*   wupb    = (u16*)  alloc(4194304*2);
  u16*   wdnb    = (u16*)  alloc(4194304*2);
  float* biascat = (float*)alloc(3072*4);
  u16*   lbtqkv  = (u16*)  alloc(3072*32*2);
  u16*   lbto    = (u16*)  alloc(1024*32*2);
  u16*   lbtup   = (u16*)  alloc(4096*32*2);
  u16*   lbtdn   = (u16*)  alloc(1024*32*2);
  u16*   t_all   = (u16*)  alloc(4096*96*2);
  u16*   t_o     = (u16*)  alloc(4096*32*2);
  u16*   t_up    = (u16*)  alloc(4096*32*2);
  u16*   t_dn    = (u16*)  alloc(4096*32*2);
  u16*   qkv     = (u16*)  alloc((size_t)4096*3072*2);
  u16*   vt      = (u16*)  alloc((size_t)128*64*512*2);
  u16*   scores  = (u16*)  alloc((size_t)128*512*512*2);
  u16*   attn_o  = (u16*)  alloc(4194304*2);
  float* o_final = (float*)alloc((size_t)4194304*4);
  float* x_med   = (float*)alloc((size_t)4194304*4);
  u16*   x_med_b = (u16*)  alloc(4194304*2);
  u16*   fn      = (u16*)  alloc((size_t)4096*4096*2);
  if (used > ws_size) return;  // workspace too small -> clean validation failure

  // 1. convert (bulk vectorized + small concat/transpose)
  convert_bulk<<<2048, 256, 0, stream>>>(x, w_q, w_k, w_v, w_o, w_up, w_dn,
                                         xb, wqkv, wob, wupb, wdnb);
  convert_small<<<588, 256, 0, stream>>>(b_q, b_k, b_v, lb_q, lb_k, lb_v,
                                         lb_o, lb_up, lb_dn,
                                         biascat, lbtqkv, lbto, lbtup, lbtdn);
  // 2. LoRA stage-1 for q,k,v (A = x fp32) -> t_all bf16 [4096][96]
  lora_t_k<float><<<1024, 256, 0, stream>>>(x, 1024, la_q, 1024, t_all, 96, 0);
  lora_t_k<float><<<1024, 256, 0, stream>>>(x, 1024, la_k, 1024, t_all, 96, 32);
  lora_t_k<float><<<1024, 256, 0, stream>>>(x, 1024, la_v, 1024, t_all, 96, 64);
  // 3. fused QKV GEMM -> qkv [4096, 3072] bf16 (LoRA via extra MFMA K-step)
  gemm_bt<128,128,64,64,EP_BF16,true><<<dim3(24,32,1), 256, 0, stream>>>(
      xb, 1024, wqkv, 1024, 1024, qkv, nullptr, 3072,
      biascat, t_all, 96, lbtqkv, nullptr, nullptr);
  // 4. V transpose -> vt [128][64][512]
  transpose_v<<<dim3(8,128), 256, 0, stream>>>(qkv, vt);
  // 5. scores = Q K^T / 8 + mask  (bf16, per head)
  gemm_bt<128,128,64,64,EP_SCORES,false><<<dim3(4,4,128), 256, 0, stream>>>(
      qkv, 3072, qkv, 3072, 64, scores, nullptr, 512,
      nullptr, nullptr, 0, nullptr, nullptr, mask);
  // 6. softmax rows in place
  softmax_k<<<65536, 256, 0, stream>>>(scores);
  // 7. attn_o = P @ V   -> [4096,1024] bf16 (B,S,H*HD layout)
  gemm_bt<128,64,32,64,EP_PV,false><<<dim3(1,4,128), 256, 0, stream>>>(
      scores, 512, vt, 512, 512, attn_o, nullptr, 1024,
      nullptr, nullptr, 0, nullptr, nullptr, nullptr);
  // 8. LoRA stage-1 for O (A = attn_o bf16)
  lora_t_k<u16><<<1024, 256, 0, stream>>>(attn_o, 1024, la_o, 1024, t_o, 32, 0);
  // 9. O projection + bias + lora + residual(x) -> o_final fp32
  gemm_bt<128,128,64,64,EP_F32RES,true><<<dim3(8,32,1), 256, 0, stream>>>(
      attn_o, 1024, wob, 1024, 1024, nullptr, o_final, 1024,
      b_o, t_o, 32, lbto, x, nullptr);
  // 10. LN1 -> x_med fp32 + bf16
  ln_k<<<4096, 256, 0, stream>>>(o_final, x_med, x_med_b, nw1, nb1);
  // 11. LoRA stage-1 for up (A = x_med fp32)
  lora_t_k<float><<<1024, 256, 0, stream>>>(x_med, 1024, la_up, 1024, t_up, 32, 0);
  // 12. up GEMM + bias + lora + GELU -> fn bf16 [4096,4096]
  gemm_bt<128,128,64,64,EP_GELU,true><<<dim3(32,32,1), 256, 0, stream>>>(
      x_med_b, 1024, wupb, 1024, 1024, fn, nullptr, 4096,
      b_up, t_up, 32, lbtup, nullptr, nullptr);
  // 13. LoRA stage-1 for down (A = fn bf16, K=4096)
  lora_t_k<u16><<<1024, 256, 0, stream>>>(fn, 4096, la_dn, 4096, t_dn, 32, 0);
  // 14. down GEMM + bias + lora + residual(x_med) -> d_out fp32
  gemm_bt<128,128,64,64,EP_F32RES,true><<<dim3(8,32,1), 256, 0, stream>>>(
      fn, 4096, wdnb, 4096, 4096, nullptr, out, 1024,
      b_dn, t_dn, 32, lbtdn, x_med, nullptr);
  // 15. LN2 in place on d_out
  ln_k<<<4096, 256, 0, stream>>>(out, out, nullptr, nw2, nb2);
}

// Round 3
// 557.939 us; speedup vs baseline: 2.1315x; 1.0174x over previous
//
#include <hip/hip_runtime.h>
#include <math.h>

typedef unsigned short u16;
typedef __attribute__((ext_vector_type(8))) short short8;
typedef __attribute__((ext_vector_type(4))) float floatx4;

#define DEV __device__ __forceinline__

DEV u16 f2bs(float f){ union{float f; unsigned u;} v; v.f=f; unsigned r = v.u + 0x7fffu + ((v.u>>16)&1u); return (u16)(r>>16); }
DEV float bs2f(u16 u){ union{float f; unsigned u;} v; v.u = ((unsigned)u)<<16; return v.f; }

#define GLL16(G,L) __builtin_amdgcn_global_load_lds((__attribute__((address_space(1))) const void*)(G), (__attribute__((address_space(3))) void*)(L), 16, 0, 0)

enum { EP_BF16=0, EP_SCORES=1, EP_PV=2, EP_F32RES=3, EP_GELU=4 };

// XCD-chunked bijective block swizzle (m204) + group-major (G rows) ordering:
// each XCD gets a contiguous logical chunk; within it, tiles sweep G A-panels
// at a time across all columns -> panel reuse hits the XCD-private L2.
DEV void swizzle_bid(int orig, int gx, int gy, int& bx, int& by){
  const int nwg = gx*gy;
  const int q = nwg >> 3, r = nwg & 7;
  const int xcd = orig & 7, idx = orig >> 3;
  const int logical = (xcd < r) ? xcd*(q+1) + idx : r*(q+1) + (xcd-r)*q + idx;
  const int G = 8;
  const int per = G*gx;
  const int gid = logical / per;
  const int rem = logical - gid*per;
  const int by0 = gid*G;
  const int rows = min(G, gy - by0);
  by = by0 + rem % rows;
  bx = rem / rows;
}

// C[m][n] = sum_k A[m][k]*B[n][k]  (B^T layout), bf16 in, fp32 acc.
// LORA: one extra K=32 MFMA step over (t[M][32] , lbt[N][32]) bf16 tiles
// (cols 16..31 are zero) -> adds t @ lb^T rank-16 term on the matrix pipe.
template<int BM,int BN,int WM,int WN,int MODE,bool LORA,bool SWZ>
__global__ __launch_bounds__(256) void gemm_bt(
    const u16* __restrict__ A, int lda,
    const u16* __restrict__ B, int ldb,
    int K,
    u16* __restrict__ obf, float* __restrict__ of32, int ldc,
    const float* __restrict__ bias,
    const u16* __restrict__ tA, int tlda,
    const u16* __restrict__ lbB,
    const float* __restrict__ resid,
    const float* __restrict__ mask)
{
  constexpr int NWM = BM/WM, NWN = BN/WN, NW = NWM*NWN;
  constexpr int FM = WM/16, FN = WN/16;
  static_assert(NW*64 == 256, "block must be 256 threads");
  __shared__ u16 ab[(BM+BN)*32];

  const int tid = threadIdx.x;
  const int lane = tid & 63, wave = tid >> 6;
  const int wr = wave / NWN, wc = wave % NWN;
  const int row16 = lane & 15, kgrp = lane >> 4;
  int bx = blockIdx.x, by = blockIdx.y;
  if constexpr (SWZ)
    swizzle_bid(blockIdx.y*gridDim.x + blockIdx.x, gridDim.x, gridDim.y, bx, by);
  const int bm0 = by * BM, bn0 = bx * BN;
  const int z = blockIdx.z;

  long aoff = 0, boff = 0, coff = 0;
  if constexpr (MODE==EP_SCORES){
    int zb = z>>4, zh = z&15;
    aoff = (long)zb*512*3072 + (long)zh*64;
    boff = aoff + 1024;                 // K section of qkv
    coff = (long)z*512*512;
  } else if constexpr (MODE==EP_PV){
    aoff = (long)z*512*512;             // P matrix per head
    boff = (long)z*64*512;              // Vt per head
    coff = (long)(z>>4)*512*1024 + (long)(z&15)*64;
  }
  const u16* Ab = A + aoff + (long)bm0*lda;
  const u16* Bb = B + boff + (long)bn0*ldb;
  const int tsel = (LORA && tlda==96) ? ((bn0>>10)*32) : 0;

  floatx4 acc[FM][FN];
  #pragma unroll
  for (int i=0;i<FM;i++)
    #pragma unroll
    for (int j=0;j<FN;j++)
      acc[i][j] = (floatx4){0.f,0.f,0.f,0.f};

  char* lds = (char*)&ab[0];
  const int nKT = K >> 5;
  const int nIT = nKT + (LORA ? 1 : 0);
  for (int kt=0; kt<nIT; ++kt){
    const u16 *Ak, *Bk; int la_, lb_;
    if (!LORA || kt < nKT){ Ak = Ab + kt*32; la_ = lda; Bk = Bb + kt*32; lb_ = ldb; }
    else { Ak = tA + (long)bm0*tlda + tsel; la_ = tlda; Bk = lbB + (long)bn0*32; lb_ = 32; }
    // stage A tile [BM][32] and B tile [BN][32] (linear LDS, 16B/lane)
    #pragma unroll
    for (int c0=0; c0<BM/16; c0+=NW){
      int c = c0 + wave;
      GLL16(Ak + (long)(c*16 + (lane>>2))*la_ + (lane&3)*8, lds + c*1024);
    }
    #pragma unroll
    for (int c0=0; c0<BN/16; c0+=NW){
      int c = c0 + wave;
      GLL16(Bk + (long)(c*16 + (lane>>2))*lb_ + (lane&3)*8, lds + BM*64 + c*1024);
    }
    __syncthreads();
    short8 af[FM], bfr[FN];
    #pragma unroll
    for (int mi=0;mi<FM;mi++)
      af[mi] = *(const short8*)&ab[(wr*WM + mi*16 + row16)*32 + kgrp*8];
    #pragma unroll
    for (int ni=0;ni<FN;ni++)
      bfr[ni] = *(const short8*)&ab[BM*32 + (wc*WN + ni*16 + row16)*32 + kgrp*8];
    #pragma unroll
    for (int mi=0;mi<FM;mi++)
      #pragma unroll
      for (int ni=0;ni<FN;ni++)
        acc[mi][ni] = __builtin_amdgcn_mfma_f32_16x16x32_bf16(af[mi], bfr[ni], acc[mi][ni], 0, 0, 0);
    __syncthreads();
  }

  #pragma unroll
  for (int mi=0;mi<FM;mi++){
    #pragma unroll
    for (int r=0;r<4;r++){
      const int ml = wr*WM + mi*16 + kgrp*4 + r;
      const long mg = bm0 + ml;
      #pragma unroll
      for (int ni=0;ni<FN;ni++){
        const int nl = wc*WN + ni*16 + row16;
        const int ng = bn0 + nl;
        float v = acc[mi][ni][r];
        if constexpr (MODE==EP_SCORES){
          v = v*0.125f + mask[(long)(z>>4)*512 + ng];
          obf[coff + mg*ldc + ng] = f2bs(v);
        } else if constexpr (MODE==EP_PV){
          obf[coff + mg*ldc + ng] = f2bs(v);
        } else {
          v += bias[ng];
          if constexpr (MODE==EP_F32RES){
            v += resid[mg*ldc + ng];
            of32[mg*ldc + ng] = v;
          } else if constexpr (MODE==EP_GELU){
            v = 0.5f*v*(1.f + erff(v*0.70710678118654752f));
            obf[mg*ldc + ng] = f2bs(v);
          } else {
            obf[mg*ldc + ng] = f2bs(v);
          }
        }
      }
    }
  }
}

// ---- bulk fp32 -> bf16 conversion (x, wqkv concat, wo, wup, wdn), float4 wide ----
__global__ __launch_bounds__(256) void convert_bulk(
  const float* __restrict__ x,
  const float* __restrict__ wq, const float* __restrict__ wk, const float* __restrict__ wv,
  const float* __restrict__ wo, const float* __restrict__ wup, const float* __restrict__ wdn,
  u16* __restrict__ xb, u16* __restrict__ wqkv, u16* __restrict__ wob,
  u16* __restrict__ wupb, u16* __restrict__ wdnb)
{
  const long NX = 4194304, NWt = 1048576;
  const long T4 = (NX + 3*NWt + NWt + NX + NX) >> 2;
  for (long i4 = (long)blockIdx.x*256 + threadIdx.x; i4 < T4; i4 += (long)gridDim.x*256){
    long j = i4 << 2;
    const float* src; u16* dst; long soff, doff;
    if (j < NX){ src=x; dst=xb; soff=j; doff=j; }
    else { j -= NX;
      if (j < 3*NWt){ int p=(int)(j>>20); src = p==0?wq:(p==1?wk:wv); dst=wqkv; soff = j & (NWt-1); doff = j; }
      else { j -= 3*NWt;
        if (j < NWt){ src=wo; dst=wob; soff=j; doff=j; }
        else { j -= NWt;
          if (j < NX){ src=wup; dst=wupb; soff=j; doff=j; }
          else { j -= NX; src=wdn; dst=wdnb; soff=j; doff=j; }
        }
      }
    }
    const float4 v = *(const float4*)(src + soff);
    ushort4 o;
    o.x = f2bs(v.x); o.y = f2bs(v.y); o.z = f2bs(v.z); o.w = f2bs(v.w);
    *(ushort4*)(dst + doff) = o;
  }
}

// ---- small conversions: bias concat + lb^T bf16 tiles padded to 32 cols ----
__global__ __launch_bounds__(256) void convert_small(
  const float* __restrict__ bq, const float* __restrict__ bk, const float* __restrict__ bv,
  const float* __restrict__ lbq, const float* __restrict__ lbk, const float* __restrict__ lbv,
  const float* __restrict__ lbo, const float* __restrict__ lbup, const float* __restrict__ lbdn,
  float* __restrict__ biascat, u16* __restrict__ lbtqkv, u16* __restrict__ lbto,
  u16* __restrict__ lbtup, u16* __restrict__ lbtdn)
{
  long i = (long)blockIdx.x*256 + threadIdx.x;
  if (i < 3072){ int p=(int)(i>>10); biascat[i] = (p==0?bq:(p==1?bk:bv))[i&1023]; return; }
  i -= 3072;
  if (i < 49152){ int k=(int)(i/3072), n=(int)(i%3072); int p=n>>10;
    const float* l = p==0?lbq:(p==1?lbk:lbv);
    lbtqkv[n*32+k] = f2bs(l[k*1024 + (n&1023)]); lbtqkv[n*32+16+k] = 0; return; }
  i -= 49152;
  if (i < 16384){ int k=(int)(i>>10), n=(int)(i&1023);
    lbto[n*32+k] = f2bs(lbo[k*1024+n]); lbto[n*32+16+k] = 0; return; }
  i -= 16384;
  if (i < 65536){ int k=(int)(i>>12), n=(int)(i&4095);
    lbtup[n*32+k] = f2bs(lbup[k*4096+n]); lbtup[n*32+16+k] = 0; return; }
  i -= 65536;
  if (i < 16384){ int k=(int)(i>>10), n=(int)(i&1023);
    lbtdn[n*32+k] = f2bs(lbdn[k*1024+n]); lbtdn[n*32+16+k] = 0; }
}

// ---- LoRA stage 1: t[m][r] = sum_k A[m][k]*la[k][r] -> bf16, cols 16..31 zeroed ----
template<typename TA>
__global__ __launch_bounds__(256) void lora_t_k(
    const void* __restrict__ Av, int lda,
    const float* __restrict__ la, int K,
    u16* __restrict__ t, int tld, int tcol)
{
  const TA* A = (const TA*)Av;
  const int m0 = blockIdx.x * 4;
  const int r = threadIdx.x & 15, ch = threadIdx.x >> 4;   // 16 chunks
  const int kper = K >> 4;
  float p0=0.f, p1=0.f, p2=0.f, p3=0.f;
  const TA* a0 = A + (long)m0*lda;
  for (int kk = ch*kper; kk < (ch+1)*kper; ++kk){
    float w = la[(long)kk*16 + r];
    float v0, v1, v2, v3;
    if constexpr (sizeof(TA)==2){
      v0 = bs2f(((const u16*)a0)[kk]);
      v1 = bs2f(((const u16*)a0)[(long)lda + kk]);
      v2 = bs2f(((const u16*)a0)[2L*lda + kk]);
      v3 = bs2f(((const u16*)a0)[3L*lda + kk]);
    } else {
      v0 = ((const float*)a0)[kk];
      v1 = ((const float*)a0)[(long)lda + kk];
      v2 = ((const float*)a0)[2L*lda + kk];
      v3 = ((const float*)a0)[3L*lda + kk];
    }
    p0 += v0*w; p1 += v1*w; p2 += v2*w; p3 += v3*w;
  }
  __shared__ float part[16][4][16];
  part[ch][0][r]=p0; part[ch][1][r]=p1; part[ch][2][r]=p2; part[ch][3][r]=p3;
  __syncthreads();
  if (threadIdx.x < 64){
    int i = threadIdx.x >> 4, rr = threadIdx.x & 15;
    float s = 0.f;
    #pragma unroll
    for (int c=0;c<16;c++) s += part[c][i][rr];
    u16* dst = t + (long)(m0+i)*tld + tcol;
    dst[rr] = f2bs(s);
    dst[16+rr] = 0;
  }
}

// ---- V transpose: vt[(b*16+h)*64 + d][s] = qkv[(b*512+s)*3072 + 2048 + h*64 + d] ----
__global__ __launch_bounds__(256) void transpose_v(const u16* __restrict__ qkv, u16* __restrict__ vt){
  const int st = blockIdx.x;     // s tile (0..7)
  const int z = blockIdx.y;      // b*16+h
  const int b = z >> 4, h = z & 15;
  __shared__ u16 tile[64][68];
  const int t = threadIdx.x;
  const int q16 = t & 15, g16 = t >> 4;
  const u16* src = qkv + ((long)(b*512 + st*64))*3072 + 2048 + h*64;
  #pragma unroll
  for (int i=0;i<4;i++){
    int s_l = i*16 + g16;
    const u16* pp = src + (long)s_l*3072 + q16*4;
    #pragma unroll
    for (int jj=0;jj<4;jj++) tile[s_l][q16*4+jj] = pp[jj];
  }
  __syncthreads();
  u16* dst = vt + (long)z*64*512 + st*64;
  #pragma unroll
  for (int i=0;i<4;i++){
    int d_l = i*16 + g16;
    int s_l = q16*4;
    unsigned long long v = (unsigned long long)tile[s_l][d_l]
      | ((unsigned long long)tile[s_l+1][d_l] << 16)
      | ((unsigned long long)tile[s_l+2][d_l] << 32)
      | ((unsigned long long)tile[s_l+3][d_l] << 48);
    *(unsigned long long*)(dst + (long)d_l*512 + s_l) = v;
  }
}

// ---- softmax in place over rows of 512 bf16, packed 2-wide ----
__global__ __launch_bounds__(256) void softmax_k(u16* __restrict__ sc){
  const long row = blockIdx.x;
  unsigned* p = (unsigned*)(sc + row*512);
  const int t = threadIdx.x;
  const unsigned u = p[t];
  float a = bs2f((u16)(u & 0xffff)), b = bs2f((u16)(u >> 16));
  const int lane = t & 63, w = t >> 6;
  __shared__ float red[4];
  float m = fmaxf(a, b);
  #pragma unroll
  for (int o=32;o;o>>=1) m = fmaxf(m, __shfl_down(m, o));
  if (!lane) red[w] = m;
  __syncthreads();
  const float M = fmaxf(fmaxf(red[0],red[1]), fmaxf(red[2],red[3]));
  __syncthreads();
  float ea = expf(a - M), eb = expf(b - M);
  float s = ea + eb;
  #pragma unroll
  for (int o=32;o;o>>=1) s += __shfl_down(s, o);
  if (!lane) red[w] = s;
  __syncthreads();
  const float inv = 1.f / (red[0]+red[1]+red[2]+red[3]);
  p[t] = (unsigned)f2bs(ea*inv) | ((unsigned)f2bs(eb*inv) << 16);
}

// ---- LayerNorm over rows of 1024 fp32; optional fp32 + bf16 outputs ----
__global__ __launch_bounds__(256) void ln_k(
    const float* __restrict__ in, float* __restrict__ outf, u16* __restrict__ outb,
    const float* __restrict__ gam, const float* __restrict__ bet)
{
  const long row = blockIdx.x;
  const float4 v = ((const float4*)(in + row*1024))[threadIdx.x];
  float s = v.x+v.y+v.z+v.w;
  float q = v.x*v.x + v.y*v.y + v.z*v.z + v.w*v.w;
  const int lane = threadIdx.x & 63, w = threadIdx.x >> 6;
  __shared__ float rs[4], rq[4];
  #pragma unroll
  for (int o=32;o;o>>=1){ s += __shfl_down(s,o); q += __shfl_down(q,o); }
  if (!lane){ rs[w]=s; rq[w]=q; }
  __syncthreads();
  const float S = rs[0]+rs[1]+rs[2]+rs[3];
  const float Q = rq[0]+rq[1]+rq[2]+rq[3];
  const float mu = S*(1.f/1024.f);
  const float var = Q*(1.f/1024.f) - mu*mu;
  const float rstd = rsqrtf(var + 1e-5f);
  const float4 g = ((const float4*)gam)[threadIdx.x];
  const float4 b = ((const float4*)bet)[threadIdx.x];
  float4 o;
  o.x = (v.x-mu)*rstd*g.x + b.x;
  o.y = (v.y-mu)*rstd*g.y + b.y;
  o.z = (v.z-mu)*rstd*g.z + b.z;
  o.w = (v.w-mu)*rstd*g.w + b.w;
  if (outf) ((float4*)(outf + row*1024))[threadIdx.x] = o;
  if (outb){
    uint2 u;
    u.x = (unsigned)f2bs(o.x) | ((unsigned)f2bs(o.y) << 16);
    u.y = (unsigned)f2bs(o.z) | ((unsigned)f2bs(o.w) << 16);
    ((uint2*)(outb + row*1024))[threadIdx.x] = u;
  }
}

extern "C" void kernel_launch(void* const* d_in, const int* in_sizes, int n_in,
                              void* d_out, int out_size, void* d_ws, size_t ws_size,
                              hipStream_t stream) {
  const float* x      = (const float*)d_in[0];
  const float* mask   = (const float*)d_in[1];
  const float* w_q    = (const float*)d_in[2];
  const float* b_q    = (const float*)d_in[3];
  const float* la_q   = (const float*)d_in[4];
  const float* lb_q   = (const float*)d_in[5];
  const float* w_k    = (const float*)d_in[6];
  const float* b_k    = (const float*)d_in[7];
  const float* la_k   = (const float*)d_in[8];
  const float* lb_k   = (const float*)d_in[9];
  const float* w_v    = (const float*)d_in[10];
  const float* b_v    = (const float*)d_in[11];
  const float* la_v   = (const float*)d_in[12];
  const float* lb_v   = (const float*)d_in[13];
  const float* w_o    = (const float*)d_in[14];
  const float* b_o    = (const float*)d_in[15];
  const float* la_o   = (const float*)d_in[16];
  const float* lb_o   = (const float*)d_in[17];
  const float* nw1    = (const float*)d_in[18];
  const float* nb1    = (const float*)d_in[19];
  const float* w_up   = (const float*)d_in[20];
  const float* b_up   = (const float*)d_in[21];
  const float* la_up  = (const float*)d_in[22];
  const float* lb_up  = (const float*)d_in[23];
  const float* w_dn   = (const float*)d_in[24];
  const float* b_dn   = (const float*)d_in[25];
  const float* la_dn  = (const float*)d_in[26];
  const float* lb_dn  = (const float*)d_in[27];
  const float* nw2    = (const float*)d_in[28];
  const float* nb2    = (const float*)d_in[29];
  float* out = (float*)d_out;

  char* ws = (char*)d_ws;
  size_t used = 0;
  auto alloc = [&](size_t bytes) -> char* {
    char* p = ws + used;
    used += (bytes + 255) & ~(size_t)255;
    return p;
  };
  u16*   xb      = (u16*)  alloc(4194304*2);
  u16*   wqkv    = (u16*)  alloc(3145728*2);
  u16*   wob     = (u16*)  alloc(1048576*2);
  u16*   wupb    = (u16*)  alloc(4194304*2);
  u16*   wdnb    = (u16*)  alloc(4194304*2);
  float* biascat = (float*)alloc(3072*4);
  u16*   lbtqkv  = (u16*)  alloc(3072*32*2);
  u16*   lbto    = (u16*)  alloc(1024*32*2);
  u16*   lbtup   = (u16*)  alloc(4096*32*2);
  u16*   lbtdn   = (u16*)  alloc(1024*32*2);
  u16*   t_all   = (u16*)  alloc(4096*96*2);
  u16*   t_o     = (u16*)  alloc(4096*32*2);
  u16*   t_up    = (u16*)  alloc(4096*32*2);
  u16*   t_dn    = (u16*)  alloc(4096*32*2);
  u16*   qkv     = (u16*)  alloc((size_t)4096*3072*2);
  u16*   vt      = (u16*)  alloc((size_t)128*64*512*2);
  u16*   scores  = (u16*)  alloc((size_t)128*512*512*2);
  u16*   attn_o  = (u16*)  alloc(4194304*2);
  float* o_final = (float*)alloc((size_t)4194304*4);
  float* x_med   = (float*)alloc((size_t)4194304*4);
  u16*   x_med_b = (u16*)  alloc(4194304*2);
  u16*   fn      = (u16*)  alloc((size_t)4096*4096*2);
  if (used > ws_size) return;  // workspace too small -> clean validation failure

  // 1. convert (bulk vectorized + small concat/transpose)
  convert_bulk<<<2048, 256, 0, stream>>>(x, w_q, w_k, w_v, w_o, w_up, w_dn,
                                         xb, wqkv, wob, wupb, wdnb);
  convert_small<<<588, 256, 0, stream>>>(b_q, b_k, b_v, lb_q, lb_k, lb_v,
                                         lb_o, lb_up, lb_dn,
                                         biascat, lbtqkv, lbto, lbtup, lbtdn);
  // 2. LoRA stage-1 for q,k,v (A = x fp32) -> t_all bf16 [4096][96]
  lora_t_k<float><<<1024, 256, 0, stream>>>(x, 1024, la_q, 1024, t_all, 96, 0);
  lora_t_k<float><<<1024, 256, 0, stream>>>(x, 1024, la_k, 1024, t_all, 96, 32);
  lora_t_k<float><<<1024, 256, 0, stream>>>(x, 1024, la_v, 1024, t_all, 96, 64);
  // 3. fused QKV GEMM -> qkv [4096, 3072] bf16 (LoRA via extra MFMA K-step)
  gemm_bt<128,128,64,64,EP_BF16,true,true><<<dim3(24,32,1), 256, 0, stream>>>(
      xb, 1024, wqkv, 1024, 1024, qkv, nullptr, 3072,
      biascat, t_all, 96, lbtqkv, nullptr, nullptr);
  // 4. V transpose -> vt [128][64][512]
  transpose_v<<<dim3(8,128), 256, 0, stream>>>(qkv, vt);
  // 5. scores = Q K^T / 8 + mask  (bf16, per head)
  gemm_bt<128,128,64,64,EP_SCORES,false,false><<<dim3(4,4,128), 256, 0, stream>>>(
      qkv, 3072, qkv, 3072, 64, scores, nullptr, 512,
      nullptr, nullptr, 0, nullptr, nullptr, mask);
  // 6. softmax rows in place
  softmax_k<<<65536, 256, 0, stream>>>(scores);
  // 7. attn_o = P @ V   -> [4096,1024] bf16 (B,S,H*HD layout)
  gemm_bt<128,64,32,64,EP_PV,false,false><<<dim3(1,4,128), 256, 0, stream>>>(
      scores, 512, vt, 512, 512, attn_o, nullptr, 1024,
      nullptr, nullptr, 0, nullptr, nullptr, nullptr);
  // 8. LoRA stage-1 for O (A = attn_o bf16)
  lora_t_k<u16><<<1024, 256, 0, stream>>>(attn_o, 1024, la_o, 1024, t_o, 32, 0);
  // 9. O projection + bias + lora + residual(x) -> o_final fp32
  gemm_bt<128,128,64,64,EP_F32RES,true,true><<<dim3(8,32,1), 256, 0, stream>>>(
      attn_o, 1024, wob, 1024, 1024, nullptr, o_final, 1024,
      b_o, t_o, 32, lbto, x, nullptr);
  // 10. LN1 -> x_med fp32 + bf16
  ln_k<<<4096, 256, 0, stream>>>(o_final, x_med, x_med_b, nw1, nb1);
  // 11. LoRA stage-1 for up (A = x_med fp32)
  lora_t_k<float><<<1024, 256, 0, stream>>>(x_med, 1024, la_up, 1024, t_up, 32, 0);
  // 12. up GEMM + bias + lora + GELU -> fn bf16 [4096,4096]
  gemm_bt<128,128,64,64,EP_GELU,true,true><<<dim3(32,32,1), 256, 0, stream>>>(
      x_med_b, 1024, wupb, 1024, 1024, fn, nullptr, 4096,
      b_up, t_up, 32, lbtup, nullptr, nullptr);
  // 13. LoRA stage-1 for down (A = fn bf16, K=4096)
  lora_t_k<u16><<<1024, 256, 0, stream>>>(fn, 4096, la_dn, 4096, t_dn, 32, 0);
  // 14. down GEMM + bias + lora + residual(x_med) -> d_out fp32
  gemm_bt<128,128,64,64,EP_F32RES,true,true><<<dim3(8,32,1), 256, 0, stream>>>(
      fn, 4096, wdnb, 4096, 4096, nullptr, out, 1024,
      b_dn, t_dn, 32, lbtdn, x_med, nullptr);
  // 15. LN2 in place on d_out
  ln_k<<<4096, 256, 0, stream>>>(out, out, nullptr, nw2, nb2);
}

// Round 4
// 444.982 us; speedup vs baseline: 2.6726x; 1.2538x over previous
//
#include <hip/hip_runtime.h>
#include <math.h>

typedef unsigned short u16;
typedef __attribute__((ext_vector_type(8))) short short8;
typedef __attribute__((ext_vector_type(4))) float floatx4;

#define DEV __device__ __forceinline__

DEV u16 f2bs(float f){ union{float f; unsigned u;} v; v.f=f; unsigned r = v.u + 0x7fffu + ((v.u>>16)&1u); return (u16)(r>>16); }
DEV float bs2f(u16 u){ union{float f; unsigned u;} v; v.u = ((unsigned)u)<<16; return v.f; }

#define GLL16(G,L) __builtin_amdgcn_global_load_lds((__attribute__((address_space(1))) const void*)(G), (__attribute__((address_space(3))) void*)(L), 16, 0, 0)

enum { EP_BF16=0, EP_F32RES=3, EP_GELU=4 };

// XCD-chunked bijective block swizzle (m204) + group-major (G rows) ordering.
DEV void swizzle_bid(int orig, int gx, int gy, int& bx, int& by){
  const int nwg = gx*gy;
  const int q = nwg >> 3, r = nwg & 7;
  const int xcd = orig & 7, idx = orig >> 3;
  const int logical = (xcd < r) ? xcd*(q+1) + idx : r*(q+1) + (xcd-r)*q + idx;
  const int G = 8;
  const int per = G*gx;
  const int gid = logical / per;
  const int rem = logical - gid*per;
  const int by0 = gid*G;
  const int rows = min(G, gy - by0);
  by = by0 + rem % rows;
  bx = rem / rows;
}

// C[m][n] = sum_k A[m][k]*B[n][k]  (B^T layout), bf16 in, fp32 acc.
// LDS tiles [rows][32] with 16B-chunk XOR swizzle: LDS stays linear for
// global_load_lds; the global SOURCE chunk is pre-swizzled and the frag READ
// applies the same involution (rule 21).
template<int BM,int BN,int WM,int WN,int MODE,bool LORA,bool SWZ>
__global__ __launch_bounds__(256) void gemm_bt(
    const u16* __restrict__ A, int lda,
    const u16* __restrict__ B, int ldb,
    int K,
    u16* __restrict__ obf, float* __restrict__ of32, int ldc,
    const float* __restrict__ bias,
    const u16* __restrict__ tA, int tlda,
    const u16* __restrict__ lbB,
    const float* __restrict__ resid)
{
  constexpr int NWM = BM/WM, NWN = BN/WN, NW = NWM*NWN;
  constexpr int FM = WM/16, FN = WN/16;
  static_assert(NW*64 == 256, "block must be 256 threads");
  __shared__ u16 ab[(BM+BN)*32];

  const int tid = threadIdx.x;
  const int lane = tid & 63, wave = tid >> 6;
  const int wr = wave / NWN, wc = wave % NWN;
  const int row16 = lane & 15, kgrp = lane >> 4;
  int bx = blockIdx.x, by = blockIdx.y;
  if constexpr (SWZ)
    swizzle_bid(blockIdx.y*gridDim.x + blockIdx.x, gridDim.x, gridDim.y, bx, by);
  const int bm0 = by * BM, bn0 = bx * BN;

  const u16* Ab = A + (long)bm0*lda;
  const u16* Bb = B + (long)bn0*ldb;
  const int tsel = (LORA && tlda==96) ? ((bn0>>10)*32) : 0;
  // pre-swizzled source chunk: chunk' = (lane&3) ^ ((lane>>2)&3)
  const int gcol = (((lane&3) ^ ((lane>>2)&3)))*8;
  const int grow = lane>>2;

  floatx4 acc[FM][FN];
  #pragma unroll
  for (int i=0;i<FM;i++)
    #pragma unroll
    for (int j=0;j<FN;j++)
      acc[i][j] = (floatx4){0.f,0.f,0.f,0.f};

  char* lds = (char*)&ab[0];
  const int nKT = K >> 5;
  const int nIT = nKT + (LORA ? 1 : 0);
  for (int kt=0; kt<nIT; ++kt){
    const u16 *Ak, *Bk; int la_, lb_;
    if (!LORA || kt < nKT){ Ak = Ab + kt*32; la_ = lda; Bk = Bb + kt*32; lb_ = ldb; }
    else { Ak = tA + (long)bm0*tlda + tsel; la_ = tlda; Bk = lbB + (long)bn0*32; lb_ = 32; }
    #pragma unroll
    for (int c0=0; c0<BM/16; c0+=NW){
      int c = c0 + wave;
      GLL16(Ak + (long)(c*16 + grow)*la_ + gcol, lds + c*1024);
    }
    #pragma unroll
    for (int c0=0; c0<BN/16; c0+=NW){
      int c = c0 + wave;
      GLL16(Bk + (long)(c*16 + grow)*lb_ + gcol, lds + BM*64 + c*1024);
    }
    __syncthreads();
    short8 af[FM], bfr[FN];
    #pragma unroll
    for (int mi=0;mi<FM;mi++){
      int r_ = wr*WM + mi*16 + row16;
      af[mi] = *(const short8*)(lds + r_*64 + ((kgrp ^ (r_&3))<<4));
    }
    #pragma unroll
    for (int ni=0;ni<FN;ni++){
      int r_ = wc*WN + ni*16 + row16;
      bfr[ni] = *(const short8*)(lds + BM*64 + r_*64 + ((kgrp ^ (r_&3))<<4));
    }
    #pragma unroll
    for (int mi=0;mi<FM;mi++)
      #pragma unroll
      for (int ni=0;ni<FN;ni++)
        acc[mi][ni] = __builtin_amdgcn_mfma_f32_16x16x32_bf16(af[mi], bfr[ni], acc[mi][ni], 0, 0, 0);
    __syncthreads();
  }

  #pragma unroll
  for (int mi=0;mi<FM;mi++){
    #pragma unroll
    for (int r=0;r<4;r++){
      const int ml = wr*WM + mi*16 + kgrp*4 + r;
      const long mg = bm0 + ml;
      #pragma unroll
      for (int ni=0;ni<FN;ni++){
        const int nl = wc*WN + ni*16 + row16;
        const int ng = bn0 + nl;
        float v = acc[mi][ni][r] + bias[ng];
        if constexpr (MODE==EP_F32RES){
          v += resid[mg*ldc + ng];
          of32[mg*ldc + ng] = v;
        } else if constexpr (MODE==EP_GELU){
          v = 0.5f*v*(1.f + erff(v*0.70710678118654752f));
          obf[mg*ldc + ng] = f2bs(v);
        } else {
          obf[mg*ldc + ng] = f2bs(v);
        }
      }
    }
  }
}

// ---- fused flash attention: per (q-tile 128, head) block, 4 waves ----
// S = Q K^T /8 + mask, online softmax, O = P V. LDS tiles [rows][64] with
// 16B-chunk XOR swizzle (chunk ^ row&7) -> 2-way max on frag reads.
__global__ __launch_bounds__(256) void flash_attn(
    const u16* __restrict__ qkv,   // [4096][3072]
    const u16* __restrict__ vt,    // [128][64][512]
    const float* __restrict__ mask,// [8][512]
    u16* __restrict__ attn_o)      // [4096][1024]
{
  __shared__ u16 sm[25600]; // Q[128][64] | K[64][64] | V[64][64] | P 4x[32][72]
  u16* Qs = sm;
  u16* Ks = sm + 8192;
  u16* Vs = sm + 12288;
  u16* Ps = sm + 16384;

  const int tid = threadIdx.x, lane = tid & 63, wave = tid >> 6;
  const int c = lane & 15, kg = lane >> 4;
  const int qt = blockIdx.x;        // 0..3
  const int z  = blockIdx.y;        // b*16+h
  const int b = z >> 4, h = z & 15;
  const int q0 = qt * 128;
  // staging lane offsets (8 rows x 128B per wave-issue, source chunk pre-swizzled)
  const int srow = lane >> 3;
  const int scol = ((lane&7) ^ srow) * 8;

  {
    const u16* src = qkv + ((long)(b*512 + q0))*3072 + h*64;
    #pragma unroll
    for (int i=0;i<4;i++){
      int rb = i*32 + wave*8;
      GLL16(src + (long)(rb + srow)*3072 + scol, (char*)Qs + rb*128);
    }
  }
  __syncthreads();

  auto ld_swz = [&](const u16* t, int row, int koff8) -> short8 {
    return *(const short8*)((const char*)t + row*128 + ((koff8 ^ (row&7))<<4));
  };

  short8 af[2][2];
  #pragma unroll
  for (int mi=0;mi<2;mi++)
    #pragma unroll
    for (int ks=0;ks<2;ks++)
      af[mi][ks] = ld_swz(Qs, wave*32 + mi*16 + c, ks*4 + kg);

  floatx4 o_acc[2][4];
  float m_run[2][4], l_run[2][4];
  #pragma unroll
  for (int mi=0;mi<2;mi++){
    #pragma unroll
    for (int dj=0;dj<4;dj++) o_acc[mi][dj] = (floatx4){0.f,0.f,0.f,0.f};
    #pragma unroll
    for (int r=0;r<4;r++){ m_run[mi][r] = -3.0e38f; l_run[mi][r] = 0.f; }
  }

  const u16* kbase = qkv + ((long)(b*512))*3072 + 1024 + h*64;
  const u16* vbase = vt + (long)z*64*512;

  for (int kv=0; kv<8; ++kv){
    __syncthreads();   // prev-iter K/V reads done before overwrite
    #pragma unroll
    for (int i=0;i<2;i++){
      int rb = i*32 + wave*8;
      GLL16(kbase + (long)(kv*64 + rb + srow)*3072 + scol, (char*)Ks + rb*128);
      GLL16(vbase + (long)(rb + srow)*512 + kv*64 + scol, (char*)Vs + rb*128);
    }
    __syncthreads();

    floatx4 s_acc[2][4];
    #pragma unroll
    for (int mi=0;mi<2;mi++)
      #pragma unroll
      for (int ni=0;ni<4;ni++)
        s_acc[mi][ni] = (floatx4){0.f,0.f,0.f,0.f};
    #pragma unroll
    for (int ks=0;ks<2;ks++){
      short8 bf[4];
      #pragma unroll
      for (int ni=0;ni<4;ni++)
        bf[ni] = ld_swz(Ks, ni*16 + c, ks*4 + kg);
      #pragma unroll
      for (int mi=0;mi<2;mi++)
        #pragma unroll
        for (int ni=0;ni<4;ni++)
          s_acc[mi][ni] = __builtin_amdgcn_mfma_f32_16x16x32_bf16(af[mi][ks], bf[ni], s_acc[mi][ni], 0, 0, 0);
    }

    float mv[4];
    #pragma unroll
    for (int ni=0;ni<4;ni++) mv[ni] = mask[b*512 + kv*64 + ni*16 + c];

    #pragma unroll
    for (int mi=0;mi<2;mi++){
      #pragma unroll
      for (int r=0;r<4;r++){
        float s0 = s_acc[mi][0][r]*0.125f + mv[0];
        float s1 = s_acc[mi][1][r]*0.125f + mv[1];
        float s2 = s_acc[mi][2][r]*0.125f + mv[2];
        float s3 = s_acc[mi][3][r]*0.125f + mv[3];
        float tmax = fmaxf(fmaxf(s0,s1), fmaxf(s2,s3));
        #pragma unroll
        for (int o=1;o<16;o<<=1) tmax = fmaxf(tmax, __shfl_xor(tmax, o));
        const float mnew = fmaxf(m_run[mi][r], tmax);
        const float p0 = __expf(s0 - mnew), p1 = __expf(s1 - mnew);
        const float p2 = __expf(s2 - mnew), p3 = __expf(s3 - mnew);
        float psum = p0+p1+p2+p3;
        #pragma unroll
        for (int o=1;o<16;o<<=1) psum += __shfl_xor(psum, o);
        const float alpha = __expf(m_run[mi][r] - mnew);
        l_run[mi][r] = l_run[mi][r]*alpha + psum;
        m_run[mi][r] = mnew;
        #pragma unroll
        for (int dj=0;dj<4;dj++) o_acc[mi][dj][r] *= alpha;
        const int rl = mi*16 + kg*4 + r;
        u16* pw = Ps + wave*2304 + rl*72;
        pw[c]      = f2bs(p0);
        pw[16 + c] = f2bs(p1);
        pw[32 + c] = f2bs(p2);
        pw[48 + c] = f2bs(p3);
      }
    }
    __syncthreads();  // P visible (also orders intra-wave ds_write->ds_read)

    #pragma unroll
    for (int ks=0;ks<2;ks++){
      short8 pa[2], vb[4];
      #pragma unroll
      for (int mi=0;mi<2;mi++)
        pa[mi] = *(const short8*)&Ps[wave*2304 + (mi*16 + c)*72 + ks*32 + kg*8];
      #pragma unroll
      for (int dj=0;dj<4;dj++)
        vb[dj] = ld_swz(Vs, dj*16 + c, ks*4 + kg);
      #pragma unroll
      for (int mi=0;mi<2;mi++)
        #pragma unroll
        for (int dj=0;dj<4;dj++)
          o_acc[mi][dj] = __builtin_amdgcn_mfma_f32_16x16x32_bf16(pa[mi], vb[dj], o_acc[mi][dj], 0, 0, 0);
    }
  }

  #pragma unroll
  for (int mi=0;mi<2;mi++){
    #pragma unroll
    for (int r=0;r<4;r++){
      const float inv = 1.f / l_run[mi][r];
      const int s_g = q0 + wave*32 + mi*16 + kg*4 + r;
      u16* dst = attn_o + (long)(b*512 + s_g)*1024 + h*64;
      #pragma unroll
      for (int dj=0;dj<4;dj++)
        dst[dj*16 + c] = f2bs(o_acc[mi][dj][r]*inv);
    }
  }
}

// ---- bulk fp32 -> bf16 conversion (x, wqkv concat, wo, wup, wdn), float4 wide ----
__global__ __launch_bounds__(256) void convert_bulk(
  const float* __restrict__ x,
  const float* __restrict__ wq, const float* __restrict__ wk, const float* __restrict__ wv,
  const float* __restrict__ wo, const float* __restrict__ wup, const float* __restrict__ wdn,
  u16* __restrict__ xb, u16* __restrict__ wqkv, u16* __restrict__ wob,
  u16* __restrict__ wupb, u16* __restrict__ wdnb)
{
  const long NX = 4194304, NWt = 1048576;
  const long T4 = (NX + 3*NWt + NWt + NX + NX) >> 2;
  for (long i4 = (long)blockIdx.x*256 + threadIdx.x; i4 < T4; i4 += (long)gridDim.x*256){
    long j = i4 << 2;
    const float* src; u16* dst; long soff, doff;
    if (j < NX){ src=x; dst=xb; soff=j; doff=j; }
    else { j -= NX;
      if (j < 3*NWt){ int p=(int)(j>>20); src = p==0?wq:(p==1?wk:wv); dst=wqkv; soff = j & (NWt-1); doff = j; }
      else { j -= 3*NWt;
        if (j < NWt){ src=wo; dst=wob; soff=j; doff=j; }
        else { j -= NWt;
          if (j < NX){ src=wup; dst=wupb; soff=j; doff=j; }
          else { j -= NX; src=wdn; dst=wdnb; soff=j; doff=j; }
        }
      }
    }
    const float4 v = *(const float4*)(src + soff);
    ushort4 o;
    o.x = f2bs(v.x); o.y = f2bs(v.y); o.z = f2bs(v.z); o.w = f2bs(v.w);
    *(ushort4*)(dst + doff) = o;
  }
}

// ---- small conversions: bias concat + lb^T bf16 tiles padded to 32 cols ----
__global__ __launch_bounds__(256) void convert_small(
  const float* __restrict__ bq, const float* __restrict__ bk, const float* __restrict__ bv,
  const float* __restrict__ lbq, const float* __restrict__ lbk, const float* __restrict__ lbv,
  const float* __restrict__ lbo, const float* __restrict__ lbup, const float* __restrict__ lbdn,
  float* __restrict__ biascat, u16* __restrict__ lbtqkv, u16* __restrict__ lbto,
  u16* __restrict__ lbtup, u16* __restrict__ lbtdn)
{
  long i = (long)blockIdx.x*256 + threadIdx.x;
  if (i < 3072){ int p=(int)(i>>10); biascat[i] = (p==0?bq:(p==1?bk:bv))[i&1023]; return; }
  i -= 3072;
  if (i < 49152){ int k=(int)(i/3072), n=(int)(i%3072); int p=n>>10;
    const float* l = p==0?lbq:(p==1?lbk:lbv);
    lbtqkv[n*32+k] = f2bs(l[k*1024 + (n&1023)]); lbtqkv[n*32+16+k] = 0; return; }
  i -= 49152;
  if (i < 16384){ int k=(int)(i>>10), n=(int)(i&1023);
    lbto[n*32+k] = f2bs(lbo[k*1024+n]); lbto[n*32+16+k] = 0; return; }
  i -= 16384;
  if (i < 65536){ int k=(int)(i>>12), n=(int)(i&4095);
    lbtup[n*32+k] = f2bs(lbup[k*4096+n]); lbtup[n*32+16+k] = 0; return; }
  i -= 65536;
  if (i < 16384){ int k=(int)(i>>10), n=(int)(i&1023);
    lbtdn[n*32+k] = f2bs(lbdn[k*1024+n]); lbtdn[n*32+16+k] = 0; }
}

// ---- LoRA stage 1: t[m][r] = sum_k A[m][k]*la[k][r] -> bf16, cols 16..31 zeroed ----
template<typename TA>
__global__ __launch_bounds__(256) void lora_t_k(
    const void* __restrict__ Av, int lda,
    const float* __restrict__ la, int K,
    u16* __restrict__ t, int tld, int tcol)
{
  const TA* A = (const TA*)Av;
  const int m0 = blockIdx.x * 4;
  const int r = threadIdx.x & 15, ch = threadIdx.x >> 4;   // 16 chunks
  const int kper = K >> 4;
  float p0=0.f, p1=0.f, p2=0.f, p3=0.f;
  const TA* a0 = A + (long)m0*lda;
  for (int kk = ch*kper; kk < (ch+1)*kper; ++kk){
    float w = la[(long)kk*16 + r];
    float v0, v1, v2, v3;
    if constexpr (sizeof(TA)==2){
      v0 = bs2f(((const u16*)a0)[kk]);
      v1 = bs2f(((const u16*)a0)[(long)lda + kk]);
      v2 = bs2f(((const u16*)a0)[2L*lda + kk]);
      v3 = bs2f(((const u16*)a0)[3L*lda + kk]);
    } else {
      v0 = ((const float*)a0)[kk];
      v1 = ((const float*)a0)[(long)lda + kk];
      v2 = ((const float*)a0)[2L*lda + kk];
      v3 = ((const float*)a0)[3L*lda + kk];
    }
    p0 += v0*w; p1 += v1*w; p2 += v2*w; p3 += v3*w;
  }
  __shared__ float part[16][4][16];
  part[ch][0][r]=p0; part[ch][1][r]=p1; part[ch][2][r]=p2; part[ch][3][r]=p3;
  __syncthreads();
  if (threadIdx.x < 64){
    int i = threadIdx.x >> 4, rr = threadIdx.x & 15;
    float s = 0.f;
    #pragma unroll
    for (int c=0;c<16;c++) s += part[c][i][rr];
    u16* dst = t + (long)(m0+i)*tld + tcol;
    dst[rr] = f2bs(s);
    dst[16+rr] = 0;
  }
}

// ---- V transpose: vt[(b*16+h)*64 + d][s] = qkv[(b*512+s)*3072 + 2048 + h*64 + d] ----
__global__ __launch_bounds__(256) void transpose_v(const u16* __restrict__ qkv, u16* __restrict__ vt){
  const int st = blockIdx.x;     // s tile (0..7)
  const int z = blockIdx.y;      // b*16+h
  const int b = z >> 4, h = z & 15;
  __shared__ u16 tile[64][68];
  const int t = threadIdx.x;
  const int q16 = t & 15, g16 = t >> 4;
  const u16* src = qkv + ((long)(b*512 + st*64))*3072 + 2048 + h*64;
  #pragma unroll
  for (int i=0;i<4;i++){
    int s_l = i*16 + g16;
    const u16* pp = src + (long)s_l*3072 + q16*4;
    #pragma unroll
    for (int jj=0;jj<4;jj++) tile[s_l][q16*4+jj] = pp[jj];
  }
  __syncthreads();
  u16* dst = vt + (long)z*64*512 + st*64;
  #pragma unroll
  for (int i=0;i<4;i++){
    int d_l = i*16 + g16;
    int s_l = q16*4;
    unsigned long long v = (unsigned long long)tile[s_l][d_l]
      | ((unsigned long long)tile[s_l+1][d_l] << 16)
      | ((unsigned long long)tile[s_l+2][d_l] << 32)
      | ((unsigned long long)tile[s_l+3][d_l] << 48);
    *(unsigned long long*)(dst + (long)d_l*512 + s_l) = v;
  }
}

// ---- LayerNorm over rows of 1024 fp32; optional fp32 + bf16 outputs ----
__global__ __launch_bounds__(256) void ln_k(
    const float* __restrict__ in, float* __restrict__ outf, u16* __restrict__ outb,
    const float* __restrict__ gam, const float* __restrict__ bet)
{
  const long row = blockIdx.x;
  const float4 v = ((const float4*)(in + row*1024))[threadIdx.x];
  float s = v.x+v.y+v.z+v.w;
  float q = v.x*v.x + v.y*v.y + v.z*v.z + v.w*v.w;
  const int lane = threadIdx.x & 63, w = threadIdx.x >> 6;
  __shared__ float rs[4], rq[4];
  #pragma unroll
  for (int o=32;o;o>>=1){ s += __shfl_down(s,o); q += __shfl_down(q,o); }
  if (!lane){ rs[w]=s; rq[w]=q; }
  __syncthreads();
  const float S = rs[0]+rs[1]+rs[2]+rs[3];
  const float Q = rq[0]+rq[1]+rq[2]+rq[3];
  const float mu = S*(1.f/1024.f);
  const float var = Q*(1.f/1024.f) - mu*mu;
  const float rstd = rsqrtf(var + 1e-5f);
  const float4 g = ((const float4*)gam)[threadIdx.x];
  const float4 b = ((const float4*)bet)[threadIdx.x];
  float4 o;
  o.x = (v.x-mu)*rstd*g.x + b.x;
  o.y = (v.y-mu)*rstd*g.y + b.y;
  o.z = (v.z-mu)*rstd*g.z + b.z;
  o.w = (v.w-mu)*rstd*g.w + b.w;
  if (outf) ((float4*)(outf + row*1024))[threadIdx.x] = o;
  if (outb){
    uint2 u;
    u.x = (unsigned)f2bs(o.x) | ((unsigned)f2bs(o.y) << 16);
    u.y = (unsigned)f2bs(o.z) | ((unsigned)f2bs(o.w) << 16);
    ((uint2*)(outb + row*1024))[threadIdx.x] = u;
  }
}

extern "C" void kernel_launch(void* const* d_in, const int* in_sizes, int n_in,
                              void* d_out, int out_size, void* d_ws, size_t ws_size,
                              hipStream_t stream) {
  const float* x      = (const float*)d_in[0];
  const float* mask   = (const float*)d_in[1];
  const float* w_q    = (const float*)d_in[2];
  const float* b_q    = (const float*)d_in[3];
  const float* la_q   = (const float*)d_in[4];
  const float* lb_q   = (const float*)d_in[5];
  const float* w_k    = (const float*)d_in[6];
  const float* b_k    = (const float*)d_in[7];
  const float* la_k   = (const float*)d_in[8];
  const float* lb_k   = (const float*)d_in[9];
  const float* w_v    = (const float*)d_in[10];
  const float* b_v    = (const float*)d_in[11];
  const float* la_v   = (const float*)d_in[12];
  const float* lb_v   = (const float*)d_in[13];
  const float* w_o    = (const float*)d_in[14];
  const float* b_o    = (const float*)d_in[15];
  const float* la_o   = (const float*)d_in[16];
  const float* lb_o   = (const float*)d_in[17];
  const float* nw1    = (const float*)d_in[18];
  const float* nb1    = (const float*)d_in[19];
  const float* w_up   = (const float*)d_in[20];
  const float* b_up   = (const float*)d_in[21];
  const float* la_up  = (const float*)d_in[22];
  const float* lb_up  = (const float*)d_in[23];
  const float* w_dn   = (const float*)d_in[24];
  const float* b_dn   = (const float*)d_in[25];
  const float* la_dn  = (const float*)d_in[26];
  const float* lb_dn  = (const float*)d_in[27];
  const float* nw2    = (const float*)d_in[28];
  const float* nb2    = (const float*)d_in[29];
  float* out = (float*)d_out;

  char* ws = (char*)d_ws;
  size_t used = 0;
  auto alloc = [&](size_t bytes) -> char* {
    char* p = ws + used;
    used += (bytes + 255) & ~(size_t)255;
    return p;
  };
  u16*   xb      = (u16*)  alloc(4194304*2);
  u16*   wqkv    = (u16*)  alloc(3145728*2);
  u16*   wob     = (u16*)  alloc(1048576*2);
  u16*   wupb    = (u16*)  alloc(4194304*2);
  u16*   wdnb    = (u16*)  alloc(4194304*2);
  float* biascat = (float*)alloc(3072*4);
  u16*   lbtqkv  = (u16*)  alloc(3072*32*2);
  u16*   lbto    = (u16*)  alloc(1024*32*2);
  u16*   lbtup   = (u16*)  alloc(4096*32*2);
  u16*   lbtdn   = (u16*)  alloc(1024*32*2);
  u16*   t_all   = (u16*)  alloc(4096*96*2);
  u16*   t_o     = (u16*)  alloc(4096*32*2);
  u16*   t_up    = (u16*)  alloc(4096*32*2);
  u16*   t_dn    = (u16*)  alloc(4096*32*2);
  u16*   qkv     = (u16*)  alloc((size_t)4096*3072*2);
  u16*   vt      = (u16*)  alloc((size_t)128*64*512*2);
  u16*   attn_o  = (u16*)  alloc(4194304*2);
  float* o_final = (float*)alloc((size_t)4194304*4);
  float* x_med   = (float*)alloc((size_t)4194304*4);
  u16*   x_med_b = (u16*)  alloc(4194304*2);
  u16*   fn      = (u16*)  alloc((size_t)4096*4096*2);
  if (used > ws_size) return;  // workspace too small -> clean validation failure

  // 1. convert
  convert_bulk<<<2048, 256, 0, stream>>>(x, w_q, w_k, w_v, w_o, w_up, w_dn,
                                         xb, wqkv, wob, wupb, wdnb);
  convert_small<<<588, 256, 0, stream>>>(b_q, b_k, b_v, lb_q, lb_k, lb_v,
                                         lb_o, lb_up, lb_dn,
                                         biascat, lbtqkv, lbto, lbtup, lbtdn);
  // 2. LoRA stage-1 for q,k,v
  lora_t_k<float><<<1024, 256, 0, stream>>>(x, 1024, la_q, 1024, t_all, 96, 0);
  lora_t_k<float><<<1024, 256, 0, stream>>>(x, 1024, la_k, 1024, t_all, 96, 32);
  lora_t_k<float><<<1024, 256, 0, stream>>>(x, 1024, la_v, 1024, t_all, 96, 64);
  // 3. fused QKV GEMM -> qkv [4096, 3072] bf16
  gemm_bt<128,128,64,64,EP_BF16,true,true><<<dim3(24,32,1), 256, 0, stream>>>(
      xb, 1024, wqkv, 1024, 1024, qkv, nullptr, 3072,
      biascat, t_all, 96, lbtqkv, nullptr);
  // 4. V transpose -> vt [128][64][512]
  transpose_v<<<dim3(8,128), 256, 0, stream>>>(qkv, vt);
  // 5. fused flash attention -> attn_o bf16 [4096][1024]
  flash_attn<<<dim3(4,128), 256, 0, stream>>>(qkv, vt, mask, attn_o);
  // 6. LoRA stage-1 for O
  lora_t_k<u16><<<1024, 256, 0, stream>>>(attn_o, 1024, la_o, 1024, t_o, 32, 0);
  // 7. O projection + bias + lora + residual(x) -> o_final fp32
  gemm_bt<64,128,32,64,EP_F32RES,true,true><<<dim3(8,64,1), 256, 0, stream>>>(
      attn_o, 1024, wob, 1024, 1024, nullptr, o_final, 1024,
      b_o, t_o, 32, lbto, x);
  // 8. LN1 -> x_med fp32 + bf16
  ln_k<<<4096, 256, 0, stream>>>(o_final, x_med, x_med_b, nw1, nb1);
  // 9. LoRA stage-1 for up
  lora_t_k<float><<<1024, 256, 0, stream>>>(x_med, 1024, la_up, 1024, t_up, 32, 0);
  // 10. up GEMM + bias + lora + GELU -> fn bf16 [4096,4096]
  gemm_bt<128,128,64,64,EP_GELU,true,true><<<dim3(32,32,1), 256, 0, stream>>>(
      x_med_b, 1024, wupb, 1024, 1024, fn, nullptr, 4096,
      b_up, t_up, 32, lbtup, nullptr);
  // 11. LoRA stage-1 for down (K=4096)
  lora_t_k<u16><<<1024, 256, 0, stream>>>(fn, 4096, la_dn, 4096, t_dn, 32, 0);
  // 12. down GEMM + bias + lora + residual(x_med) -> d_out fp32
  gemm_bt<64,128,32,64,EP_F32RES,true,true><<<dim3(8,64,1), 256, 0, stream>>>(
      fn, 4096, wdnb, 4096, 4096, nullptr, out, 1024,
      b_dn, t_dn, 32, lbtdn, x_med);
  // 13. LN2 in place on d_out
  ln_k<<<4096, 256, 0, stream>>>(out, out, nullptr, nw2, nb2);
}

// Round 5
// 335.857 us; speedup vs baseline: 3.5409x; 1.3249x over previous
//
#include <hip/hip_runtime.h>
#include <math.h>

typedef unsigned short u16;
typedef __attribute__((ext_vector_type(8))) short short8;
typedef __attribute__((ext_vector_type(4))) float floatx4;

#define DEV __device__ __forceinline__

DEV u16 f2bs(float f){ union{float f; unsigned u;} v; v.f=f; unsigned r = v.u + 0x7fffu + ((v.u>>16)&1u); return (u16)(r>>16); }
DEV float bs2f(u16 u){ union{float f; unsigned u;} v; v.u = ((unsigned)u)<<16; return v.f; }

#define GLL16(G,L) __builtin_amdgcn_global_load_lds((__attribute__((address_space(1))) const void*)(G), (__attribute__((address_space(3))) void*)(L), 16, 0, 0)

enum { EP_BF16=0, EP_F32RES=3, EP_GELU=4 };

// XCD-chunked bijective block swizzle (m204) + group-major (G rows) ordering.
DEV void swizzle_bid(int orig, int gx, int gy, int& bx, int& by){
  const int nwg = gx*gy;
  const int q = nwg >> 3, r = nwg & 7;
  const int xcd = orig & 7, idx = orig >> 3;
  const int logical = (xcd < r) ? xcd*(q+1) + idx : r*(q+1) + (xcd-r)*q + idx;
  const int G = 8;
  const int per = G*gx;
  const int gid = logical / per;
  const int rem = logical - gid*per;
  const int by0 = gid*G;
  const int rows = min(G, gy - by0);
  by = by0 + rem % rows;
  bx = rem / rows;
}

// C[m][n] = sum_k A[m][k]*B[n][k]  (B^T layout), bf16 in, fp32 acc.
template<int BM,int BN,int WM,int WN,int MODE,bool LORA,bool SWZ>
__global__ __launch_bounds__(256) void gemm_bt(
    const u16* __restrict__ A, int lda,
    const u16* __restrict__ B, int ldb,
    int K,
    u16* __restrict__ obf, float* __restrict__ of32, int ldc,
    const float* __restrict__ bias,
    const u16* __restrict__ tA, int tlda,
    const u16* __restrict__ lbB,
    const float* __restrict__ resid)
{
  constexpr int NWM = BM/WM, NWN = BN/WN, NW = NWM*NWN;
  constexpr int FM = WM/16, FN = WN/16;
  static_assert(NW*64 == 256, "block must be 256 threads");
  __shared__ u16 ab[(BM+BN)*32];

  const int tid = threadIdx.x;
  const int lane = tid & 63, wave = tid >> 6;
  const int wr = wave / NWN, wc = wave % NWN;
  const int row16 = lane & 15, kgrp = lane >> 4;
  int bx = blockIdx.x, by = blockIdx.y;
  if constexpr (SWZ)
    swizzle_bid(blockIdx.y*gridDim.x + blockIdx.x, gridDim.x, gridDim.y, bx, by);
  const int bm0 = by * BM, bn0 = bx * BN;

  const u16* Ab = A + (long)bm0*lda;
  const u16* Bb = B + (long)bn0*ldb;
  const int tsel = (LORA && tlda==96) ? ((bn0>>10)*32) : 0;
  // pre-swizzled source chunk: chunk' = (lane&3) ^ ((lane>>2)&3)
  const int gcol = (((lane&3) ^ ((lane>>2)&3)))*8;
  const int grow = lane>>2;

  floatx4 acc[FM][FN];
  #pragma unroll
  for (int i=0;i<FM;i++)
    #pragma unroll
    for (int j=0;j<FN;j++)
      acc[i][j] = (floatx4){0.f,0.f,0.f,0.f};

  char* lds = (char*)&ab[0];
  const int nKT = K >> 5;
  const int nIT = nKT + (LORA ? 1 : 0);
  for (int kt=0; kt<nIT; ++kt){
    const u16 *Ak, *Bk; int la_, lb_;
    if (!LORA || kt < nKT){ Ak = Ab + kt*32; la_ = lda; Bk = Bb + kt*32; lb_ = ldb; }
    else { Ak = tA + (long)bm0*tlda + tsel; la_ = tlda; Bk = lbB + (long)bn0*32; lb_ = 32; }
    #pragma unroll
    for (int c0=0; c0<BM/16; c0+=NW){
      int c = c0 + wave;
      GLL16(Ak + (long)(c*16 + grow)*la_ + gcol, lds + c*1024);
    }
    #pragma unroll
    for (int c0=0; c0<BN/16; c0+=NW){
      int c = c0 + wave;
      GLL16(Bk + (long)(c*16 + grow)*lb_ + gcol, lds + BM*64 + c*1024);
    }
    __syncthreads();
    short8 af[FM], bfr[FN];
    #pragma unroll
    for (int mi=0;mi<FM;mi++){
      int r_ = wr*WM + mi*16 + row16;
      af[mi] = *(const short8*)(lds + r_*64 + ((kgrp ^ (r_&3))<<4));
    }
    #pragma unroll
    for (int ni=0;ni<FN;ni++){
      int r_ = wc*WN + ni*16 + row16;
      bfr[ni] = *(const short8*)(lds + BM*64 + r_*64 + ((kgrp ^ (r_&3))<<4));
    }
    #pragma unroll
    for (int mi=0;mi<FM;mi++)
      #pragma unroll
      for (int ni=0;ni<FN;ni++)
        acc[mi][ni] = __builtin_amdgcn_mfma_f32_16x16x32_bf16(af[mi], bfr[ni], acc[mi][ni], 0, 0, 0);
    __syncthreads();
  }

  #pragma unroll
  for (int mi=0;mi<FM;mi++){
    #pragma unroll
    for (int r=0;r<4;r++){
      const int ml = wr*WM + mi*16 + kgrp*4 + r;
      const long mg = bm0 + ml;
      #pragma unroll
      for (int ni=0;ni<FN;ni++){
        const int nl = wc*WN + ni*16 + row16;
        const int ng = bn0 + nl;
        float v = acc[mi][ni][r] + bias[ng];
        if constexpr (MODE==EP_F32RES){
          v += resid[mg*ldc + ng];
          of32[mg*ldc + ng] = v;
        } else if constexpr (MODE==EP_GELU){
          v = 0.5f*v*(1.f + erff(v*0.70710678118654752f));
          obf[mg*ldc + ng] = f2bs(v);
        } else {
          obf[mg*ldc + ng] = f2bs(v);
        }
      }
    }
  }
}

// ---- LoRA stage-1 via MFMA: t[m][r] = sum_k A[m][k]*la[k][r] ----
// One wave per 16 rows; NT targets share the A-fragment (q/k/v fusion).
// lat = la^T bf16 [NT*16][K]; out cols tj*32 + (0..15), 16..31 zeroed.
template<int NT>
__global__ __launch_bounds__(64) void lora_mfma(
    const u16* __restrict__ A, const int K,
    const u16* __restrict__ lat,
    u16* __restrict__ t, int tld)
{
  const int lane = threadIdx.x & 63;
  const int c = lane & 15, kg = lane >> 4;
  const int m0 = blockIdx.x * 16;
  const u16* Arow = A + (long)(m0 + c)*K + kg*8;
  const u16* Brow = lat + (long)c*K + kg*8;
  floatx4 acc[NT];
  #pragma unroll
  for (int tj=0;tj<NT;tj++) acc[tj] = (floatx4){0.f,0.f,0.f,0.f};
  const int nKS = K >> 5;
  #pragma unroll 4
  for (int ks=0; ks<nKS; ++ks){
    short8 a = *(const short8*)(Arow + ks*32);
    #pragma unroll
    for (int tj=0; tj<NT; ++tj){
      short8 b = *(const short8*)(Brow + (long)tj*16*K + ks*32);
      acc[tj] = __builtin_amdgcn_mfma_f32_16x16x32_bf16(a, b, acc[tj], 0, 0, 0);
    }
  }
  #pragma unroll
  for (int tj=0; tj<NT; ++tj)
    #pragma unroll
    for (int r=0;r<4;r++){
      u16* dst = t + (long)(m0 + kg*4 + r)*tld + tj*32;
      dst[c] = f2bs(acc[tj][r]);
      dst[16+c] = 0;
    }
}

// ---- fused flash attention: per (q-tile 128, head) block, 4 waves ----
__global__ __launch_bounds__(256) void flash_attn(
    const u16* __restrict__ qkv,   // [4096][3072]
    const u16* __restrict__ vt,    // [128][64][512]
    const float* __restrict__ mask,// [8][512]
    u16* __restrict__ attn_o)      // [4096][1024]
{
  __shared__ u16 sm[25600]; // Q[128][64] | K[64][64] | V[64][64] | P 4x[32][72]
  u16* Qs = sm;
  u16* Ks = sm + 8192;
  u16* Vs = sm + 12288;
  u16* Ps = sm + 16384;

  const int tid = threadIdx.x, lane = tid & 63, wave = tid >> 6;
  const int c = lane & 15, kg = lane >> 4;
  const int qt = blockIdx.x;        // 0..3
  const int z  = blockIdx.y;        // b*16+h
  const int b = z >> 4, h = z & 15;
  const int q0 = qt * 128;
  const int srow = lane >> 3;
  const int scol = ((lane&7) ^ srow) * 8;

  {
    const u16* src = qkv + ((long)(b*512 + q0))*3072 + h*64;
    #pragma unroll
    for (int i=0;i<4;i++){
      int rb = i*32 + wave*8;
      GLL16(src + (long)(rb + srow)*3072 + scol, (char*)Qs + rb*128);
    }
  }
  __syncthreads();

  auto ld_swz = [&](const u16* t, int row, int koff8) -> short8 {
    return *(const short8*)((const char*)t + row*128 + ((koff8 ^ (row&7))<<4));
  };

  short8 af[2][2];
  #pragma unroll
  for (int mi=0;mi<2;mi++)
    #pragma unroll
    for (int ks=0;ks<2;ks++)
      af[mi][ks] = ld_swz(Qs, wave*32 + mi*16 + c, ks*4 + kg);

  floatx4 o_acc[2][4];
  float m_run[2][4], l_run[2][4];
  #pragma unroll
  for (int mi=0;mi<2;mi++){
    #pragma unroll
    for (int dj=0;dj<4;dj++) o_acc[mi][dj] = (floatx4){0.f,0.f,0.f,0.f};
    #pragma unroll
    for (int r=0;r<4;r++){ m_run[mi][r] = -3.0e38f; l_run[mi][r] = 0.f; }
  }

  const u16* kbase = qkv + ((long)(b*512))*3072 + 1024 + h*64;
  const u16* vbase = vt + (long)z*64*512;

  for (int kv=0; kv<8; ++kv){
    __syncthreads();
    #pragma unroll
    for (int i=0;i<2;i++){
      int rb = i*32 + wave*8;
      GLL16(kbase + (long)(kv*64 + rb + srow)*3072 + scol, (char*)Ks + rb*128);
      GLL16(vbase + (long)(rb + srow)*512 + kv*64 + scol, (char*)Vs + rb*128);
    }
    __syncthreads();

    floatx4 s_acc[2][4];
    #pragma unroll
    for (int mi=0;mi<2;mi++)
      #pragma unroll
      for (int ni=0;ni<4;ni++)
        s_acc[mi][ni] = (floatx4){0.f,0.f,0.f,0.f};
    #pragma unroll
    for (int ks=0;ks<2;ks++){
      short8 bf[4];
      #pragma unroll
      for (int ni=0;ni<4;ni++)
        bf[ni] = ld_swz(Ks, ni*16 + c, ks*4 + kg);
      #pragma unroll
      for (int mi=0;mi<2;mi++)
        #pragma unroll
        for (int ni=0;ni<4;ni++)
          s_acc[mi][ni] = __builtin_amdgcn_mfma_f32_16x16x32_bf16(af[mi][ks], bf[ni], s_acc[mi][ni], 0, 0, 0);
    }

    float mv[4];
    #pragma unroll
    for (int ni=0;ni<4;ni++) mv[ni] = mask[b*512 + kv*64 + ni*16 + c];

    #pragma unroll
    for (int mi=0;mi<2;mi++){
      #pragma unroll
      for (int r=0;r<4;r++){
        float s0 = s_acc[mi][0][r]*0.125f + mv[0];
        float s1 = s_acc[mi][1][r]*0.125f + mv[1];
        float s2 = s_acc[mi][2][r]*0.125f + mv[2];
        float s3 = s_acc[mi][3][r]*0.125f + mv[3];
        float tmax = fmaxf(fmaxf(s0,s1), fmaxf(s2,s3));
        #pragma unroll
        for (int o=1;o<16;o<<=1) tmax = fmaxf(tmax, __shfl_xor(tmax, o));
        const float mnew = fmaxf(m_run[mi][r], tmax);
        const float p0 = __expf(s0 - mnew), p1 = __expf(s1 - mnew);
        const float p2 = __expf(s2 - mnew), p3 = __expf(s3 - mnew);
        float psum = p0+p1+p2+p3;
        #pragma unroll
        for (int o=1;o<16;o<<=1) psum += __shfl_xor(psum, o);
        const float alpha = __expf(m_run[mi][r] - mnew);
        l_run[mi][r] = l_run[mi][r]*alpha + psum;
        m_run[mi][r] = mnew;
        #pragma unroll
        for (int dj=0;dj<4;dj++) o_acc[mi][dj][r] *= alpha;
        const int rl = mi*16 + kg*4 + r;
        u16* pw = Ps + wave*2304 + rl*72;
        pw[c]      = f2bs(p0);
        pw[16 + c] = f2bs(p1);
        pw[32 + c] = f2bs(p2);
        pw[48 + c] = f2bs(p3);
      }
    }
    __syncthreads();

    #pragma unroll
    for (int ks=0;ks<2;ks++){
      short8 pa[2], vb[4];
      #pragma unroll
      for (int mi=0;mi<2;mi++)
        pa[mi] = *(const short8*)&Ps[wave*2304 + (mi*16 + c)*72 + ks*32 + kg*8];
      #pragma unroll
      for (int dj=0;dj<4;dj++)
        vb[dj] = ld_swz(Vs, dj*16 + c, ks*4 + kg);
      #pragma unroll
      for (int mi=0;mi<2;mi++)
        #pragma unroll
        for (int dj=0;dj<4;dj++)
          o_acc[mi][dj] = __builtin_amdgcn_mfma_f32_16x16x32_bf16(pa[mi], vb[dj], o_acc[mi][dj], 0, 0, 0);
    }
  }

  #pragma unroll
  for (int mi=0;mi<2;mi++){
    #pragma unroll
    for (int r=0;r<4;r++){
      const float inv = 1.f / l_run[mi][r];
      const int s_g = q0 + wave*32 + mi*16 + kg*4 + r;
      u16* dst = attn_o + (long)(b*512 + s_g)*1024 + h*64;
      #pragma unroll
      for (int dj=0;dj<4;dj++)
        dst[dj*16 + c] = f2bs(o_acc[mi][dj][r]*inv);
    }
  }
}

// ---- bulk fp32 -> bf16 conversion, float4 wide ----
__global__ __launch_bounds__(256) void convert_bulk(
  const float* __restrict__ x,
  const float* __restrict__ wq, const float* __restrict__ wk, const float* __restrict__ wv,
  const float* __restrict__ wo, const float* __restrict__ wup, const float* __restrict__ wdn,
  u16* __restrict__ xb, u16* __restrict__ wqkv, u16* __restrict__ wob,
  u16* __restrict__ wupb, u16* __restrict__ wdnb)
{
  const long NX = 4194304, NWt = 1048576;
  const long T4 = (NX + 3*NWt + NWt + NX + NX) >> 2;
  for (long i4 = (long)blockIdx.x*256 + threadIdx.x; i4 < T4; i4 += (long)gridDim.x*256){
    long j = i4 << 2;
    const float* src; u16* dst; long soff, doff;
    if (j < NX){ src=x; dst=xb; soff=j; doff=j; }
    else { j -= NX;
      if (j < 3*NWt){ int p=(int)(j>>20); src = p==0?wq:(p==1?wk:wv); dst=wqkv; soff = j & (NWt-1); doff = j; }
      else { j -= 3*NWt;
        if (j < NWt){ src=wo; dst=wob; soff=j; doff=j; }
        else { j -= NWt;
          if (j < NX){ src=wup; dst=wupb; soff=j; doff=j; }
          else { j -= NX; src=wdn; dst=wdnb; soff=j; doff=j; }
        }
      }
    }
    const float4 v = *(const float4*)(src + soff);
    ushort4 o;
    o.x = f2bs(v.x); o.y = f2bs(v.y); o.z = f2bs(v.z); o.w = f2bs(v.w);
    *(ushort4*)(dst + doff) = o;
  }
}

// ---- small conversions: bias concat, lb^T tiles, la^T tiles ----
__global__ __launch_bounds__(256) void convert_small(
  const float* __restrict__ bq, const float* __restrict__ bk, const float* __restrict__ bv,
  const float* __restrict__ lbq, const float* __restrict__ lbk, const float* __restrict__ lbv,
  const float* __restrict__ lbo, const float* __restrict__ lbup, const float* __restrict__ lbdn,
  const float* __restrict__ laq, const float* __restrict__ lak, const float* __restrict__ lav,
  const float* __restrict__ lao, const float* __restrict__ laup, const float* __restrict__ ladn,
  float* __restrict__ biascat, u16* __restrict__ lbtqkv, u16* __restrict__ lbto,
  u16* __restrict__ lbtup, u16* __restrict__ lbtdn,
  u16* __restrict__ latqkv, u16* __restrict__ lato,
  u16* __restrict__ latup, u16* __restrict__ latdn)
{
  long i = (long)blockIdx.x*256 + threadIdx.x;
  if (i < 3072){ int p=(int)(i>>10); biascat[i] = (p==0?bq:(p==1?bk:bv))[i&1023]; return; }
  i -= 3072;
  if (i < 49152){ int k=(int)(i/3072), n=(int)(i%3072); int p=n>>10;
    const float* l = p==0?lbq:(p==1?lbk:lbv);
    lbtqkv[n*32+k] = f2bs(l[k*1024 + (n&1023)]); lbtqkv[n*32+16+k] = 0; return; }
  i -= 49152;
  if (i < 16384){ int k=(int)(i>>10), n=(int)(i&1023);
    lbto[n*32+k] = f2bs(lbo[k*1024+n]); lbto[n*32+16+k] = 0; return; }
  i -= 16384;
  if (i < 65536){ int k=(int)(i>>12), n=(int)(i&4095);
    lbtup[n*32+k] = f2bs(lbup[k*4096+n]); lbtup[n*32+16+k] = 0; return; }
  i -= 65536;
  if (i < 16384){ int k=(int)(i>>10), n=(int)(i&1023);
    lbtdn[n*32+k] = f2bs(lbdn[k*1024+n]); lbtdn[n*32+16+k] = 0; return; }
  i -= 16384;
  if (i < 49152){ int r=(int)(i>>10), k=(int)(i&1023);
    const float* l = r<16 ? laq : (r<32 ? lak : lav);
    latqkv[i] = f2bs(l[k*16 + (r&15)]); return; }
  i -= 49152;
  if (i < 16384){ int r=(int)(i>>10), k=(int)(i&1023);
    lato[i] = f2bs(lao[k*16+r]); return; }
  i -= 16384;
  if (i < 16384){ int r=(int)(i>>10), k=(int)(i&1023);
    latup[i] = f2bs(laup[k*16+r]); return; }
  i -= 16384;
  if (i < 65536){ int r=(int)(i>>12), k=(int)(i&4095);
    latdn[i] = f2bs(ladn[k*16+r]); }
}

// ---- V transpose ----
__global__ __launch_bounds__(256) void transpose_v(const u16* __restrict__ qkv, u16* __restrict__ vt){
  const int st = blockIdx.x;     // s tile (0..7)
  const int z = blockIdx.y;      // b*16+h
  const int b = z >> 4, h = z & 15;
  __shared__ u16 tile[64][68];
  const int t = threadIdx.x;
  const int q16 = t & 15, g16 = t >> 4;
  const u16* src = qkv + ((long)(b*512 + st*64))*3072 + 2048 + h*64;
  #pragma unroll
  for (int i=0;i<4;i++){
    int s_l = i*16 + g16;
    const u16* pp = src + (long)s_l*3072 + q16*4;
    #pragma unroll
    for (int jj=0;jj<4;jj++) tile[s_l][q16*4+jj] = pp[jj];
  }
  __syncthreads();
  u16* dst = vt + (long)z*64*512 + st*64;
  #pragma unroll
  for (int i=0;i<4;i++){
    int d_l = i*16 + g16;
    int s_l = q16*4;
    unsigned long long v = (unsigned long long)tile[s_l][d_l]
      | ((unsigned long long)tile[s_l+1][d_l] << 16)
      | ((unsigned long long)tile[s_l+2][d_l] << 32)
      | ((unsigned long long)tile[s_l+3][d_l] << 48);
    *(unsigned long long*)(dst + (long)d_l*512 + s_l) = v;
  }
}

// ---- LayerNorm over rows of 1024 fp32; optional fp32 + bf16 outputs ----
__global__ __launch_bounds__(256) void ln_k(
    const float* __restrict__ in, float* __restrict__ outf, u16* __restrict__ outb,
    const float* __restrict__ gam, const float* __restrict__ bet)
{
  const long row = blockIdx.x;
  const float4 v = ((const float4*)(in + row*1024))[threadIdx.x];
  float s = v.x+v.y+v.z+v.w;
  float q = v.x*v.x + v.y*v.y + v.z*v.z + v.w*v.w;
  const int lane = threadIdx.x & 63, w = threadIdx.x >> 6;
  __shared__ float rs[4], rq[4];
  #pragma unroll
  for (int o=32;o;o>>=1){ s += __shfl_down(s,o); q += __shfl_down(q,o); }
  if (!lane){ rs[w]=s; rq[w]=q; }
  __syncthreads();
  const float S = rs[0]+rs[1]+rs[2]+rs[3];
  const float Q = rq[0]+rq[1]+rq[2]+rq[3];
  const float mu = S*(1.f/1024.f);
  const float var = Q*(1.f/1024.f) - mu*mu;
  const float rstd = rsqrtf(var + 1e-5f);
  const float4 g = ((const float4*)gam)[threadIdx.x];
  const float4 b = ((const float4*)bet)[threadIdx.x];
  float4 o;
  o.x = (v.x-mu)*rstd*g.x + b.x;
  o.y = (v.y-mu)*rstd*g.y + b.y;
  o.z = (v.z-mu)*rstd*g.z + b.z;
  o.w = (v.w-mu)*rstd*g.w + b.w;
  if (outf) ((float4*)(outf + row*1024))[threadIdx.x] = o;
  if (outb){
    uint2 u;
    u.x = (unsigned)f2bs(o.x) | ((unsigned)f2bs(o.y) << 16);
    u.y = (unsigned)f2bs(o.z) | ((unsigned)f2bs(o.w) << 16);
    ((uint2*)(outb + row*1024))[threadIdx.x] = u;
  }
}

extern "C" void kernel_launch(void* const* d_in, const int* in_sizes, int n_in,
                              void* d_out, int out_size, void* d_ws, size_t ws_size,
                              hipStream_t stream) {
  const float* x      = (const float*)d_in[0];
  const float* mask   = (const float*)d_in[1];
  const float* w_q    = (const float*)d_in[2];
  const float* b_q    = (const float*)d_in[3];
  const float* la_q   = (const float*)d_in[4];
  const float* lb_q   = (const float*)d_in[5];
  const float* w_k    = (const float*)d_in[6];
  const float* b_k    = (const float*)d_in[7];
  const float* la_k   = (const float*)d_in[8];
  const float* lb_k   = (const float*)d_in[9];
  const float* w_v    = (const float*)d_in[10];
  const float* b_v    = (const float*)d_in[11];
  const float* la_v   = (const float*)d_in[12];
  const float* lb_v   = (const float*)d_in[13];
  const float* w_o    = (const float*)d_in[14];
  const float* b_o    = (const float*)d_in[15];
  const float* la_o   = (const float*)d_in[16];
  const float* lb_o   = (const float*)d_in[17];
  const float* nw1    = (const float*)d_in[18];
  const float* nb1    = (const float*)d_in[19];
  const float* w_up   = (const float*)d_in[20];
  const float* b_up   = (const float*)d_in[21];
  const float* la_up  = (const float*)d_in[22];
  const float* lb_up  = (const float*)d_in[23];
  const float* w_dn   = (const float*)d_in[24];
  const float* b_dn   = (const float*)d_in[25];
  const float* la_dn  = (const float*)d_in[26];
  const float* lb_dn  = (const float*)d_in[27];
  const float* nw2    = (const float*)d_in[28];
  const float* nb2    = (const float*)d_in[29];
  float* out = (float*)d_out;

  char* ws = (char*)d_ws;
  size_t used = 0;
  auto alloc = [&](size_t bytes) -> char* {
    char* p = ws + used;
    used += (bytes + 255) & ~(size_t)255;
    return p;
  };
  u16*   xb      = (u16*)  alloc(4194304*2);
  u16*   wqkv    = (u16*)  alloc(3145728*2);
  u16*   wob     = (u16*)  alloc(1048576*2);
  u16*   wupb    = (u16*)  alloc(4194304*2);
  u16*   wdnb    = (u16*)  alloc(4194304*2);
  float* biascat = (float*)alloc(3072*4);
  u16*   lbtqkv  = (u16*)  alloc(3072*32*2);
  u16*   lbto    = (u16*)  alloc(1024*32*2);
  u16*   lbtup   = (u16*)  alloc(4096*32*2);
  u16*   lbtdn   = (u16*)  alloc(1024*32*2);
  u16*   latqkv  = (u16*)  alloc(48*1024*2);
  u16*   lato    = (u16*)  alloc(16*1024*2);
  u16*   latup   = (u16*)  alloc(16*1024*2);
  u16*   latdn   = (u16*)  alloc(16*4096*2);
  u16*   t_all   = (u16*)  alloc(4096*96*2);
  u16*   t_o     = (u16*)  alloc(4096*32*2);
  u16*   t_up    = (u16*)  alloc(4096*32*2);
  u16*   t_dn    = (u16*)  alloc(4096*32*2);
  u16*   qkv     = (u16*)  alloc((size_t)4096*3072*2);
  u16*   vt      = (u16*)  alloc((size_t)128*64*512*2);
  u16*   attn_o  = (u16*)  alloc(4194304*2);
  float* o_final = (float*)alloc((size_t)4194304*4);
  float* x_med   = (float*)alloc((size_t)4194304*4);
  u16*   x_med_b = (u16*)  alloc(4194304*2);
  u16*   fn      = (u16*)  alloc((size_t)4096*4096*2);
  if (used > ws_size) return;  // workspace too small -> clean validation failure

  // 1. convert
  convert_bulk<<<2048, 256, 0, stream>>>(x, w_q, w_k, w_v, w_o, w_up, w_dn,
                                         xb, wqkv, wob, wupb, wdnb);
  convert_small<<<1164, 256, 0, stream>>>(b_q, b_k, b_v, lb_q, lb_k, lb_v,
                                          lb_o, lb_up, lb_dn,
                                          la_q, la_k, la_v, la_o, la_up, la_dn,
                                          biascat, lbtqkv, lbto, lbtup, lbtdn,
                                          latqkv, lato, latup, latdn);
  // 2. LoRA stage-1 q,k,v fused (A = xb bf16, shared A-read)
  lora_mfma<3><<<256, 64, 0, stream>>>(xb, 1024, latqkv, t_all, 96);
  // 3. fused QKV GEMM -> qkv [4096, 3072] bf16
  gemm_bt<128,128,64,64,EP_BF16,true,true><<<dim3(24,32,1), 256, 0, stream>>>(
      xb, 1024, wqkv, 1024, 1024, qkv, nullptr, 3072,
      biascat, t_all, 96, lbtqkv, nullptr);
  // 4. V transpose -> vt [128][64][512]
  transpose_v<<<dim3(8,128), 256, 0, stream>>>(qkv, vt);
  // 5. fused flash attention -> attn_o bf16 [4096][1024]
  flash_attn<<<dim3(4,128), 256, 0, stream>>>(qkv, vt, mask, attn_o);
  // 6. LoRA stage-1 for O
  lora_mfma<1><<<256, 64, 0, stream>>>(attn_o, 1024, lato, t_o, 32);
  // 7. O projection + bias + lora + residual(x) -> o_final fp32
  gemm_bt<64,128,32,64,EP_F32RES,true,true><<<dim3(8,64,1), 256, 0, stream>>>(
      attn_o, 1024, wob, 1024, 1024, nullptr, o_final, 1024,
      b_o, t_o, 32, lbto, x);
  // 8. LN1 -> x_med fp32 + bf16
  ln_k<<<4096, 256, 0, stream>>>(o_final, x_med, x_med_b, nw1, nb1);
  // 9. LoRA stage-1 for up (A = x_med_b bf16)
  lora_mfma<1><<<256, 64, 0, stream>>>(x_med_b, 1024, latup, t_up, 32);
  // 10. up GEMM + bias + lora + GELU -> fn bf16 [4096,4096]
  gemm_bt<128,128,64,64,EP_GELU,true,true><<<dim3(32,32,1), 256, 0, stream>>>(
      x_med_b, 1024, wupb, 1024, 1024, fn, nullptr, 4096,
      b_up, t_up, 32, lbtup, nullptr);
  // 11. LoRA stage-1 for down (A = fn bf16, K=4096)
  lora_mfma<1><<<256, 64, 0, stream>>>(fn, 4096, latdn, t_dn, 32);
  // 12. down GEMM + bias + lora + residual(x_med) -> d_out fp32
  gemm_bt<64,128,32,64,EP_F32RES,true,true><<<dim3(8,64,1), 256, 0, stream>>>(
      fn, 4096, wdnb, 4096, 4096, nullptr, out, 1024,
      b_dn, t_dn, 32, lbtdn, x_med);
  // 13. LN2 in place on d_out
  ln_k<<<4096, 256, 0, stream>>>(out, out, nullptr, nw2, nb2);
}

// Round 6
// 315.243 us; speedup vs baseline: 3.7725x; 1.0654x over previous
//
#include <hip/hip_runtime.h>
#include <math.h>

typedef unsigned short u16;
typedef __attribute__((ext_vector_type(8))) short short8;
typedef __attribute__((ext_vector_type(4))) float floatx4;

#define DEV __device__ __forceinline__

DEV u16 f2bs(float f){ union{float f; unsigned u;} v; v.f=f; unsigned r = v.u + 0x7fffu + ((v.u>>16)&1u); return (u16)(r>>16); }
DEV float bs2f(u16 u){ union{float f; unsigned u;} v; v.u = ((unsigned)u)<<16; return v.f; }

#define GLL16(G,L) __builtin_amdgcn_global_load_lds((__attribute__((address_space(1))) const void*)(G), (__attribute__((address_space(3))) void*)(L), 16, 0, 0)

enum { EP_BF16=0, EP_F32RES=3, EP_GELU=4 };

// XCD-chunked bijective block swizzle (m204) + group-major (G rows) ordering.
DEV void swizzle_bid(int orig, int gx, int gy, int& bx, int& by){
  const int nwg = gx*gy;
  const int q = nwg >> 3, r = nwg & 7;
  const int xcd = orig & 7, idx = orig >> 3;
  const int logical = (xcd < r) ? xcd*(q+1) + idx : r*(q+1) + (xcd-r)*q + idx;
  const int G = 8;
  const int per = G*gx;
  const int gid = logical / per;
  const int rem = logical - gid*per;
  const int by0 = gid*G;
  const int rows = min(G, gy - by0);
  by = by0 + rem % rows;
  bx = rem / rows;
}

// C[m][n] = sum_k A[m][k]*B[n][k]  (B^T layout), bf16 in, fp32 acc.
// Double-buffered LDS: stage tile k+1 BEFORE computing tile k, so the
// __syncthreads vmcnt(0) drain overlaps load latency with MFMA (T3 2-phase).
template<int BM,int BN,int WM,int WN,int MODE,bool LORA,bool SWZ>
__global__ __launch_bounds__(256) void gemm_bt(
    const u16* __restrict__ A, int lda,
    const u16* __restrict__ B, int ldb,
    int K,
    u16* __restrict__ obf, float* __restrict__ of32, int ldc,
    const float* __restrict__ bias,
    const u16* __restrict__ tA, int tlda,
    const u16* __restrict__ lbB,
    const float* __restrict__ resid)
{
  constexpr int NWM = BM/WM, NWN = BN/WN, NW = NWM*NWN;
  constexpr int FM = WM/16, FN = WN/16;
  constexpr int TILE = (BM+BN)*32;
  static_assert(NW*64 == 256, "block must be 256 threads");
  __shared__ u16 ab[2*TILE];

  const int tid = threadIdx.x;
  const int lane = tid & 63, wave = tid >> 6;
  const int wr = wave / NWN, wc = wave % NWN;
  const int row16 = lane & 15, kgrp = lane >> 4;
  int bx = blockIdx.x, by = blockIdx.y;
  if constexpr (SWZ)
    swizzle_bid(blockIdx.y*gridDim.x + blockIdx.x, gridDim.x, gridDim.y, bx, by);
  const int bm0 = by * BM, bn0 = bx * BN;

  const u16* Ab = A + (long)bm0*lda;
  const u16* Bb = B + (long)bn0*ldb;
  const int tsel = (LORA && tlda==96) ? ((bn0>>10)*32) : 0;
  // pre-swizzled source chunk: chunk' = (lane&3) ^ ((lane>>2)&3)
  const int gcol = (((lane&3) ^ ((lane>>2)&3)))*8;
  const int grow = lane>>2;

  const int nKT = K >> 5;
  const int nIT = nKT + (LORA ? 1 : 0);

  auto stage = [&](int kt, int buf){
    const u16 *Ak, *Bk; long la_, lb_;
    if (!LORA || kt < nKT){ Ak = Ab + kt*32; la_ = lda; Bk = Bb + kt*32; lb_ = ldb; }
    else { Ak = tA + (long)bm0*tlda + tsel; la_ = tlda; Bk = lbB + (long)bn0*32; lb_ = 32; }
    char* l = (char*)(ab + buf*TILE);
    #pragma unroll
    for (int c0=0; c0<BM/16; c0+=NW){
      int c = c0 + wave;
      GLL16(Ak + (long)(c*16 + grow)*la_ + gcol, l + c*1024);
    }
    #pragma unroll
    for (int c0=0; c0<BN/16; c0+=NW){
      int c = c0 + wave;
      GLL16(Bk + (long)(c*16 + grow)*lb_ + gcol, l + BM*64 + c*1024);
    }
  };

  floatx4 acc[FM][FN];
  #pragma unroll
  for (int i=0;i<FM;i++)
    #pragma unroll
    for (int j=0;j<FN;j++)
      acc[i][j] = (floatx4){0.f,0.f,0.f,0.f};

  stage(0, 0);
  __syncthreads();
  int cur = 0;
  for (int kt=0; kt<nIT; ++kt){
    if (kt+1 < nIT) stage(kt+1, cur^1);   // prefetch: in flight during MFMA
    const char* lds = (const char*)(ab + cur*TILE);
    short8 af[FM], bfr[FN];
    #pragma unroll
    for (int mi=0;mi<FM;mi++){
      int r_ = wr*WM + mi*16 + row16;
      af[mi] = *(const short8*)(lds + r_*64 + ((kgrp ^ (r_&3))<<4));
    }
    #pragma unroll
    for (int ni=0;ni<FN;ni++){
      int r_ = wc*WN + ni*16 + row16;
      bfr[ni] = *(const short8*)(lds + BM*64 + r_*64 + ((kgrp ^ (r_&3))<<4));
    }
    #pragma unroll
    for (int mi=0;mi<FM;mi++)
      #pragma unroll
      for (int ni=0;ni<FN;ni++)
        acc[mi][ni] = __builtin_amdgcn_mfma_f32_16x16x32_bf16(af[mi], bfr[ni], acc[mi][ni], 0, 0, 0);
    __syncthreads();   // drains vmcnt(0): next tile staged; cur reads done
    cur ^= 1;
  }

  #pragma unroll
  for (int mi=0;mi<FM;mi++){
    #pragma unroll
    for (int r=0;r<4;r++){
      const int ml = wr*WM + mi*16 + kgrp*4 + r;
      const long mg = bm0 + ml;
      #pragma unroll
      for (int ni=0;ni<FN;ni++){
        const int nl = wc*WN + ni*16 + row16;
        const int ng = bn0 + nl;
        float v = acc[mi][ni][r] + bias[ng];
        if constexpr (MODE==EP_F32RES){
          v += resid[mg*ldc + ng];
          of32[mg*ldc + ng] = v;
        } else if constexpr (MODE==EP_GELU){
          v = 0.5f*v*(1.f + erff(v*0.70710678118654752f));
          obf[mg*ldc + ng] = f2bs(v);
        } else {
          obf[mg*ldc + ng] = f2bs(v);
        }
      }
    }
  }
}

// ---- LoRA stage-1 via MFMA: t[m][r] = sum_k A[m][k]*la[k][r] ----
template<int NT>
__global__ __launch_bounds__(64) void lora_mfma(
    const u16* __restrict__ A, const int K,
    const u16* __restrict__ lat,
    u16* __restrict__ t, int tld)
{
  const int lane = threadIdx.x & 63;
  const int c = lane & 15, kg = lane >> 4;
  const int m0 = blockIdx.x * 16;
  const u16* Arow = A + (long)(m0 + c)*K + kg*8;
  const u16* Brow = lat + (long)c*K + kg*8;
  floatx4 acc[NT];
  #pragma unroll
  for (int tj=0;tj<NT;tj++) acc[tj] = (floatx4){0.f,0.f,0.f,0.f};
  const int nKS = K >> 5;
  #pragma unroll 4
  for (int ks=0; ks<nKS; ++ks){
    short8 a = *(const short8*)(Arow + ks*32);
    #pragma unroll
    for (int tj=0; tj<NT; ++tj){
      short8 b = *(const short8*)(Brow + (long)tj*16*K + ks*32);
      acc[tj] = __builtin_amdgcn_mfma_f32_16x16x32_bf16(a, b, acc[tj], 0, 0, 0);
    }
  }
  #pragma unroll
  for (int tj=0; tj<NT; ++tj)
    #pragma unroll
    for (int r=0;r<4;r++){
      u16* dst = t + (long)(m0 + kg*4 + r)*tld + tj*32;
      dst[c] = f2bs(acc[tj][r]);
      dst[16+c] = 0;
    }
}

// ---- fused flash attention: per (q-tile 128, head) block, 4 waves ----
// K/V tiles double-buffered; next-tile stage issued before current compute.
__global__ __launch_bounds__(256) void flash_attn(
    const u16* __restrict__ qkv,   // [4096][3072]
    const u16* __restrict__ vt,    // [128][64][512]
    const float* __restrict__ mask,// [8][512]
    u16* __restrict__ attn_o)      // [4096][1024]
{
  __shared__ u16 sm[33792]; // Q[128][64] | K dbuf 2x4096 | V dbuf 2x4096 | P 4x[32][72]
  u16* Qs = sm;
  u16* Ps = sm + 24576;

  const int tid = threadIdx.x, lane = tid & 63, wave = tid >> 6;
  const int c = lane & 15, kg = lane >> 4;
  const int qt = blockIdx.x;        // 0..3
  const int z  = blockIdx.y;        // b*16+h
  const int b = z >> 4, h = z & 15;
  const int q0 = qt * 128;
  const int srow = lane >> 3;
  const int scol = ((lane&7) ^ srow) * 8;

  const u16* kbase = qkv + ((long)(b*512))*3072 + 1024 + h*64;
  const u16* vbase = vt + (long)z*64*512;

  auto stage_kv = [&](int kv, int buf){
    char* Kd = (char*)(sm + 8192  + buf*4096);
    char* Vd = (char*)(sm + 16384 + buf*4096);
    #pragma unroll
    for (int i=0;i<2;i++){
      int rb = i*32 + wave*8;
      GLL16(kbase + (long)(kv*64 + rb + srow)*3072 + scol, Kd + rb*128);
      GLL16(vbase + (long)(rb + srow)*512 + kv*64 + scol, Vd + rb*128);
    }
  };

  {
    const u16* src = qkv + ((long)(b*512 + q0))*3072 + h*64;
    #pragma unroll
    for (int i=0;i<4;i++){
      int rb = i*32 + wave*8;
      GLL16(src + (long)(rb + srow)*3072 + scol, (char*)Qs + rb*128);
    }
  }
  stage_kv(0, 0);
  __syncthreads();

  auto ld_swz = [&](const u16* t, int row, int koff8) -> short8 {
    return *(const short8*)((const char*)t + row*128 + ((koff8 ^ (row&7))<<4));
  };

  short8 af[2][2];
  #pragma unroll
  for (int mi=0;mi<2;mi++)
    #pragma unroll
    for (int ks=0;ks<2;ks++)
      af[mi][ks] = ld_swz(Qs, wave*32 + mi*16 + c, ks*4 + kg);

  floatx4 o_acc[2][4];
  float m_run[2][4], l_run[2][4];
  #pragma unroll
  for (int mi=0;mi<2;mi++){
    #pragma unroll
    for (int dj=0;dj<4;dj++) o_acc[mi][dj] = (floatx4){0.f,0.f,0.f,0.f};
    #pragma unroll
    for (int r=0;r<4;r++){ m_run[mi][r] = -3.0e38f; l_run[mi][r] = 0.f; }
  }

  int cur = 0;
  for (int kv=0; kv<8; ++kv){
    if (kv+1 < 8) stage_kv(kv+1, cur^1);   // prefetch next K/V
    const u16* Ks = sm + 8192  + cur*4096;
    const u16* Vs = sm + 16384 + cur*4096;

    floatx4 s_acc[2][4];
    #pragma unroll
    for (int mi=0;mi<2;mi++)
      #pragma unroll
      for (int ni=0;ni<4;ni++)
        s_acc[mi][ni] = (floatx4){0.f,0.f,0.f,0.f};
    #pragma unroll
    for (int ks=0;ks<2;ks++){
      short8 bf[4];
      #pragma unroll
      for (int ni=0;ni<4;ni++)
        bf[ni] = ld_swz(Ks, ni*16 + c, ks*4 + kg);
      #pragma unroll
      for (int mi=0;mi<2;mi++)
        #pragma unroll
        for (int ni=0;ni<4;ni++)
          s_acc[mi][ni] = __builtin_amdgcn_mfma_f32_16x16x32_bf16(af[mi][ks], bf[ni], s_acc[mi][ni], 0, 0, 0);
    }

    float mv[4];
    #pragma unroll
    for (int ni=0;ni<4;ni++) mv[ni] = mask[b*512 + kv*64 + ni*16 + c];

    #pragma unroll
    for (int mi=0;mi<2;mi++){
      #pragma unroll
      for (int r=0;r<4;r++){
        float s0 = s_acc[mi][0][r]*0.125f + mv[0];
        float s1 = s_acc[mi][1][r]*0.125f + mv[1];
        float s2 = s_acc[mi][2][r]*0.125f + mv[2];
        float s3 = s_acc[mi][3][r]*0.125f + mv[3];
        float tmax = fmaxf(fmaxf(s0,s1), fmaxf(s2,s3));
        #pragma unroll
        for (int o=1;o<16;o<<=1) tmax = fmaxf(tmax, __shfl_xor(tmax, o));
        const float mnew = fmaxf(m_run[mi][r], tmax);
        const float p0 = __expf(s0 - mnew), p1 = __expf(s1 - mnew);
        const float p2 = __expf(s2 - mnew), p3 = __expf(s3 - mnew);
        float psum = p0+p1+p2+p3;
        #pragma unroll
        for (int o=1;o<16;o<<=1) psum += __shfl_xor(psum, o);
        const float alpha = __expf(m_run[mi][r] - mnew);
        l_run[mi][r] = l_run[mi][r]*alpha + psum;
        m_run[mi][r] = mnew;
        #pragma unroll
        for (int dj=0;dj<4;dj++) o_acc[mi][dj][r] *= alpha;
        const int rl = mi*16 + kg*4 + r;
        u16* pw = Ps + wave*2304 + rl*72;
        pw[c]      = f2bs(p0);
        pw[16 + c] = f2bs(p1);
        pw[32 + c] = f2bs(p2);
        pw[48 + c] = f2bs(p3);
      }
    }
    __syncthreads();  // P visible; next-tile stage drained (overlapped w/ QK^T+softmax)

    #pragma unroll
    for (int ks=0;ks<2;ks++){
      short8 pa[2], vb[4];
      #pragma unroll
      for (int mi=0;mi<2;mi++)
        pa[mi] = *(const short8*)&Ps[wave*2304 + (mi*16 + c)*72 + ks*32 + kg*8];
      #pragma unroll
      for (int dj=0;dj<4;dj++)
        vb[dj] = ld_swz(Vs, dj*16 + c, ks*4 + kg);
      #pragma unroll
      for (int mi=0;mi<2;mi++)
        #pragma unroll
        for (int dj=0;dj<4;dj++)
          o_acc[mi][dj] = __builtin_amdgcn_mfma_f32_16x16x32_bf16(pa[mi], vb[dj], o_acc[mi][dj], 0, 0, 0);
    }
    __syncthreads();  // all reads of cur buffers done before next overwrite
    cur ^= 1;
  }

  #pragma unroll
  for (int mi=0;mi<2;mi++){
    #pragma unroll
    for (int r=0;r<4;r++){
      const float inv = 1.f / l_run[mi][r];
      const int s_g = q0 + wave*32 + mi*16 + kg*4 + r;
      u16* dst = attn_o + (long)(b*512 + s_g)*1024 + h*64;
      #pragma unroll
      for (int dj=0;dj<4;dj++)
        dst[dj*16 + c] = f2bs(o_acc[mi][dj][r]*inv);
    }
  }
}

// ---- bulk fp32 -> bf16 conversion, float4 wide ----
__global__ __launch_bounds__(256) void convert_bulk(
  const float* __restrict__ x,
  const float* __restrict__ wq, const float* __restrict__ wk, const float* __restrict__ wv,
  const float* __restrict__ wo, const float* __restrict__ wup, const float* __restrict__ wdn,
  u16* __restrict__ xb, u16* __restrict__ wqkv, u16* __restrict__ wob,
  u16* __restrict__ wupb, u16* __restrict__ wdnb)
{
  const long NX = 4194304, NWt = 1048576;
  const long T4 = (NX + 3*NWt + NWt + NX + NX) >> 2;
  for (long i4 = (long)blockIdx.x*256 + threadIdx.x; i4 < T4; i4 += (long)gridDim.x*256){
    long j = i4 << 2;
    const float* src; u16* dst; long soff, doff;
    if (j < NX){ src=x; dst=xb; soff=j; doff=j; }
    else { j -= NX;
      if (j < 3*NWt){ int p=(int)(j>>20); src = p==0?wq:(p==1?wk:wv); dst=wqkv; soff = j & (NWt-1); doff = j; }
      else { j -= 3*NWt;
        if (j < NWt){ src=wo; dst=wob; soff=j; doff=j; }
        else { j -= NWt;
          if (j < NX){ src=wup; dst=wupb; soff=j; doff=j; }
          else { j -= NX; src=wdn; dst=wdnb; soff=j; doff=j; }
        }
      }
    }
    const float4 v = *(const float4*)(src + soff);
    ushort4 o;
    o.x = f2bs(v.x); o.y = f2bs(v.y); o.z = f2bs(v.z); o.w = f2bs(v.w);
    *(ushort4*)(dst + doff) = o;
  }
}

// ---- small conversions: bias concat, lb^T tiles, la^T tiles ----
__global__ __launch_bounds__(256) void convert_small(
  const float* __restrict__ bq, const float* __restrict__ bk, const float* __restrict__ bv,
  const float* __restrict__ lbq, const float* __restrict__ lbk, const float* __restrict__ lbv,
  const float* __restrict__ lbo, const float* __restrict__ lbup, const float* __restrict__ lbdn,
  const float* __restrict__ laq, const float* __restrict__ lak, const float* __restrict__ lav,
  const float* __restrict__ lao, const float* __restrict__ laup, const float* __restrict__ ladn,
  float* __restrict__ biascat, u16* __restrict__ lbtqkv, u16* __restrict__ lbto,
  u16* __restrict__ lbtup, u16* __restrict__ lbtdn,
  u16* __restrict__ latqkv, u16* __restrict__ lato,
  u16* __restrict__ latup, u16* __restrict__ latdn)
{
  long i = (long)blockIdx.x*256 + threadIdx.x;
  if (i < 3072){ int p=(int)(i>>10); biascat[i] = (p==0?bq:(p==1?bk:bv))[i&1023]; return; }
  i -= 3072;
  if (i < 49152){ int k=(int)(i/3072), n=(int)(i%3072); int p=n>>10;
    const float* l = p==0?lbq:(p==1?lbk:lbv);
    lbtqkv[n*32+k] = f2bs(l[k*1024 + (n&1023)]); lbtqkv[n*32+16+k] = 0; return; }
  i -= 49152;
  if (i < 16384){ int k=(int)(i>>10), n=(int)(i&1023);
    lbto[n*32+k] = f2bs(lbo[k*1024+n]); lbto[n*32+16+k] = 0; return; }
  i -= 16384;
  if (i < 65536){ int k=(int)(i>>12), n=(int)(i&4095);
    lbtup[n*32+k] = f2bs(lbup[k*4096+n]); lbtup[n*32+16+k] = 0; return; }
  i -= 65536;
  if (i < 16384){ int k=(int)(i>>10), n=(int)(i&1023);
    lbtdn[n*32+k] = f2bs(lbdn[k*1024+n]); lbtdn[n*32+16+k] = 0; return; }
  i -= 16384;
  if (i < 49152){ int r=(int)(i>>10), k=(int)(i&1023);
    const float* l = r<16 ? laq : (r<32 ? lak : lav);
    latqkv[i] = f2bs(l[k*16 + (r&15)]); return; }
  i -= 49152;
  if (i < 16384){ int r=(int)(i>>10), k=(int)(i&1023);
    lato[i] = f2bs(lao[k*16+r]); return; }
  i -= 16384;
  if (i < 16384){ int r=(int)(i>>10), k=(int)(i&1023);
    latup[i] = f2bs(laup[k*16+r]); return; }
  i -= 16384;
  if (i < 65536){ int r=(int)(i>>12), k=(int)(i&4095);
    latdn[i] = f2bs(ladn[k*16+r]); }
}

// ---- V transpose ----
__global__ __launch_bounds__(256) void transpose_v(const u16* __restrict__ qkv, u16* __restrict__ vt){
  const int st = blockIdx.x;     // s tile (0..7)
  const int z = blockIdx.y;      // b*16+h
  const int b = z >> 4, h = z & 15;
  __shared__ u16 tile[64][68];
  const int t = threadIdx.x;
  const int q16 = t & 15, g16 = t >> 4;
  const u16* src = qkv + ((long)(b*512 + st*64))*3072 + 2048 + h*64;
  #pragma unroll
  for (int i=0;i<4;i++){
    int s_l = i*16 + g16;
    const u16* pp = src + (long)s_l*3072 + q16*4;
    #pragma unroll
    for (int jj=0;jj<4;jj++) tile[s_l][q16*4+jj] = pp[jj];
  }
  __syncthreads();
  u16* dst = vt + (long)z*64*512 + st*64;
  #pragma unroll
  for (int i=0;i<4;i++){
    int d_l = i*16 + g16;
    int s_l = q16*4;
    unsigned long long v = (unsigned long long)tile[s_l][d_l]
      | ((unsigned long long)tile[s_l+1][d_l] << 16)
      | ((unsigned long long)tile[s_l+2][d_l] << 32)
      | ((unsigned long long)tile[s_l+3][d_l] << 48);
    *(unsigned long long*)(dst + (long)d_l*512 + s_l) = v;
  }
}

// ---- LayerNorm over rows of 1024 fp32; optional fp32 + bf16 outputs ----
__global__ __launch_bounds__(256) void ln_k(
    const float* __restrict__ in, float* __restrict__ outf, u16* __restrict__ outb,
    const float* __restrict__ gam, const float* __restrict__ bet)
{
  const long row = blockIdx.x;
  const float4 v = ((const float4*)(in + row*1024))[threadIdx.x];
  float s = v.x+v.y+v.z+v.w;
  float q = v.x*v.x + v.y*v.y + v.z*v.z + v.w*v.w;
  const int lane = threadIdx.x & 63, w = threadIdx.x >> 6;
  __shared__ float rs[4], rq[4];
  #pragma unroll
  for (int o=32;o;o>>=1){ s += __shfl_down(s,o); q += __shfl_down(q,o); }
  if (!lane){ rs[w]=s; rq[w]=q; }
  __syncthreads();
  const float S = rs[0]+rs[1]+rs[2]+rs[3];
  const float Q = rq[0]+rq[1]+rq[2]+rq[3];
  const float mu = S*(1.f/1024.f);
  const float var = Q*(1.f/1024.f) - mu*mu;
  const float rstd = rsqrtf(var + 1e-5f);
  const float4 g = ((const float4*)gam)[threadIdx.x];
  const float4 b = ((const float4*)bet)[threadIdx.x];
  float4 o;
  o.x = (v.x-mu)*rstd*g.x + b.x;
  o.y = (v.y-mu)*rstd*g.y + b.y;
  o.z = (v.z-mu)*rstd*g.z + b.z;
  o.w = (v.w-mu)*rstd*g.w + b.w;
  if (outf) ((float4*)(outf + row*1024))[threadIdx.x] = o;
  if (outb){
    uint2 u;
    u.x = (unsigned)f2bs(o.x) | ((unsigned)f2bs(o.y) << 16);
    u.y = (unsigned)f2bs(o.z) | ((unsigned)f2bs(o.w) << 16);
    ((uint2*)(outb + row*1024))[threadIdx.x] = u;
  }
}

extern "C" void kernel_launch(void* const* d_in, const int* in_sizes, int n_in,
                              void* d_out, int out_size, void* d_ws, size_t ws_size,
                              hipStream_t stream) {
  const float* x      = (const float*)d_in[0];
  const float* mask   = (const float*)d_in[1];
  const float* w_q    = (const float*)d_in[2];
  const float* b_q    = (const float*)d_in[3];
  const float* la_q   = (const float*)d_in[4];
  const float* lb_q   = (const float*)d_in[5];
  const float* w_k    = (const float*)d_in[6];
  const float* b_k    = (const float*)d_in[7];
  const float* la_k   = (const float*)d_in[8];
  const float* lb_k   = (const float*)d_in[9];
  const float* w_v    = (const float*)d_in[10];
  const float* b_v    = (const float*)d_in[11];
  const float* la_v   = (const float*)d_in[12];
  const float* lb_v   = (const float*)d_in[13];
  const float* w_o    = (const float*)d_in[14];
  const float* b_o    = (const float*)d_in[15];
  const float* la_o   = (const float*)d_in[16];
  const float* lb_o   = (const float*)d_in[17];
  const float* nw1    = (const float*)d_in[18];
  const float* nb1    = (const float*)d_in[19];
  const float* w_up   = (const float*)d_in[20];
  const float* b_up   = (const float*)d_in[21];
  const float* la_up  = (const float*)d_in[22];
  const float* lb_up  = (const float*)d_in[23];
  const float* w_dn   = (const float*)d_in[24];
  const float* b_dn   = (const float*)d_in[25];
  const float* la_dn  = (const float*)d_in[26];
  const float* lb_dn  = (const float*)d_in[27];
  const float* nw2    = (const float*)d_in[28];
  const float* nb2    = (const float*)d_in[29];
  float* out = (float*)d_out;

  char* ws = (char*)d_ws;
  size_t used = 0;
  auto alloc = [&](size_t bytes) -> char* {
    char* p = ws + used;
    used += (bytes + 255) & ~(size_t)255;
    return p;
  };
  u16*   xb      = (u16*)  alloc(4194304*2);
  u16*   wqkv    = (u16*)  alloc(3145728*2);
  u16*   wob     = (u16*)  alloc(1048576*2);
  u16*   wupb    = (u16*)  alloc(4194304*2);
  u16*   wdnb    = (u16*)  alloc(4194304*2);
  float* biascat = (float*)alloc(3072*4);
  u16*   lbtqkv  = (u16*)  alloc(3072*32*2);
  u16*   lbto    = (u16*)  alloc(1024*32*2);
  u16*   lbtup   = (u16*)  alloc(4096*32*2);
  u16*   lbtdn   = (u16*)  alloc(1024*32*2);
  u16*   latqkv  = (u16*)  alloc(48*1024*2);
  u16*   lato    = (u16*)  alloc(16*1024*2);
  u16*   latup   = (u16*)  alloc(16*1024*2);
  u16*   latdn   = (u16*)  alloc(16*4096*2);
  u16*   t_all   = (u16*)  alloc(4096*96*2);
  u16*   t_o     = (u16*)  alloc(4096*32*2);
  u16*   t_up    = (u16*)  alloc(4096*32*2);
  u16*   t_dn    = (u16*)  alloc(4096*32*2);
  u16*   qkv     = (u16*)  alloc((size_t)4096*3072*2);
  u16*   vt      = (u16*)  alloc((size_t)128*64*512*2);
  u16*   attn_o  = (u16*)  alloc(4194304*2);
  float* o_final = (float*)alloc((size_t)4194304*4);
  float* x_med   = (float*)alloc((size_t)4194304*4);
  u16*   x_med_b = (u16*)  alloc(4194304*2);
  u16*   fn      = (u16*)  alloc((size_t)4096*4096*2);
  if (used > ws_size) return;  // workspace too small -> clean validation failure

  // 1. convert
  convert_bulk<<<2048, 256, 0, stream>>>(x, w_q, w_k, w_v, w_o, w_up, w_dn,
                                         xb, wqkv, wob, wupb, wdnb);
  convert_small<<<1164, 256, 0, stream>>>(b_q, b_k, b_v, lb_q, lb_k, lb_v,
                                          lb_o, lb_up, lb_dn,
                                          la_q, la_k, la_v, la_o, la_up, la_dn,
                                          biascat, lbtqkv, lbto, lbtup, lbtdn,
                                          latqkv, lato, latup, latdn);
  // 2. LoRA stage-1 q,k,v fused (A = xb bf16, shared A-read)
  lora_mfma<3><<<256, 64, 0, stream>>>(xb, 1024, latqkv, t_all, 96);
  // 3. fused QKV GEMM -> qkv [4096, 3072] bf16
  gemm_bt<128,128,64,64,EP_BF16,true,true><<<dim3(24,32,1), 256, 0, stream>>>(
      xb, 1024, wqkv, 1024, 1024, qkv, nullptr, 3072,
      biascat, t_all, 96, lbtqkv, nullptr);
  // 4. V transpose -> vt [128][64][512]
  transpose_v<<<dim3(8,128), 256, 0, stream>>>(qkv, vt);
  // 5. fused flash attention -> attn_o bf16 [4096][1024]
  flash_attn<<<dim3(4,128), 256, 0, stream>>>(qkv, vt, mask, attn_o);
  // 6. LoRA stage-1 for O
  lora_mfma<1><<<256, 64, 0, stream>>>(attn_o, 1024, lato, t_o, 32);
  // 7. O projection + bias + lora + residual(x) -> o_final fp32
  gemm_bt<64,128,32,64,EP_F32RES,true,true><<<dim3(8,64,1), 256, 0, stream>>>(
      attn_o, 1024, wob, 1024, 1024, nullptr, o_final, 1024,
      b_o, t_o, 32, lbto, x);
  // 8. LN1 -> x_med fp32 + bf16
  ln_k<<<4096, 256, 0, stream>>>(o_final, x_med, x_med_b, nw1, nb1);
  // 9. LoRA stage-1 for up (A = x_med_b bf16)
  lora_mfma<1><<<256, 64, 0, stream>>>(x_med_b, 1024, latup, t_up, 32);
  // 10. up GEMM + bias + lora + GELU -> fn bf16 [4096,4096]
  gemm_bt<128,128,64,64,EP_GELU,true,true><<<dim3(32,32,1), 256, 0, stream>>>(
      x_med_b, 1024, wupb, 1024, 1024, fn, nullptr, 4096,
      b_up, t_up, 32, lbtup, nullptr);
  // 11. LoRA stage-1 for down (A = fn bf16, K=4096)
  lora_mfma<1><<<256, 64, 0, stream>>>(fn, 4096, latdn, t_dn, 32);
  // 12. down GEMM + bias + lora + residual(x_med) -> d_out fp32
  gemm_bt<64,128,32,64,EP_F32RES,true,true><<<dim3(8,64,1), 256, 0, stream>>>(
      fn, 4096, wdnb, 4096, 4096, nullptr, out, 1024,
      b_dn, t_dn, 32, lbtdn, x_med);
  // 13. LN2 in place on d_out
  ln_k<<<4096, 256, 0, stream>>>(out, out, nullptr, nw2, nb2);
}

// Round 7
// 303.285 us; speedup vs baseline: 3.9212x; 1.0394x over previous
//
#include <hip/hip_runtime.h>
#include <math.h>

typedef unsigned short u16;
typedef __attribute__((ext_vector_type(8))) short short8;
typedef __attribute__((ext_vector_type(4))) float floatx4;

#define DEV __device__ __forceinline__

DEV u16 f2bs(float f){ union{float f; unsigned u;} v; v.f=f; unsigned r = v.u + 0x7fffu + ((v.u>>16)&1u); return (u16)(r>>16); }
DEV float bs2f(u16 u){ union{float f; unsigned u;} v; v.u = ((unsigned)u)<<16; return v.f; }

#define GLL16(G,L) __builtin_amdgcn_global_load_lds((__attribute__((address_space(1))) const void*)(G), (__attribute__((address_space(3))) void*)(L), 16, 0, 0)

enum { EP_BF16=0, EP_F32RES=3, EP_GELU=4 };

// XCD-chunked bijective block swizzle (m204) + group-major (G rows) ordering.
DEV void swizzle_bid(int orig, int gx, int gy, int& bx, int& by){
  const int nwg = gx*gy;
  const int q = nwg >> 3, r = nwg & 7;
  const int xcd = orig & 7, idx = orig >> 3;
  const int logical = (xcd < r) ? xcd*(q+1) + idx : r*(q+1) + (xcd-r)*q + idx;
  const int G = 8;
  const int per = G*gx;
  const int gid = logical / per;
  const int rem = logical - gid*per;
  const int by0 = gid*G;
  const int rows = min(G, gy - by0);
  by = by0 + rem % rows;
  bx = rem / rows;
}

// C[m][n] = sum_k A[m][k]*B[n][k]  (B^T layout), bf16 in, fp32 acc.
// Double-buffered LDS with COUNTED vmcnt (T4): tile k+1's global_load_lds
// stay in flight across the barrier; only tile k's are waited (vmcnt(LPT)).
// Raw s_barrier (no vmcnt(0) drain); lgkmcnt(0)+sched_barrier guard reads.
template<int BM,int BN,int WM,int WN,int MODE,bool LORA,bool SWZ>
__global__ __launch_bounds__(256) void gemm_bt(
    const u16* __restrict__ A, int lda,
    const u16* __restrict__ B, int ldb,
    int K,
    u16* __restrict__ obf, float* __restrict__ of32, int ldc,
    const float* __restrict__ bias,
    const u16* __restrict__ tA, int tlda,
    const u16* __restrict__ lbB,
    const float* __restrict__ resid)
{
  constexpr int NWM = BM/WM, NWN = BN/WN, NW = NWM*NWN;
  constexpr int FM = WM/16, FN = WN/16;
  constexpr int TILE = (BM+BN)*32;
  constexpr int LPT = (BM/16 + BN/16)/NW;   // global_load_lds per wave per tile
  static_assert(NW*64 == 256, "block must be 256 threads");
  __shared__ u16 ab[2*TILE];

  const int tid = threadIdx.x;
  const int lane = tid & 63, wave = tid >> 6;
  const int wr = wave / NWN, wc = wave % NWN;
  const int row16 = lane & 15, kgrp = lane >> 4;
  int bx = blockIdx.x, by = blockIdx.y;
  if constexpr (SWZ)
    swizzle_bid(blockIdx.y*gridDim.x + blockIdx.x, gridDim.x, gridDim.y, bx, by);
  const int bm0 = by * BM, bn0 = bx * BN;

  const u16* Ab = A + (long)bm0*lda;
  const u16* Bb = B + (long)bn0*ldb;
  const int tsel = (LORA && tlda==96) ? ((bn0>>10)*32) : 0;
  // pre-swizzled source chunk: chunk' = (lane&3) ^ ((lane>>2)&3)
  const int gcol = (((lane&3) ^ ((lane>>2)&3)))*8;
  const int grow = lane>>2;

  const int nKT = K >> 5;
  const int nIT = nKT + (LORA ? 1 : 0);

  auto stage = [&](int kt, int buf){
    const u16 *Ak, *Bk; long la_, lb_;
    if (!LORA || kt < nKT){ Ak = Ab + kt*32; la_ = lda; Bk = Bb + kt*32; lb_ = ldb; }
    else { Ak = tA + (long)bm0*tlda + tsel; la_ = tlda; Bk = lbB + (long)bn0*32; lb_ = 32; }
    char* l = (char*)(ab + buf*TILE);
    #pragma unroll
    for (int c0=0; c0<BM/16; c0+=NW){
      int c = c0 + wave;
      GLL16(Ak + (long)(c*16 + grow)*la_ + gcol, l + c*1024);
    }
    #pragma unroll
    for (int c0=0; c0<BN/16; c0+=NW){
      int c = c0 + wave;
      GLL16(Bk + (long)(c*16 + grow)*lb_ + gcol, l + BM*64 + c*1024);
    }
  };

  floatx4 acc[FM][FN];
  #pragma unroll
  for (int i=0;i<FM;i++)
    #pragma unroll
    for (int j=0;j<FN;j++)
      acc[i][j] = (floatx4){0.f,0.f,0.f,0.f};

  stage(0, 0);
  if (nIT > 1) stage(1, 1);
  int cur = 0;
  for (int kt=0; kt<nIT; ++kt){
    // wait ONLY tile kt's loads (tile kt+1's LPT may remain in flight)
    if (kt+1 < nIT) asm volatile("s_waitcnt vmcnt(%0)" :: "n"(LPT) : "memory");
    else            asm volatile("s_waitcnt vmcnt(0)" ::: "memory");
    __builtin_amdgcn_s_barrier();

    const char* lds = (const char*)(ab + cur*TILE);
    short8 af[FM], bfr[FN];
    #pragma unroll
    for (int mi=0;mi<FM;mi++){
      int r_ = wr*WM + mi*16 + row16;
      af[mi] = *(const short8*)(lds + r_*64 + ((kgrp ^ (r_&3))<<4));
    }
    #pragma unroll
    for (int ni=0;ni<FN;ni++){
      int r_ = wc*WN + ni*16 + row16;
      bfr[ni] = *(const short8*)(lds + BM*64 + r_*64 + ((kgrp ^ (r_&3))<<4));
    }
    #pragma unroll
    for (int mi=0;mi<FM;mi++)
      #pragma unroll
      for (int ni=0;ni<FN;ni++)
        acc[mi][ni] = __builtin_amdgcn_mfma_f32_16x16x32_bf16(af[mi], bfr[ni], acc[mi][ni], 0, 0, 0);

    asm volatile("s_waitcnt lgkmcnt(0)" ::: "memory");
    __builtin_amdgcn_sched_barrier(0);
    __builtin_amdgcn_s_barrier();        // all waves done reading buf[cur]
    if (kt+2 < nIT) stage(kt+2, cur);    // reuse freed buffer
    cur ^= 1;
  }

  #pragma unroll
  for (int mi=0;mi<FM;mi++){
    #pragma unroll
    for (int r=0;r<4;r++){
      const int ml = wr*WM + mi*16 + kgrp*4 + r;
      const long mg = bm0 + ml;
      #pragma unroll
      for (int ni=0;ni<FN;ni++){
        const int nl = wc*WN + ni*16 + row16;
        const int ng = bn0 + nl;
        float v = acc[mi][ni][r] + bias[ng];
        if constexpr (MODE==EP_F32RES){
          v += resid[mg*ldc + ng];
          of32[mg*ldc + ng] = v;
        } else if constexpr (MODE==EP_GELU){
          v = 0.5f*v*(1.f + erff(v*0.70710678118654752f));
          obf[mg*ldc + ng] = f2bs(v);
        } else {
          obf[mg*ldc + ng] = f2bs(v);
        }
      }
    }
  }
}

// ---- LoRA stage-1 via MFMA: t[m][r] = sum_k A[m][k]*la[k][r] ----
template<int NT>
__global__ __launch_bounds__(64) void lora_mfma(
    const u16* __restrict__ A, const int K,
    const u16* __restrict__ lat,
    u16* __restrict__ t, int tld)
{
  const int lane = threadIdx.x & 63;
  const int c = lane & 15, kg = lane >> 4;
  const int m0 = blockIdx.x * 16;
  const u16* Arow = A + (long)(m0 + c)*K + kg*8;
  const u16* Brow = lat + (long)c*K + kg*8;
  floatx4 acc[NT];
  #pragma unroll
  for (int tj=0;tj<NT;tj++) acc[tj] = (floatx4){0.f,0.f,0.f,0.f};
  const int nKS = K >> 5;
  #pragma unroll 4
  for (int ks=0; ks<nKS; ++ks){
    short8 a = *(const short8*)(Arow + ks*32);
    #pragma unroll
    for (int tj=0; tj<NT; ++tj){
      short8 b = *(const short8*)(Brow + (long)tj*16*K + ks*32);
      acc[tj] = __builtin_amdgcn_mfma_f32_16x16x32_bf16(a, b, acc[tj], 0, 0, 0);
    }
  }
  #pragma unroll
  for (int tj=0; tj<NT; ++tj)
    #pragma unroll
    for (int r=0;r<4;r++){
      u16* dst = t + (long)(m0 + kg*4 + r)*tld + tj*32;
      dst[c] = f2bs(acc[tj][r]);
      dst[16+c] = 0;
    }
}

// ---- fused flash attention: per (q-tile 128, head) block, 4 waves ----
__global__ __launch_bounds__(256) void flash_attn(
    const u16* __restrict__ qkv,   // [4096][3072]
    const u16* __restrict__ vt,    // [128][64][512]
    const float* __restrict__ mask,// [8][512]
    u16* __restrict__ attn_o)      // [4096][1024]
{
  __shared__ u16 sm[33792]; // Q[128][64] | K dbuf 2x4096 | V dbuf 2x4096 | P 4x[32][72]
  u16* Qs = sm;
  u16* Ps = sm + 24576;

  const int tid = threadIdx.x, lane = tid & 63, wave = tid >> 6;
  const int c = lane & 15, kg = lane >> 4;
  const int qt = blockIdx.x;        // 0..3
  const int z  = blockIdx.y;        // b*16+h
  const int b = z >> 4, h = z & 15;
  const int q0 = qt * 128;
  const int srow = lane >> 3;
  const int scol = ((lane&7) ^ srow) * 8;

  const u16* kbase = qkv + ((long)(b*512))*3072 + 1024 + h*64;
  const u16* vbase = vt + (long)z*64*512;

  auto stage_kv = [&](int kv, int buf){
    char* Kd = (char*)(sm + 8192  + buf*4096);
    char* Vd = (char*)(sm + 16384 + buf*4096);
    #pragma unroll
    for (int i=0;i<2;i++){
      int rb = i*32 + wave*8;
      GLL16(kbase + (long)(kv*64 + rb + srow)*3072 + scol, Kd + rb*128);
      GLL16(vbase + (long)(rb + srow)*512 + kv*64 + scol, Vd + rb*128);
    }
  };

  {
    const u16* src = qkv + ((long)(b*512 + q0))*3072 + h*64;
    #pragma unroll
    for (int i=0;i<4;i++){
      int rb = i*32 + wave*8;
      GLL16(src + (long)(rb + srow)*3072 + scol, (char*)Qs + rb*128);
    }
  }
  stage_kv(0, 0);
  __syncthreads();

  auto ld_swz = [&](const u16* t, int row, int koff8) -> short8 {
    return *(const short8*)((const char*)t + row*128 + ((koff8 ^ (row&7))<<4));
  };

  short8 af[2][2];
  #pragma unroll
  for (int mi=0;mi<2;mi++)
    #pragma unroll
    for (int ks=0;ks<2;ks++)
      af[mi][ks] = ld_swz(Qs, wave*32 + mi*16 + c, ks*4 + kg);

  floatx4 o_acc[2][4];
  float m_run[2][4], l_run[2][4];
  #pragma unroll
  for (int mi=0;mi<2;mi++){
    #pragma unroll
    for (int dj=0;dj<4;dj++) o_acc[mi][dj] = (floatx4){0.f,0.f,0.f,0.f};
    #pragma unroll
    for (int r=0;r<4;r++){ m_run[mi][r] = -3.0e38f; l_run[mi][r] = 0.f; }
  }

  int cur = 0;
  for (int kv=0; kv<8; ++kv){
    if (kv+1 < 8) stage_kv(kv+1, cur^1);   // prefetch next K/V
    const u16* Ks = sm + 8192  + cur*4096;
    const u16* Vs = sm + 16384 + cur*4096;

    floatx4 s_acc[2][4];
    #pragma unroll
    for (int mi=0;mi<2;mi++)
      #pragma unroll
      for (int ni=0;ni<4;ni++)
        s_acc[mi][ni] = (floatx4){0.f,0.f,0.f,0.f};
    #pragma unroll
    for (int ks=0;ks<2;ks++){
      short8 bf[4];
      #pragma unroll
      for (int ni=0;ni<4;ni++)
        bf[ni] = ld_swz(Ks, ni*16 + c, ks*4 + kg);
      #pragma unroll
      for (int mi=0;mi<2;mi++)
        #pragma unroll
        for (int ni=0;ni<4;ni++)
          s_acc[mi][ni] = __builtin_amdgcn_mfma_f32_16x16x32_bf16(af[mi][ks], bf[ni], s_acc[mi][ni], 0, 0, 0);
    }

    float mv[4];
    #pragma unroll
    for (int ni=0;ni<4;ni++) mv[ni] = mask[b*512 + kv*64 + ni*16 + c];

    #pragma unroll
    for (int mi=0;mi<2;mi++){
      #pragma unroll
      for (int r=0;r<4;r++){
        float s0 = s_acc[mi][0][r]*0.125f + mv[0];
        float s1 = s_acc[mi][1][r]*0.125f + mv[1];
        float s2 = s_acc[mi][2][r]*0.125f + mv[2];
        float s3 = s_acc[mi][3][r]*0.125f + mv[3];
        float tmax = fmaxf(fmaxf(s0,s1), fmaxf(s2,s3));
        #pragma unroll
        for (int o=1;o<16;o<<=1) tmax = fmaxf(tmax, __shfl_xor(tmax, o));
        const float mnew = fmaxf(m_run[mi][r], tmax);
        const float p0 = __expf(s0 - mnew), p1 = __expf(s1 - mnew);
        const float p2 = __expf(s2 - mnew), p3 = __expf(s3 - mnew);
        float psum = p0+p1+p2+p3;
        #pragma unroll
        for (int o=1;o<16;o<<=1) psum += __shfl_xor(psum, o);
        const float alpha = __expf(m_run[mi][r] - mnew);
        l_run[mi][r] = l_run[mi][r]*alpha + psum;
        m_run[mi][r] = mnew;
        #pragma unroll
        for (int dj=0;dj<4;dj++) o_acc[mi][dj][r] *= alpha;
        const int rl = mi*16 + kg*4 + r;
        u16* pw = Ps + wave*2304 + rl*72;
        pw[c]      = f2bs(p0);
        pw[16 + c] = f2bs(p1);
        pw[32 + c] = f2bs(p2);
        pw[48 + c] = f2bs(p3);
      }
    }
    __syncthreads();  // P visible; next-tile stage drained (overlapped w/ QK^T+softmax)

    #pragma unroll
    for (int ks=0;ks<2;ks++){
      short8 pa[2], vb[4];
      #pragma unroll
      for (int mi=0;mi<2;mi++)
        pa[mi] = *(const short8*)&Ps[wave*2304 + (mi*16 + c)*72 + ks*32 + kg*8];
      #pragma unroll
      for (int dj=0;dj<4;dj++)
        vb[dj] = ld_swz(Vs, dj*16 + c, ks*4 + kg);
      #pragma unroll
      for (int mi=0;mi<2;mi++)
        #pragma unroll
        for (int dj=0;dj<4;dj++)
          o_acc[mi][dj] = __builtin_amdgcn_mfma_f32_16x16x32_bf16(pa[mi], vb[dj], o_acc[mi][dj], 0, 0, 0);
    }
    __syncthreads();  // all reads of cur buffers done before next overwrite
    cur ^= 1;
  }

  #pragma unroll
  for (int mi=0;mi<2;mi++){
    #pragma unroll
    for (int r=0;r<4;r++){
      const float inv = 1.f / l_run[mi][r];
      const int s_g = q0 + wave*32 + mi*16 + kg*4 + r;
      u16* dst = attn_o + (long)(b*512 + s_g)*1024 + h*64;
      #pragma unroll
      for (int dj=0;dj<4;dj++)
        dst[dj*16 + c] = f2bs(o_acc[mi][dj][r]*inv);
    }
  }
}

// ---- bulk fp32 -> bf16 conversion, float4 wide ----
__global__ __launch_bounds__(256) void convert_bulk(
  const float* __restrict__ x,
  const float* __restrict__ wq, const float* __restrict__ wk, const float* __restrict__ wv,
  const float* __restrict__ wo, const float* __restrict__ wup, const float* __restrict__ wdn,
  u16* __restrict__ xb, u16* __restrict__ wqkv, u16* __restrict__ wob,
  u16* __restrict__ wupb, u16* __restrict__ wdnb)
{
  const long NX = 4194304, NWt = 1048576;
  const long T4 = (NX + 3*NWt + NWt + NX + NX) >> 2;
  for (long i4 = (long)blockIdx.x*256 + threadIdx.x; i4 < T4; i4 += (long)gridDim.x*256){
    long j = i4 << 2;
    const float* src; u16* dst; long soff, doff;
    if (j < NX){ src=x; dst=xb; soff=j; doff=j; }
    else { j -= NX;
      if (j < 3*NWt){ int p=(int)(j>>20); src = p==0?wq:(p==1?wk:wv); dst=wqkv; soff = j & (NWt-1); doff = j; }
      else { j -= 3*NWt;
        if (j < NWt){ src=wo; dst=wob; soff=j; doff=j; }
        else { j -= NWt;
          if (j < NX){ src=wup; dst=wupb; soff=j; doff=j; }
          else { j -= NX; src=wdn; dst=wdnb; soff=j; doff=j; }
        }
      }
    }
    const float4 v = *(const float4*)(src + soff);
    ushort4 o;
    o.x = f2bs(v.x); o.y = f2bs(v.y); o.z = f2bs(v.z); o.w = f2bs(v.w);
    *(ushort4*)(dst + doff) = o;
  }
}

// ---- small conversions: bias concat, lb^T tiles, la^T tiles ----
__global__ __launch_bounds__(256) void convert_small(
  const float* __restrict__ bq, const float* __restrict__ bk, const float* __restrict__ bv,
  const float* __restrict__ lbq, const float* __restrict__ lbk, const float* __restrict__ lbv,
  const float* __restrict__ lbo, const float* __restrict__ lbup, const float* __restrict__ lbdn,
  const float* __restrict__ laq, const float* __restrict__ lak, const float* __restrict__ lav,
  const float* __restrict__ lao, const float* __restrict__ laup, const float* __restrict__ ladn,
  float* __restrict__ biascat, u16* __restrict__ lbtqkv, u16* __restrict__ lbto,
  u16* __restrict__ lbtup, u16* __restrict__ lbtdn,
  u16* __restrict__ latqkv, u16* __restrict__ lato,
  u16* __restrict__ latup, u16* __restrict__ latdn)
{
  long i = (long)blockIdx.x*256 + threadIdx.x;
  if (i < 3072){ int p=(int)(i>>10); biascat[i] = (p==0?bq:(p==1?bk:bv))[i&1023]; return; }
  i -= 3072;
  if (i < 49152){ int k=(int)(i/3072), n=(int)(i%3072); int p=n>>10;
    const float* l = p==0?lbq:(p==1?lbk:lbv);
    lbtqkv[n*32+k] = f2bs(l[k*1024 + (n&1023)]); lbtqkv[n*32+16+k] = 0; return; }
  i -= 49152;
  if (i < 16384){ int k=(int)(i>>10), n=(int)(i&1023);
    lbto[n*32+k] = f2bs(lbo[k*1024+n]); lbto[n*32+16+k] = 0; return; }
  i -= 16384;
  if (i < 65536){ int k=(int)(i>>12), n=(int)(i&4095);
    lbtup[n*32+k] = f2bs(lbup[k*4096+n]); lbtup[n*32+16+k] = 0; return; }
  i -= 65536;
  if (i < 16384){ int k=(int)(i>>10), n=(int)(i&1023);
    lbtdn[n*32+k] = f2bs(lbdn[k*1024+n]); lbtdn[n*32+16+k] = 0; return; }
  i -= 16384;
  if (i < 49152){ int r=(int)(i>>10), k=(int)(i&1023);
    const float* l = r<16 ? laq : (r<32 ? lak : lav);
    latqkv[i] = f2bs(l[k*16 + (r&15)]); return; }
  i -= 49152;
  if (i < 16384){ int r=(int)(i>>10), k=(int)(i&1023);
    lato[i] = f2bs(lao[k*16+r]); return; }
  i -= 16384;
  if (i < 16384){ int r=(int)(i>>10), k=(int)(i&1023);
    latup[i] = f2bs(laup[k*16+r]); return; }
  i -= 16384;
  if (i < 65536){ int r=(int)(i>>12), k=(int)(i&4095);
    latdn[i] = f2bs(ladn[k*16+r]); }
}

// ---- V transpose ----
__global__ __launch_bounds__(256) void transpose_v(const u16* __restrict__ qkv, u16* __restrict__ vt){
  const int st = blockIdx.x;     // s tile (0..7)
  const int z = blockIdx.y;      // b*16+h
  const int b = z >> 4, h = z & 15;
  __shared__ u16 tile[64][68];
  const int t = threadIdx.x;
  const int q16 = t & 15, g16 = t >> 4;
  const u16* src = qkv + ((long)(b*512 + st*64))*3072 + 2048 + h*64;
  #pragma unroll
  for (int i=0;i<4;i++){
    int s_l = i*16 + g16;
    const u16* pp = src + (long)s_l*3072 + q16*4;
    #pragma unroll
    for (int jj=0;jj<4;jj++) tile[s_l][q16*4+jj] = pp[jj];
  }
  __syncthreads();
  u16* dst = vt + (long)z*64*512 + st*64;
  #pragma unroll
  for (int i=0;i<4;i++){
    int d_l = i*16 + g16;
    int s_l = q16*4;
    unsigned long long v = (unsigned long long)tile[s_l][d_l]
      | ((unsigned long long)tile[s_l+1][d_l] << 16)
      | ((unsigned long long)tile[s_l+2][d_l] << 32)
      | ((unsigned long long)tile[s_l+3][d_l] << 48);
    *(unsigned long long*)(dst + (long)d_l*512 + s_l) = v;
  }
}

// ---- LayerNorm over rows of 1024 fp32; optional fp32 + bf16 outputs ----
__global__ __launch_bounds__(256) void ln_k(
    const float* __restrict__ in, float* __restrict__ outf, u16* __restrict__ outb,
    const float* __restrict__ gam, const float* __restrict__ bet)
{
  const long row = blockIdx.x;
  const float4 v = ((const float4*)(in + row*1024))[threadIdx.x];
  float s = v.x+v.y+v.z+v.w;
  float q = v.x*v.x + v.y*v.y + v.z*v.z + v.w*v.w;
  const int lane = threadIdx.x & 63, w = threadIdx.x >> 6;
  __shared__ float rs[4], rq[4];
  #pragma unroll
  for (int o=32;o;o>>=1){ s += __shfl_down(s,o); q += __shfl_down(q,o); }
  if (!lane){ rs[w]=s; rq[w]=q; }
  __syncthreads();
  const float S = rs[0]+rs[1]+rs[2]+rs[3];
  const float Q = rq[0]+rq[1]+rq[2]+rq[3];
  const float mu = S*(1.f/1024.f);
  const float var = Q*(1.f/1024.f) - mu*mu;
  const float rstd = rsqrtf(var + 1e-5f);
  const float4 g = ((const float4*)gam)[threadIdx.x];
  const float4 b = ((const float4*)bet)[threadIdx.x];
  float4 o;
  o.x = (v.x-mu)*rstd*g.x + b.x;
  o.y = (v.y-mu)*rstd*g.y + b.y;
  o.z = (v.z-mu)*rstd*g.z + b.z;
  o.w = (v.w-mu)*rstd*g.w + b.w;
  if (outf) ((float4*)(outf + row*1024))[threadIdx.x] = o;
  if (outb){
    uint2 u;
    u.x = (unsigned)f2bs(o.x) | ((unsigned)f2bs(o.y) << 16);
    u.y = (unsigned)f2bs(o.z) | ((unsigned)f2bs(o.w) << 16);
    ((uint2*)(outb + row*1024))[threadIdx.x] = u;
  }
}

extern "C" void kernel_launch(void* const* d_in, const int* in_sizes, int n_in,
                              void* d_out, int out_size, void* d_ws, size_t ws_size,
                              hipStream_t stream) {
  const float* x      = (const float*)d_in[0];
  const float* mask   = (const float*)d_in[1];
  const float* w_q    = (const float*)d_in[2];
  const float* b_q    = (const float*)d_in[3];
  const float* la_q   = (const float*)d_in[4];
  const float* lb_q   = (const float*)d_in[5];
  const float* w_k    = (const float*)d_in[6];
  const float* b_k    = (const float*)d_in[7];
  const float* la_k   = (const float*)d_in[8];
  const float* lb_k   = (const float*)d_in[9];
  const float* w_v    = (const float*)d_in[10];
  const float* b_v    = (const float*)d_in[11];
  const float* la_v   = (const float*)d_in[12];
  const float* lb_v   = (const float*)d_in[13];
  const float* w_o    = (const float*)d_in[14];
  const float* b_o    = (const float*)d_in[15];
  const float* la_o   = (const float*)d_in[16];
  const float* lb_o   = (const float*)d_in[17];
  const float* nw1    = (const float*)d_in[18];
  const float* nb1    = (const float*)d_in[19];
  const float* w_up   = (const float*)d_in[20];
  const float* b_up   = (const float*)d_in[21];
  const float* la_up  = (const float*)d_in[22];
  const float* lb_up  = (const float*)d_in[23];
  const float* w_dn   = (const float*)d_in[24];
  const float* b_dn   = (const float*)d_in[25];
  const float* la_dn  = (const float*)d_in[26];
  const float* lb_dn  = (const float*)d_in[27];
  const float* nw2    = (const float*)d_in[28];
  const float* nb2    = (const float*)d_in[29];
  float* out = (float*)d_out;

  char* ws = (char*)d_ws;
  size_t used = 0;
  auto alloc = [&](size_t bytes) -> char* {
    char* p = ws + used;
    used += (bytes + 255) & ~(size_t)255;
    return p;
  };
  u16*   xb      = (u16*)  alloc(4194304*2);
  u16*   wqkv    = (u16*)  alloc(3145728*2);
  u16*   wob     = (u16*)  alloc(1048576*2);
  u16*   wupb    = (u16*)  alloc(4194304*2);
  u16*   wdnb    = (u16*)  alloc(4194304*2);
  float* biascat = (float*)alloc(3072*4);
  u16*   lbtqkv  = (u16*)  alloc(3072*32*2);
  u16*   lbto    = (u16*)  alloc(1024*32*2);
  u16*   lbtup   = (u16*)  alloc(4096*32*2);
  u16*   lbtdn   = (u16*)  alloc(1024*32*2);
  u16*   latqkv  = (u16*)  alloc(48*1024*2);
  u16*   lato    = (u16*)  alloc(16*1024*2);
  u16*   latup   = (u16*)  alloc(16*1024*2);
  u16*   latdn   = (u16*)  alloc(16*4096*2);
  u16*   t_all   = (u16*)  alloc(4096*96*2);
  u16*   t_o     = (u16*)  alloc(4096*32*2);
  u16*   t_up    = (u16*)  alloc(4096*32*2);
  u16*   t_dn    = (u16*)  alloc(4096*32*2);
  u16*   qkv     = (u16*)  alloc((size_t)4096*3072*2);
  u16*   vt      = (u16*)  alloc((size_t)128*64*512*2);
  u16*   attn_o  = (u16*)  alloc(4194304*2);
  float* o_final = (float*)alloc((size_t)4194304*4);
  float* x_med   = (float*)alloc((size_t)4194304*4);
  u16*   x_med_b = (u16*)  alloc(4194304*2);
  u16*   fn      = (u16*)  alloc((size_t)4096*4096*2);
  if (used > ws_size) return;  // workspace too small -> clean validation failure

  // 1. convert
  convert_bulk<<<2048, 256, 0, stream>>>(x, w_q, w_k, w_v, w_o, w_up, w_dn,
                                         xb, wqkv, wob, wupb, wdnb);
  convert_small<<<1164, 256, 0, stream>>>(b_q, b_k, b_v, lb_q, lb_k, lb_v,
                                          lb_o, lb_up, lb_dn,
                                          la_q, la_k, la_v, la_o, la_up, la_dn,
                                          biascat, lbtqkv, lbto, lbtup, lbtdn,
                                          latqkv, lato, latup, latdn);
  // 2. LoRA stage-1 q,k,v fused (A = xb bf16, shared A-read)
  lora_mfma<3><<<256, 64, 0, stream>>>(xb, 1024, latqkv, t_all, 96);
  // 3. fused QKV GEMM -> qkv [4096, 3072] bf16
  gemm_bt<128,128,64,64,EP_BF16,true,true><<<dim3(24,32,1), 256, 0, stream>>>(
      xb, 1024, wqkv, 1024, 1024, qkv, nullptr, 3072,
      biascat, t_all, 96, lbtqkv, nullptr);
  // 4. V transpose -> vt [128][64][512]
  transpose_v<<<dim3(8,128), 256, 0, stream>>>(qkv, vt);
  // 5. fused flash attention -> attn_o bf16 [4096][1024]
  flash_attn<<<dim3(4,128), 256, 0, stream>>>(qkv, vt, mask, attn_o);
  // 6. LoRA stage-1 for O
  lora_mfma<1><<<256, 64, 0, stream>>>(attn_o, 1024, lato, t_o, 32);
  // 7. O projection + bias + lora + residual(x) -> o_final fp32
  gemm_bt<64,128,32,64,EP_F32RES,true,true><<<dim3(8,64,1), 256, 0, stream>>>(
      attn_o, 1024, wob, 1024, 1024, nullptr, o_final, 1024,
      b_o, t_o, 32, lbto, x);
  // 8. LN1 -> x_med fp32 + bf16
  ln_k<<<4096, 256, 0, stream>>>(o_final, x_med, x_med_b, nw1, nb1);
  // 9. LoRA stage-1 for up (A = x_med_b bf16)
  lora_mfma<1><<<256, 64, 0, stream>>>(x_med_b, 1024, latup, t_up, 32);
  // 10. up GEMM + bias + lora + GELU -> fn bf16 [4096,4096]
  gemm_bt<128,128,64,64,EP_GELU,true,true><<<dim3(32,32,1), 256, 0, stream>>>(
      x_med_b, 1024, wupb, 1024, 1024, fn, nullptr, 4096,
      b_up, t_up, 32, lbtup, nullptr);
  // 11. LoRA stage-1 for down (A = fn bf16, K=4096)
  lora_mfma<1><<<256, 64, 0, stream>>>(fn, 4096, latdn, t_dn, 32);
  // 12. down GEMM + bias + lora + residual(x_med) -> d_out fp32
  gemm_bt<64,128,32,64,EP_F32RES,true,true><<<dim3(8,64,1), 256, 0, stream>>>(
      fn, 4096, wdnb, 4096, 4096, nullptr, out, 1024,
      b_dn, t_dn, 32, lbtdn, x_med);
  // 13. LN2 in place on d_out
  ln_k<<<4096, 256, 0, stream>>>(out, out, nullptr, nw2, nb2);
}

// Round 8
// 298.200 us; speedup vs baseline: 3.9881x; 1.0171x over previous
//
#include <hip/hip_runtime.h>
#include <math.h>

typedef unsigned short u16;
typedef __attribute__((ext_vector_type(8))) short short8;
typedef __attribute__((ext_vector_type(4))) float floatx4;

#define DEV __device__ __forceinline__

DEV u16 f2bs(float f){ union{float f; unsigned u;} v; v.f=f; unsigned r = v.u + 0x7fffu + ((v.u>>16)&1u); return (u16)(r>>16); }
DEV float bs2f(u16 u){ union{float f; unsigned u;} v; v.u = ((unsigned)u)<<16; return v.f; }

// tanh-form GELU (max |delta| vs exact-erf gelu ~3e-4; bf16-safe).
// th = 1 - 2/(e+1) is overflow-safe (e=inf -> th=1, e=0 -> th=-1).
DEV float gelu_f(float x){
  float u2 = 2.f * x * (0.7978845608028654f + 0.03567740813636141f*x*x);
  float e = __expf(u2);
  float th = 1.f - 2.f/(e + 1.f);
  return 0.5f*x*(1.f + th);
}

#define GLL16(G,L) __builtin_amdgcn_global_load_lds((__attribute__((address_space(1))) const void*)(G), (__attribute__((address_space(3))) void*)(L), 16, 0, 0)

enum { EP_BF16=0, EP_F32RES=3, EP_GELU=4 };

// XCD-chunked bijective block swizzle (m204) + group-major (G rows) ordering.
DEV void swizzle_bid(int orig, int gx, int gy, int& bx, int& by){
  const int nwg = gx*gy;
  const int q = nwg >> 3, r = nwg & 7;
  const int xcd = orig & 7, idx = orig >> 3;
  const int logical = (xcd < r) ? xcd*(q+1) + idx : r*(q+1) + (xcd-r)*q + idx;
  const int G = 8;
  const int per = G*gx;
  const int gid = logical / per;
  const int rem = logical - gid*per;
  const int by0 = gid*G;
  const int rows = min(G, gy - by0);
  by = by0 + rem % rows;
  bx = rem / rows;
}

// C[m][n] = sum_k A[m][k]*B[n][k]  (B^T layout), bf16 in, fp32 acc.
// DEPTH-3 LDS pipeline with counted vmcnt: two tiles' global_load_lds stay
// in flight across each barrier (vmcnt(2*LPT)) -> ~2 iterations of HBM-latency
// cover. Raw s_barrier; lgkmcnt(0)+sched_barrier guard LDS reads.
template<int BM,int BN,int WM,int WN,int MODE,bool LORA,bool SWZ>
__global__ __launch_bounds__(256) void gemm_bt(
    const u16* __restrict__ A, int lda,
    const u16* __restrict__ B, int ldb,
    int K,
    u16* __restrict__ obf, float* __restrict__ of32, int ldc,
    const float* __restrict__ bias,
    const u16* __restrict__ tA, int tlda,
    const u16* __restrict__ lbB,
    const float* __restrict__ resid)
{
  constexpr int NWM = BM/WM, NWN = BN/WN, NW = NWM*NWN;
  constexpr int FM = WM/16, FN = WN/16;
  constexpr int TILE = (BM+BN)*32;
  constexpr int LPT = (BM/16 + BN/16)/NW;   // global_load_lds per wave per tile
  static_assert(NW*64 == 256, "block must be 256 threads");
  __shared__ u16 ab[3*TILE];

  const int tid = threadIdx.x;
  const int lane = tid & 63, wave = tid >> 6;
  const int wr = wave / NWN, wc = wave % NWN;
  const int row16 = lane & 15, kgrp = lane >> 4;
  int bx = blockIdx.x, by = blockIdx.y;
  if constexpr (SWZ)
    swizzle_bid(blockIdx.y*gridDim.x + blockIdx.x, gridDim.x, gridDim.y, bx, by);
  const int bm0 = by * BM, bn0 = bx * BN;

  const u16* Ab = A + (long)bm0*lda;
  const u16* Bb = B + (long)bn0*ldb;
  const int tsel = (LORA && tlda==96) ? ((bn0>>10)*32) : 0;
  // pre-swizzled source chunk: chunk' = (lane&3) ^ ((lane>>2)&3)
  const int gcol = (((lane&3) ^ ((lane>>2)&3)))*8;
  const int grow = lane>>2;

  const int nKT = K >> 5;
  const int nIT = nKT + (LORA ? 1 : 0);

  auto stage = [&](int kt, int buf){
    const u16 *Ak, *Bk; long la_, lb_;
    if (!LORA || kt < nKT){ Ak = Ab + kt*32; la_ = lda; Bk = Bb + kt*32; lb_ = ldb; }
    else { Ak = tA + (long)bm0*tlda + tsel; la_ = tlda; Bk = lbB + (long)bn0*32; lb_ = 32; }
    char* l = (char*)ab + buf*(TILE*2);
    #pragma unroll
    for (int c0=0; c0<BM/16; c0+=NW){
      int c = c0 + wave;
      GLL16(Ak + (long)(c*16 + grow)*la_ + gcol, l + c*1024);
    }
    #pragma unroll
    for (int c0=0; c0<BN/16; c0+=NW){
      int c = c0 + wave;
      GLL16(Bk + (long)(c*16 + grow)*lb_ + gcol, l + BM*64 + c*1024);
    }
  };

  floatx4 acc[FM][FN];
  #pragma unroll
  for (int i=0;i<FM;i++)
    #pragma unroll
    for (int j=0;j<FN;j++)
      acc[i][j] = (floatx4){0.f,0.f,0.f,0.f};

  stage(0, 0);
  if (nIT > 1) stage(1, 1);
  if (nIT > 2) stage(2, 2);
  int cur = 0;
  for (int kt=0; kt<nIT; ++kt){
    // wait ONLY tile kt's loads; up to 2 later tiles stay in flight
    if (kt+2 < nIT)      asm volatile("s_waitcnt vmcnt(%0)" :: "n"(2*LPT) : "memory");
    else if (kt+1 < nIT) asm volatile("s_waitcnt vmcnt(%0)" :: "n"(LPT) : "memory");
    else                 asm volatile("s_waitcnt vmcnt(0)" ::: "memory");
    __builtin_amdgcn_s_barrier();

    const char* lds = (const char*)ab + cur*(TILE*2);
    short8 af[FM], bfr[FN];
    #pragma unroll
    for (int mi=0;mi<FM;mi++){
      int r_ = wr*WM + mi*16 + row16;
      af[mi] = *(const short8*)(lds + r_*64 + ((kgrp ^ (r_&3))<<4));
    }
    #pragma unroll
    for (int ni=0;ni<FN;ni++){
      int r_ = wc*WN + ni*16 + row16;
      bfr[ni] = *(const short8*)(lds + BM*64 + r_*64 + ((kgrp ^ (r_&3))<<4));
    }
    #pragma unroll
    for (int mi=0;mi<FM;mi++)
      #pragma unroll
      for (int ni=0;ni<FN;ni++)
        acc[mi][ni] = __builtin_amdgcn_mfma_f32_16x16x32_bf16(af[mi], bfr[ni], acc[mi][ni], 0, 0, 0);

    asm volatile("s_waitcnt lgkmcnt(0)" ::: "memory");
    __builtin_amdgcn_sched_barrier(0);
    __builtin_amdgcn_s_barrier();        // all waves done reading buf[cur]
    if (kt+3 < nIT) stage(kt+3, cur);    // refill freed buffer
    cur = (cur == 2) ? 0 : cur+1;
  }

  #pragma unroll
  for (int mi=0;mi<FM;mi++){
    #pragma unroll
    for (int r=0;r<4;r++){
      const int ml = wr*WM + mi*16 + kgrp*4 + r;
      const long mg = bm0 + ml;
      #pragma unroll
      for (int ni=0;ni<FN;ni++){
        const int nl = wc*WN + ni*16 + row16;
        const int ng = bn0 + nl;
        float v = acc[mi][ni][r] + bias[ng];
        if constexpr (MODE==EP_F32RES){
          v += resid[mg*ldc + ng];
          of32[mg*ldc + ng] = v;
        } else if constexpr (MODE==EP_GELU){
          obf[mg*ldc + ng] = f2bs(gelu_f(v));
        } else {
          obf[mg*ldc + ng] = f2bs(v);
        }
      }
    }
  }
}

// ---- LoRA stage-1 via MFMA: t[m][r] = sum_k A[m][k]*la[k][r] ----
template<int NT>
__global__ __launch_bounds__(64) void lora_mfma(
    const u16* __restrict__ A, const int K,
    const u16* __restrict__ lat,
    u16* __restrict__ t, int tld)
{
  const int lane = threadIdx.x & 63;
  const int c = lane & 15, kg = lane >> 4;
  const int m0 = blockIdx.x * 16;
  const u16* Arow = A + (long)(m0 + c)*K + kg*8;
  const u16* Brow = lat + (long)c*K + kg*8;
  floatx4 acc[NT];
  #pragma unroll
  for (int tj=0;tj<NT;tj++) acc[tj] = (floatx4){0.f,0.f,0.f,0.f};
  const int nKS = K >> 5;
  #pragma unroll 4
  for (int ks=0; ks<nKS; ++ks){
    short8 a = *(const short8*)(Arow + ks*32);
    #pragma unroll
    for (int tj=0; tj<NT; ++tj){
      short8 b = *(const short8*)(Brow + (long)tj*16*K + ks*32);
      acc[tj] = __builtin_amdgcn_mfma_f32_16x16x32_bf16(a, b, acc[tj], 0, 0, 0);
    }
  }
  #pragma unroll
  for (int tj=0; tj<NT; ++tj)
    #pragma unroll
    for (int r=0;r<4;r++){
      u16* dst = t + (long)(m0 + kg*4 + r)*tld + tj*32;
      dst[c] = f2bs(acc[tj][r]);
      dst[16+c] = 0;
    }
}

// ---- fused flash attention: per (q-tile 128, head) block, 4 waves ----
__global__ __launch_bounds__(256) void flash_attn(
    const u16* __restrict__ qkv,   // [4096][3072]
    const u16* __restrict__ vt,    // [128][64][512]
    const float* __restrict__ mask,// [8][512]
    u16* __restrict__ attn_o)      // [4096][1024]
{
  __shared__ u16 sm[33792]; // Q[128][64] | K dbuf 2x4096 | V dbuf 2x4096 | P 4x[32][72]
  u16* Qs = sm;
  u16* Ps = sm + 24576;

  const int tid = threadIdx.x, lane = tid & 63, wave = tid >> 6;
  const int c = lane & 15, kg = lane >> 4;
  const int qt = blockIdx.x;        // 0..3
  const int z  = blockIdx.y;        // b*16+h
  const int b = z >> 4, h = z & 15;
  const int q0 = qt * 128;
  const int srow = lane >> 3;
  const int scol = ((lane&7) ^ srow) * 8;

  const u16* kbase = qkv + ((long)(b*512))*3072 + 1024 + h*64;
  const u16* vbase = vt + (long)z*64*512;

  auto stage_kv = [&](int kv, int buf){
    char* Kd = (char*)(sm + 8192  + buf*4096);
    char* Vd = (char*)(sm + 16384 + buf*4096);
    #pragma unroll
    for (int i=0;i<2;i++){
      int rb = i*32 + wave*8;
      GLL16(kbase + (long)(kv*64 + rb + srow)*3072 + scol, Kd + rb*128);
      GLL16(vbase + (long)(rb + srow)*512 + kv*64 + scol, Vd + rb*128);
    }
  };

  {
    const u16* src = qkv + ((long)(b*512 + q0))*3072 + h*64;
    #pragma unroll
    for (int i=0;i<4;i++){
      int rb = i*32 + wave*8;
      GLL16(src + (long)(rb + srow)*3072 + scol, (char*)Qs + rb*128);
    }
  }
  stage_kv(0, 0);
  __syncthreads();

  auto ld_swz = [&](const u16* t, int row, int koff8) -> short8 {
    return *(const short8*)((const char*)t + row*128 + ((koff8 ^ (row&7))<<4));
  };

  short8 af[2][2];
  #pragma unroll
  for (int mi=0;mi<2;mi++)
    #pragma unroll
    for (int ks=0;ks<2;ks++)
      af[mi][ks] = ld_swz(Qs, wave*32 + mi*16 + c, ks*4 + kg);

  floatx4 o_acc[2][4];
  float m_run[2][4], l_run[2][4];
  #pragma unroll
  for (int mi=0;mi<2;mi++){
    #pragma unroll
    for (int dj=0;dj<4;dj++) o_acc[mi][dj] = (floatx4){0.f,0.f,0.f,0.f};
    #pragma unroll
    for (int r=0;r<4;r++){ m_run[mi][r] = -3.0e38f; l_run[mi][r] = 0.f; }
  }

  int cur = 0;
  for (int kv=0; kv<8; ++kv){
    if (kv+1 < 8) stage_kv(kv+1, cur^1);   // prefetch next K/V
    const u16* Ks = sm + 8192  + cur*4096;
    const u16* Vs = sm + 16384 + cur*4096;

    floatx4 s_acc[2][4];
    #pragma unroll
    for (int mi=0;mi<2;mi++)
      #pragma unroll
      for (int ni=0;ni<4;ni++)
        s_acc[mi][ni] = (floatx4){0.f,0.f,0.f,0.f};
    #pragma unroll
    for (int ks=0;ks<2;ks++){
      short8 bf[4];
      #pragma unroll
      for (int ni=0;ni<4;ni++)
        bf[ni] = ld_swz(Ks, ni*16 + c, ks*4 + kg);
      #pragma unroll
      for (int mi=0;mi<2;mi++)
        #pragma unroll
        for (int ni=0;ni<4;ni++)
          s_acc[mi][ni] = __builtin_amdgcn_mfma_f32_16x16x32_bf16(af[mi][ks], bf[ni], s_acc[mi][ni], 0, 0, 0);
    }

    float mv[4];
    #pragma unroll
    for (int ni=0;ni<4;ni++) mv[ni] = mask[b*512 + kv*64 + ni*16 + c];

    #pragma unroll
    for (int mi=0;mi<2;mi++){
      #pragma unroll
      for (int r=0;r<4;r++){
        float s0 = s_acc[mi][0][r]*0.125f + mv[0];
        float s1 = s_acc[mi][1][r]*0.125f + mv[1];
        float s2 = s_acc[mi][2][r]*0.125f + mv[2];
        float s3 = s_acc[mi][3][r]*0.125f + mv[3];
        float tmax = fmaxf(fmaxf(s0,s1), fmaxf(s2,s3));
        #pragma unroll
        for (int o=1;o<16;o<<=1) tmax = fmaxf(tmax, __shfl_xor(tmax, o));
        const float mnew = fmaxf(m_run[mi][r], tmax);
        const float p0 = __expf(s0 - mnew), p1 = __expf(s1 - mnew);
        const float p2 = __expf(s2 - mnew), p3 = __expf(s3 - mnew);
        float psum = p0+p1+p2+p3;
        #pragma unroll
        for (int o=1;o<16;o<<=1) psum += __shfl_xor(psum, o);
        const float alpha = __expf(m_run[mi][r] - mnew);
        l_run[mi][r] = l_run[mi][r]*alpha + psum;
        m_run[mi][r] = mnew;
        #pragma unroll
        for (int dj=0;dj<4;dj++) o_acc[mi][dj][r] *= alpha;
        const int rl = mi*16 + kg*4 + r;
        u16* pw = Ps + wave*2304 + rl*72;
        pw[c]      = f2bs(p0);
        pw[16 + c] = f2bs(p1);
        pw[32 + c] = f2bs(p2);
        pw[48 + c] = f2bs(p3);
      }
    }
    __syncthreads();  // P visible; next-tile stage drained (overlapped w/ QK^T+softmax)

    #pragma unroll
    for (int ks=0;ks<2;ks++){
      short8 pa[2], vb[4];
      #pragma unroll
      for (int mi=0;mi<2;mi++)
        pa[mi] = *(const short8*)&Ps[wave*2304 + (mi*16 + c)*72 + ks*32 + kg*8];
      #pragma unroll
      for (int dj=0;dj<4;dj++)
        vb[dj] = ld_swz(Vs, dj*16 + c, ks*4 + kg);
      #pragma unroll
      for (int mi=0;mi<2;mi++)
        #pragma unroll
        for (int dj=0;dj<4;dj++)
          o_acc[mi][dj] = __builtin_amdgcn_mfma_f32_16x16x32_bf16(pa[mi], vb[dj], o_acc[mi][dj], 0, 0, 0);
    }
    __syncthreads();  // all reads of cur buffers done before next overwrite
    cur ^= 1;
  }

  #pragma unroll
  for (int mi=0;mi<2;mi++){
    #pragma unroll
    for (int r=0;r<4;r++){
      const float inv = 1.f / l_run[mi][r];
      const int s_g = q0 + wave*32 + mi*16 + kg*4 + r;
      u16* dst = attn_o + (long)(b*512 + s_g)*1024 + h*64;
      #pragma unroll
      for (int dj=0;dj<4;dj++)
        dst[dj*16 + c] = f2bs(o_acc[mi][dj][r]*inv);
    }
  }
}

// ---- bulk fp32 -> bf16 conversion, float4 wide ----
__global__ __launch_bounds__(256) void convert_bulk(
  const float* __restrict__ x,
  const float* __restrict__ wq, const float* __restrict__ wk, const float* __restrict__ wv,
  const float* __restrict__ wo, const float* __restrict__ wup, const float* __restrict__ wdn,
  u16* __restrict__ xb, u16* __restrict__ wqkv, u16* __restrict__ wob,
  u16* __restrict__ wupb, u16* __restrict__ wdnb)
{
  const long NX = 4194304, NWt = 1048576;
  const long T4 = (NX + 3*NWt + NWt + NX + NX) >> 2;
  for (long i4 = (long)blockIdx.x*256 + threadIdx.x; i4 < T4; i4 += (long)gridDim.x*256){
    long j = i4 << 2;
    const float* src; u16* dst; long soff, doff;
    if (j < NX){ src=x; dst=xb; soff=j; doff=j; }
    else { j -= NX;
      if (j < 3*NWt){ int p=(int)(j>>20); src = p==0?wq:(p==1?wk:wv); dst=wqkv; soff = j & (NWt-1); doff = j; }
      else { j -= 3*NWt;
        if (j < NWt){ src=wo; dst=wob; soff=j; doff=j; }
        else { j -= NWt;
          if (j < NX){ src=wup; dst=wupb; soff=j; doff=j; }
          else { j -= NX; src=wdn; dst=wdnb; soff=j; doff=j; }
        }
      }
    }
    const float4 v = *(const float4*)(src + soff);
    ushort4 o;
    o.x = f2bs(v.x); o.y = f2bs(v.y); o.z = f2bs(v.z); o.w = f2bs(v.w);
    *(ushort4*)(dst + doff) = o;
  }
}

// ---- small conversions: bias concat, lb^T tiles, la^T tiles ----
__global__ __launch_bounds__(256) void convert_small(
  const float* __restrict__ bq, const float* __restrict__ bk, const float* __restrict__ bv,
  const float* __restrict__ lbq, const float* __restrict__ lbk, const float* __restrict__ lbv,
  const float* __restrict__ lbo, const float* __restrict__ lbup, const float* __restrict__ lbdn,
  const float* __restrict__ laq, const float* __restrict__ lak, const float* __restrict__ lav,
  const float* __restrict__ lao, const float* __restrict__ laup, const float* __restrict__ ladn,
  float* __restrict__ biascat, u16* __restrict__ lbtqkv, u16* __restrict__ lbto,
  u16* __restrict__ lbtup, u16* __restrict__ lbtdn,
  u16* __restrict__ latqkv, u16* __restrict__ lato,
  u16* __restrict__ latup, u16* __restrict__ latdn)
{
  long i = (long)blockIdx.x*256 + threadIdx.x;
  if (i < 3072){ int p=(int)(i>>10); biascat[i] = (p==0?bq:(p==1?bk:bv))[i&1023]; return; }
  i -= 3072;
  if (i < 49152){ int k=(int)(i/3072), n=(int)(i%3072); int p=n>>10;
    const float* l = p==0?lbq:(p==1?lbk:lbv);
    lbtqkv[n*32+k] = f2bs(l[k*1024 + (n&1023)]); lbtqkv[n*32+16+k] = 0; return; }
  i -= 49152;
  if (i < 16384){ int k=(int)(i>>10), n=(int)(i&1023);
    lbto[n*32+k] = f2bs(lbo[k*1024+n]); lbto[n*32+16+k] = 0; return; }
  i -= 16384;
  if (i < 65536){ int k=(int)(i>>12), n=(int)(i&4095);
    lbtup[n*32+k] = f2bs(lbup[k*4096+n]); lbtup[n*32+16+k] = 0; return; }
  i -= 65536;
  if (i < 16384){ int k=(int)(i>>10), n=(int)(i&1023);
    lbtdn[n*32+k] = f2bs(lbdn[k*1024+n]); lbtdn[n*32+16+k] = 0; return; }
  i -= 16384;
  if (i < 49152){ int r=(int)(i>>10), k=(int)(i&1023);
    const float* l = r<16 ? laq : (r<32 ? lak : lav);
    latqkv[i] = f2bs(l[k*16 + (r&15)]); return; }
  i -= 49152;
  if (i < 16384){ int r=(int)(i>>10), k=(int)(i&1023);
    lato[i] = f2bs(lao[k*16+r]); return; }
  i -= 16384;
  if (i < 16384){ int r=(int)(i>>10), k=(int)(i&1023);
    latup[i] = f2bs(laup[k*16+r]); return; }
  i -= 16384;
  if (i < 65536){ int r=(int)(i>>12), k=(int)(i&4095);
    latdn[i] = f2bs(ladn[k*16+r]); }
}

// ---- V transpose ----
__global__ __launch_bounds__(256) void transpose_v(const u16* __restrict__ qkv, u16* __restrict__ vt){
  const int st = blockIdx.x;     // s tile (0..7)
  const int z = blockIdx.y;      // b*16+h
  const int b = z >> 4, h = z & 15;
  __shared__ u16 tile[64][68];
  const int t = threadIdx.x;
  const int q16 = t & 15, g16 = t >> 4;
  const u16* src = qkv + ((long)(b*512 + st*64))*3072 + 2048 + h*64;
  #pragma unroll
  for (int i=0;i<4;i++){
    int s_l = i*16 + g16;
    const u16* pp = src + (long)s_l*3072 + q16*4;
    #pragma unroll
    for (int jj=0;jj<4;jj++) tile[s_l][q16*4+jj] = pp[jj];
  }
  __syncthreads();
  u16* dst = vt + (long)z*64*512 + st*64;
  #pragma unroll
  for (int i=0;i<4;i++){
    int d_l = i*16 + g16;
    int s_l = q16*4;
    unsigned long long v = (unsigned long long)tile[s_l][d_l]
      | ((unsigned long long)tile[s_l+1][d_l] << 16)
      | ((unsigned long long)tile[s_l+2][d_l] << 32)
      | ((unsigned long long)tile[s_l+3][d_l] << 48);
    *(unsigned long long*)(dst + (long)d_l*512 + s_l) = v;
  }
}

// ---- LayerNorm over rows of 1024 fp32; optional fp32 + bf16 outputs ----
__global__ __launch_bounds__(256) void ln_k(
    const float* __restrict__ in, float* __restrict__ outf, u16* __restrict__ outb,
    const float* __restrict__ gam, const float* __restrict__ bet)
{
  const long row = blockIdx.x;
  const float4 v = ((const float4*)(in + row*1024))[threadIdx.x];
  float s = v.x+v.y+v.z+v.w;
  float q = v.x*v.x + v.y*v.y + v.z*v.z + v.w*v.w;
  const int lane = threadIdx.x & 63, w = threadIdx.x >> 6;
  __shared__ float rs[4], rq[4];
  #pragma unroll
  for (int o=32;o;o>>=1){ s += __shfl_down(s,o); q += __shfl_down(q,o); }
  if (!lane){ rs[w]=s; rq[w]=q; }
  __syncthreads();
  const float S = rs[0]+rs[1]+rs[2]+rs[3];
  const float Q = rq[0]+rq[1]+rq[2]+rq[3];
  const float mu = S*(1.f/1024.f);
  const float var = Q*(1.f/1024.f) - mu*mu;
  const float rstd = rsqrtf(var + 1e-5f);
  const float4 g = ((const float4*)gam)[threadIdx.x];
  const float4 b = ((const float4*)bet)[threadIdx.x];
  float4 o;
  o.x = (v.x-mu)*rstd*g.x + b.x;
  o.y = (v.y-mu)*rstd*g.y + b.y;
  o.z = (v.z-mu)*rstd*g.z + b.z;
  o.w = (v.w-mu)*rstd*g.w + b.w;
  if (outf) ((float4*)(outf + row*1024))[threadIdx.x] = o;
  if (outb){
    uint2 u;
    u.x = (unsigned)f2bs(o.x) | ((unsigned)f2bs(o.y) << 16);
    u.y = (unsigned)f2bs(o.z) | ((unsigned)f2bs(o.w) << 16);
    ((uint2*)(outb + row*1024))[threadIdx.x] = u;
  }
}

extern "C" void kernel_launch(void* const* d_in, const int* in_sizes, int n_in,
                              void* d_out, int out_size, void* d_ws, size_t ws_size,
                              hipStream_t stream) {
  const float* x      = (const float*)d_in[0];
  const float* mask   = (const float*)d_in[1];
  const float* w_q    = (const float*)d_in[2];
  const float* b_q    = (const float*)d_in[3];
  const float* la_q   = (const float*)d_in[4];
  const float* lb_q   = (const float*)d_in[5];
  const float* w_k    = (const float*)d_in[6];
  const float* b_k    = (const float*)d_in[7];
  const float* la_k   = (const float*)d_in[8];
  const float* lb_k   = (const float*)d_in[9];
  const float* w_v    = (const float*)d_in[10];
  const float* b_v    = (const float*)d_in[11];
  const float* la_v   = (const float*)d_in[12];
  const float* lb_v   = (const float*)d_in[13];
  const float* w_o    = (const float*)d_in[14];
  const float* b_o    = (const float*)d_in[15];
  const float* la_o   = (const float*)d_in[16];
  const float* lb_o   = (const float*)d_in[17];
  const float* nw1    = (const float*)d_in[18];
  const float* nb1    = (const float*)d_in[19];
  const float* w_up   = (const float*)d_in[20];
  const float* b_up   = (const float*)d_in[21];
  const float* la_up  = (const float*)d_in[22];
  const float* lb_up  = (const float*)d_in[23];
  const float* w_dn   = (const float*)d_in[24];
  const float* b_dn   = (const float*)d_in[25];
  const float* la_dn  = (const float*)d_in[26];
  const float* lb_dn  = (const float*)d_in[27];
  const float* nw2    = (const float*)d_in[28];
  const float* nb2    = (const float*)d_in[29];
  float* out = (float*)d_out;

  char* ws = (char*)d_ws;
  size_t used = 0;
  auto alloc = [&](size_t bytes) -> char* {
    char* p = ws + used;
    used += (bytes + 255) & ~(size_t)255;
    return p;
  };
  u16*   xb      = (u16*)  alloc(4194304*2);
  u16*   wqkv    = (u16*)  alloc(3145728*2);
  u16*   wob     = (u16*)  alloc(1048576*2);
  u16*   wupb    = (u16*)  alloc(4194304*2);
  u16*   wdnb    = (u16*)  alloc(4194304*2);
  float* biascat = (float*)alloc(3072*4);
  u16*   lbtqkv  = (u16*)  alloc(3072*32*2);
  u16*   lbto    = (u16*)  alloc(1024*32*2);
  u16*   lbtup   = (u16*)  alloc(4096*32*2);
  u16*   lbtdn   = (u16*)  alloc(1024*32*2);
  u16*   latqkv  = (u16*)  alloc(48*1024*2);
  u16*   lato    = (u16*)  alloc(16*1024*2);
  u16*   latup   = (u16*)  alloc(16*1024*2);
  u16*   latdn   = (u16*)  alloc(16*4096*2);
  u16*   t_all   = (u16*)  alloc(4096*96*2);
  u16*   t_o     = (u16*)  alloc(4096*32*2);
  u16*   t_up    = (u16*)  alloc(4096*32*2);
  u16*   t_dn    = (u16*)  alloc(4096*32*2);
  u16*   qkv     = (u16*)  alloc((size_t)4096*3072*2);
  u16*   vt      = (u16*)  alloc((size_t)128*64*512*2);
  u16*   attn_o  = (u16*)  alloc(4194304*2);
  float* o_final = (float*)alloc((size_t)4194304*4);
  float* x_med   = (float*)alloc((size_t)4194304*4);
  u16*   x_med_b = (u16*)  alloc(4194304*2);
  u16*   fn      = (u16*)  alloc((size_t)4096*4096*2);
  if (used > ws_size) return;  // workspace too small -> clean validation failure

  // 1. convert
  convert_bulk<<<2048, 256, 0, stream>>>(x, w_q, w_k, w_v, w_o, w_up, w_dn,
                                         xb, wqkv, wob, wupb, wdnb);
  convert_small<<<1164, 256, 0, stream>>>(b_q, b_k, b_v, lb_q, lb_k, lb_v,
                                          lb_o, lb_up, lb_dn,
                                          la_q, la_k, la_v, la_o, la_up, la_dn,
                                          biascat, lbtqkv, lbto, lbtup, lbtdn,
                                          latqkv, lato, latup, latdn);
  // 2. LoRA stage-1 q,k,v fused (A = xb bf16, shared A-read)
  lora_mfma<3><<<256, 64, 0, stream>>>(xb, 1024, latqkv, t_all, 96);
  // 3. fused QKV GEMM -> qkv [4096, 3072] bf16
  gemm_bt<128,128,64,64,EP_BF16,true,true><<<dim3(24,32,1), 256, 0, stream>>>(
      xb, 1024, wqkv, 1024, 1024, qkv, nullptr, 3072,
      biascat, t_all, 96, lbtqkv, nullptr);
  // 4. V transpose -> vt [128][64][512]
  transpose_v<<<dim3(8,128), 256, 0, stream>>>(qkv, vt);
  // 5. fused flash attention -> attn_o bf16 [4096][1024]
  flash_attn<<<dim3(4,128), 256, 0, stream>>>(qkv, vt, mask, attn_o);
  // 6. LoRA stage-1 for O
  lora_mfma<1><<<256, 64, 0, stream>>>(attn_o, 1024, lato, t_o, 32);
  // 7. O projection + bias + lora + residual(x) -> o_final fp32
  gemm_bt<64,128,32,64,EP_F32RES,true,true><<<dim3(8,64,1), 256, 0, stream>>>(
      attn_o, 1024, wob, 1024, 1024, nullptr, o_final, 1024,
      b_o, t_o, 32, lbto, x);
  // 8. LN1 -> x_med fp32 + bf16
  ln_k<<<4096, 256, 0, stream>>>(o_final, x_med, x_med_b, nw1, nb1);
  // 9. LoRA stage-1 for up (A = x_med_b bf16)
  lora_mfma<1><<<256, 64, 0, stream>>>(x_med_b, 1024, latup, t_up, 32);
  // 10. up GEMM + bias + lora + GELU -> fn bf16 [4096,4096]
  gemm_bt<128,128,64,64,EP_GELU,true,true><<<dim3(32,32,1), 256, 0, stream>>>(
      x_med_b, 1024, wupb, 1024, 1024, fn, nullptr, 4096,
      b_up, t_up, 32, lbtup, nullptr);
  // 11. LoRA stage-1 for down (A = fn bf16, K=4096)
  lora_mfma<1><<<256, 64, 0, stream>>>(fn, 4096, latdn, t_dn, 32);
  // 12. down GEMM + bias + lora + residual(x_med) -> d_out fp32
  gemm_bt<64,128,32,64,EP_F32RES,true,true><<<dim3(8,64,1), 256, 0, stream>>>(
      fn, 4096, wdnb, 4096, 4096, nullptr, out, 1024,
      b_dn, t_dn, 32, lbtdn, x_med);
  // 13. LN2 in place on d_out
  ln_k<<<4096, 256, 0, stream>>>(out, out, nullptr, nw2, nb2);
}

// Round 9
// 275.335 us; speedup vs baseline: 4.3193x; 1.0830x over previous
//
#include <hip/hip_runtime.h>
#include <math.h>

typedef unsigned short u16;
typedef __attribute__((ext_vector_type(8))) short short8;
typedef __attribute__((ext_vector_type(4))) float floatx4;

#define DEV __device__ __forceinline__

DEV u16 f2bs(float f){ union{float f; unsigned u;} v; v.f=f; unsigned r = v.u + 0x7fffu + ((v.u>>16)&1u); return (u16)(r>>16); }
DEV float bs2f(u16 u){ union{float f; unsigned u;} v; v.u = ((unsigned)u)<<16; return v.f; }

// tanh-form GELU (max |delta| vs exact-erf gelu ~3e-4; bf16-safe).
DEV float gelu_f(float x){
  float u2 = 2.f * x * (0.7978845608028654f + 0.03567740813636141f*x*x);
  float e = __expf(u2);
  float th = 1.f - 2.f/(e + 1.f);
  return 0.5f*x*(1.f + th);
}

#define GLL16(G,L) __builtin_amdgcn_global_load_lds((__attribute__((address_space(1))) const void*)(G), (__attribute__((address_space(3))) void*)(L), 16, 0, 0)

enum { EP_BF16=0, EP_F32RES=3, EP_GELU=4 };

// XCD-chunked bijective block swizzle (m204) + group-major (G rows) ordering.
DEV void swizzle_bid(int orig, int gx, int gy, int& bx, int& by){
  const int nwg = gx*gy;
  const int q = nwg >> 3, r = nwg & 7;
  const int xcd = orig & 7, idx = orig >> 3;
  const int logical = (xcd < r) ? xcd*(q+1) + idx : r*(q+1) + (xcd-r)*q + idx;
  const int G = 8;
  const int per = G*gx;
  const int gid = logical / per;
  const int rem = logical - gid*per;
  const int by0 = gid*G;
  const int rows = min(G, gy - by0);
  by = by0 + rem % rows;
  bx = rem / rows;
}

// C[m][n] = sum_k A[m][k]*B[n][k]  (B^T layout), bf16 in, fp32 acc.
// BK=64: LDS tiles [rows][64] (128B rows, 8x16B chunks), XOR swizzle
// chunk^=(row&7) -> 2 lanes/bank on fragment reads (free, m136).
// Depth-2 dbuf + counted vmcnt: next tile's loads stay in flight across
// the barrier; 2 MFMA k-substeps (32 k) per iteration halve barrier count.
// LoRA rank-16 rides as one extra zero-padded 64-wide K-tile.
template<int BM,int BN,int WM,int WN,int MODE,bool LORA,bool SWZ>
__global__ __launch_bounds__(256) void gemm_bt(
    const u16* __restrict__ A, int lda,
    const u16* __restrict__ B, int ldb,
    int K,
    u16* __restrict__ obf, float* __restrict__ of32, int ldc,
    const float* __restrict__ bias,
    const u16* __restrict__ tA, int tlda,   // [M][tlda], 64-wide slices, cols 16..63 zero
    const u16* __restrict__ lbB,            // [N][64], cols 16..63 zero
    const float* __restrict__ resid)
{
  constexpr int NWM = BM/WM, NWN = BN/WN, NW = NWM*NWN;
  constexpr int FM = WM/16, FN = WN/16;
  constexpr int TILE = (BM+BN)*64;           // u16 elements per buffer
  constexpr int LPT = (BM+BN)/(8*NW);        // GLL16 per wave per tile
  static_assert(NW*64 == 256, "block must be 256 threads");
  static_assert((BM/8)%NW==0 && (BN/8)%NW==0, "row-group striping");
  __shared__ u16 ab[2*TILE];

  const int tid = threadIdx.x;
  const int lane = tid & 63, wave = tid >> 6;
  const int wr = wave / NWN, wc = wave % NWN;
  const int row16 = lane & 15, kgrp = lane >> 4;
  int bx = blockIdx.x, by = blockIdx.y;
  if constexpr (SWZ)
    swizzle_bid(blockIdx.y*gridDim.x + blockIdx.x, gridDim.x, gridDim.y, bx, by);
  const int bm0 = by * BM, bn0 = bx * BN;

  const u16* Ab = A + (long)bm0*lda;
  const u16* Bb = B + (long)bn0*ldb;
  const int tsel = (LORA && tlda==192) ? ((bn0>>10)*64) : 0;
  // staging: lane covers (row = g*8 + (lane>>3), chunk = lane&7); source
  // chunk pre-swizzled by ^row&7 so LDS is linear but logically swizzled.
  const int srow = lane >> 3;
  const int gcol = ((lane&7) ^ srow) * 8;

  const int nKT = K >> 6;
  const int nIT = nKT + (LORA ? 1 : 0);

  auto stage = [&](int kt, int buf){
    const u16 *Ak, *Bk; long la_, lb_;
    if (!LORA || kt < nKT){ Ak = Ab + kt*64; la_ = lda; Bk = Bb + kt*64; lb_ = ldb; }
    else { Ak = tA + (long)bm0*tlda + tsel; la_ = tlda; Bk = lbB + (long)bn0*64; lb_ = 64; }
    char* l = (char*)(ab + buf*TILE);
    #pragma unroll
    for (int g0=0; g0<BM/8; g0+=NW){
      int g = g0 + wave;
      GLL16(Ak + (long)(g*8 + srow)*la_ + gcol, l + g*1024);
    }
    #pragma unroll
    for (int g0=0; g0<BN/8; g0+=NW){
      int g = g0 + wave;
      GLL16(Bk + (long)(g*8 + srow)*lb_ + gcol, l + BM*128 + g*1024);
    }
  };

  floatx4 acc[FM][FN];
  #pragma unroll
  for (int i=0;i<FM;i++)
    #pragma unroll
    for (int j=0;j<FN;j++)
      acc[i][j] = (floatx4){0.f,0.f,0.f,0.f};

  stage(0, 0);
  if (nIT > 1) stage(1, 1);
  int cur = 0;
  for (int kt=0; kt<nIT; ++kt){
    if (kt+1 < nIT) asm volatile("s_waitcnt vmcnt(%0)" :: "n"(LPT) : "memory");
    else            asm volatile("s_waitcnt vmcnt(0)" ::: "memory");
    __builtin_amdgcn_s_barrier();

    const char* lds = (const char*)(ab + cur*TILE);
    #pragma unroll
    for (int ks=0; ks<2; ++ks){
      short8 af[FM], bfr[FN];
      #pragma unroll
      for (int mi=0;mi<FM;mi++){
        int r_ = wr*WM + mi*16 + row16;
        af[mi] = *(const short8*)(lds + r_*128 + (((ks*4 + kgrp) ^ (r_&7))<<4));
      }
      #pragma unroll
      for (int ni=0;ni<FN;ni++){
        int r_ = wc*WN + ni*16 + row16;
        bfr[ni] = *(const short8*)(lds + BM*128 + r_*128 + (((ks*4 + kgrp) ^ (r_&7))<<4));
      }
      #pragma unroll
      for (int mi=0;mi<FM;mi++)
        #pragma unroll
        for (int ni=0;ni<FN;ni++)
          acc[mi][ni] = __builtin_amdgcn_mfma_f32_16x16x32_bf16(af[mi], bfr[ni], acc[mi][ni], 0, 0, 0);
    }

    asm volatile("s_waitcnt lgkmcnt(0)" ::: "memory");
    __builtin_amdgcn_sched_barrier(0);
    __builtin_amdgcn_s_barrier();        // all waves done reading buf[cur]
    if (kt+2 < nIT) stage(kt+2, cur);    // refill freed buffer
    cur ^= 1;
  }

  #pragma unroll
  for (int mi=0;mi<FM;mi++){
    #pragma unroll
    for (int r=0;r<4;r++){
      const int ml = wr*WM + mi*16 + kgrp*4 + r;
      const long mg = bm0 + ml;
      #pragma unroll
      for (int ni=0;ni<FN;ni++){
        const int nl = wc*WN + ni*16 + row16;
        const int ng = bn0 + nl;
        float v = acc[mi][ni][r] + bias[ng];
        if constexpr (MODE==EP_F32RES){
          v += resid[mg*ldc + ng];
          of32[mg*ldc + ng] = v;
        } else if constexpr (MODE==EP_GELU){
          obf[mg*ldc + ng] = f2bs(gelu_f(v));
        } else {
          obf[mg*ldc + ng] = f2bs(v);
        }
      }
    }
  }
}

// ---- LoRA stage-1 via MFMA: t[m][r] = sum_k A[m][k]*la[k][r] ----
// Output t: [M][tld], per-target 64-wide slice, cols 16..63 zeroed.
template<int NT>
__global__ __launch_bounds__(64) void lora_mfma(
    const u16* __restrict__ A, const int K,
    const u16* __restrict__ lat,
    u16* __restrict__ t, int tld)
{
  const int lane = threadIdx.x & 63;
  const int c = lane & 15, kg = lane >> 4;
  const int m0 = blockIdx.x * 16;
  const u16* Arow = A + (long)(m0 + c)*K + kg*8;
  const u16* Brow = lat + (long)c*K + kg*8;
  floatx4 acc[NT];
  #pragma unroll
  for (int tj=0;tj<NT;tj++) acc[tj] = (floatx4){0.f,0.f,0.f,0.f};
  const int nKS = K >> 5;
  #pragma unroll 4
  for (int ks=0; ks<nKS; ++ks){
    short8 a = *(const short8*)(Arow + ks*32);
    #pragma unroll
    for (int tj=0; tj<NT; ++tj){
      short8 b = *(const short8*)(Brow + (long)tj*16*K + ks*32);
      acc[tj] = __builtin_amdgcn_mfma_f32_16x16x32_bf16(a, b, acc[tj], 0, 0, 0);
    }
  }
  #pragma unroll
  for (int tj=0; tj<NT; ++tj)
    #pragma unroll
    for (int r=0;r<4;r++){
      u16* dst = t + (long)(m0 + kg*4 + r)*tld + tj*64;
      dst[c] = f2bs(acc[tj][r]);
      dst[16+c] = 0; dst[32+c] = 0; dst[48+c] = 0;
    }
}

// ---- fused flash attention: per (q-tile 128, head) block, 4 waves ----
__global__ __launch_bounds__(256) void flash_attn(
    const u16* __restrict__ qkv,   // [4096][3072]
    const u16* __restrict__ vt,    // [128][64][512]
    const float* __restrict__ mask,// [8][512]
    u16* __restrict__ attn_o)      // [4096][1024]
{
  __shared__ u16 sm[33792]; // Q[128][64] | K dbuf 2x4096 | V dbuf 2x4096 | P 4x[32][72]
  u16* Qs = sm;
  u16* Ps = sm + 24576;

  const int tid = threadIdx.x, lane = tid & 63, wave = tid >> 6;
  const int c = lane & 15, kg = lane >> 4;
  const int qt = blockIdx.x;        // 0..3
  const int z  = blockIdx.y;        // b*16+h
  const int b = z >> 4, h = z & 15;
  const int q0 = qt * 128;
  const int srow = lane >> 3;
  const int scol = ((lane&7) ^ srow) * 8;

  const u16* kbase = qkv + ((long)(b*512))*3072 + 1024 + h*64;
  const u16* vbase = vt + (long)z*64*512;

  auto stage_kv = [&](int kv, int buf){
    char* Kd = (char*)(sm + 8192  + buf*4096);
    char* Vd = (char*)(sm + 16384 + buf*4096);
    #pragma unroll
    for (int i=0;i<2;i++){
      int rb = i*32 + wave*8;
      GLL16(kbase + (long)(kv*64 + rb + srow)*3072 + scol, Kd + rb*128);
      GLL16(vbase + (long)(rb + srow)*512 + kv*64 + scol, Vd + rb*128);
    }
  };

  {
    const u16* src = qkv + ((long)(b*512 + q0))*3072 + h*64;
    #pragma unroll
    for (int i=0;i<4;i++){
      int rb = i*32 + wave*8;
      GLL16(src + (long)(rb + srow)*3072 + scol, (char*)Qs + rb*128);
    }
  }
  stage_kv(0, 0);
  __syncthreads();

  auto ld_swz = [&](const u16* t, int row, int koff8) -> short8 {
    return *(const short8*)((const char*)t + row*128 + ((koff8 ^ (row&7))<<4));
  };

  short8 af[2][2];
  #pragma unroll
  for (int mi=0;mi<2;mi++)
    #pragma unroll
    for (int ks=0;ks<2;ks++)
      af[mi][ks] = ld_swz(Qs, wave*32 + mi*16 + c, ks*4 + kg);

  floatx4 o_acc[2][4];
  float m_run[2][4], l_run[2][4];
  #pragma unroll
  for (int mi=0;mi<2;mi++){
    #pragma unroll
    for (int dj=0;dj<4;dj++) o_acc[mi][dj] = (floatx4){0.f,0.f,0.f,0.f};
    #pragma unroll
    for (int r=0;r<4;r++){ m_run[mi][r] = -3.0e38f; l_run[mi][r] = 0.f; }
  }

  int cur = 0;
  for (int kv=0; kv<8; ++kv){
    if (kv+1 < 8) stage_kv(kv+1, cur^1);   // prefetch next K/V
    const u16* Ks = sm + 8192  + cur*4096;
    const u16* Vs = sm + 16384 + cur*4096;

    floatx4 s_acc[2][4];
    #pragma unroll
    for (int mi=0;mi<2;mi++)
      #pragma unroll
      for (int ni=0;ni<4;ni++)
        s_acc[mi][ni] = (floatx4){0.f,0.f,0.f,0.f};
    #pragma unroll
    for (int ks=0;ks<2;ks++){
      short8 bf[4];
      #pragma unroll
      for (int ni=0;ni<4;ni++)
        bf[ni] = ld_swz(Ks, ni*16 + c, ks*4 + kg);
      #pragma unroll
      for (int mi=0;mi<2;mi++)
        #pragma unroll
        for (int ni=0;ni<4;ni++)
          s_acc[mi][ni] = __builtin_amdgcn_mfma_f32_16x16x32_bf16(af[mi][ks], bf[ni], s_acc[mi][ni], 0, 0, 0);
    }

    float mv[4];
    #pragma unroll
    for (int ni=0;ni<4;ni++) mv[ni] = mask[b*512 + kv*64 + ni*16 + c];

    #pragma unroll
    for (int mi=0;mi<2;mi++){
      #pragma unroll
      for (int r=0;r<4;r++){
        float s0 = s_acc[mi][0][r]*0.125f + mv[0];
        float s1 = s_acc[mi][1][r]*0.125f + mv[1];
        float s2 = s_acc[mi][2][r]*0.125f + mv[2];
        float s3 = s_acc[mi][3][r]*0.125f + mv[3];
        float tmax = fmaxf(fmaxf(s0,s1), fmaxf(s2,s3));
        #pragma unroll
        for (int o=1;o<16;o<<=1) tmax = fmaxf(tmax, __shfl_xor(tmax, o));
        const float mnew = fmaxf(m_run[mi][r], tmax);
        const float p0 = __expf(s0 - mnew), p1 = __expf(s1 - mnew);
        const float p2 = __expf(s2 - mnew), p3 = __expf(s3 - mnew);
        float psum = p0+p1+p2+p3;
        #pragma unroll
        for (int o=1;o<16;o<<=1) psum += __shfl_xor(psum, o);
        const float alpha = __expf(m_run[mi][r] - mnew);
        l_run[mi][r] = l_run[mi][r]*alpha + psum;
        m_run[mi][r] = mnew;
        #pragma unroll
        for (int dj=0;dj<4;dj++) o_acc[mi][dj][r] *= alpha;
        const int rl = mi*16 + kg*4 + r;
        u16* pw = Ps + wave*2304 + rl*72;
        pw[c]      = f2bs(p0);
        pw[16 + c] = f2bs(p1);
        pw[32 + c] = f2bs(p2);
        pw[48 + c] = f2bs(p3);
      }
    }
    __syncthreads();

    #pragma unroll
    for (int ks=0;ks<2;ks++){
      short8 pa[2], vb[4];
      #pragma unroll
      for (int mi=0;mi<2;mi++)
        pa[mi] = *(const short8*)&Ps[wave*2304 + (mi*16 + c)*72 + ks*32 + kg*8];
      #pragma unroll
      for (int dj=0;dj<4;dj++)
        vb[dj] = ld_swz(Vs, dj*16 + c, ks*4 + kg);
      #pragma unroll
      for (int mi=0;mi<2;mi++)
        #pragma unroll
        for (int dj=0;dj<4;dj++)
          o_acc[mi][dj] = __builtin_amdgcn_mfma_f32_16x16x32_bf16(pa[mi], vb[dj], o_acc[mi][dj], 0, 0, 0);
    }
    __syncthreads();
    cur ^= 1;
  }

  #pragma unroll
  for (int mi=0;mi<2;mi++){
    #pragma unroll
    for (int r=0;r<4;r++){
      const float inv = 1.f / l_run[mi][r];
      const int s_g = q0 + wave*32 + mi*16 + kg*4 + r;
      u16* dst = attn_o + (long)(b*512 + s_g)*1024 + h*64;
      #pragma unroll
      for (int dj=0;dj<4;dj++)
        dst[dj*16 + c] = f2bs(o_acc[mi][dj][r]*inv);
    }
  }
}

// ---- bulk fp32 -> bf16 conversion, float4 wide ----
__global__ __launch_bounds__(256) void convert_bulk(
  const float* __restrict__ x,
  const float* __restrict__ wq, const float* __restrict__ wk, const float* __restrict__ wv,
  const float* __restrict__ wo, const float* __restrict__ wup, const float* __restrict__ wdn,
  u16* __restrict__ xb, u16* __restrict__ wqkv, u16* __restrict__ wob,
  u16* __restrict__ wupb, u16* __restrict__ wdnb)
{
  const long NX = 4194304, NWt = 1048576;
  const long T4 = (NX + 3*NWt + NWt + NX + NX) >> 2;
  for (long i4 = (long)blockIdx.x*256 + threadIdx.x; i4 < T4; i4 += (long)gridDim.x*256){
    long j = i4 << 2;
    const float* src; u16* dst; long soff, doff;
    if (j < NX){ src=x; dst=xb; soff=j; doff=j; }
    else { j -= NX;
      if (j < 3*NWt){ int p=(int)(j>>20); src = p==0?wq:(p==1?wk:wv); dst=wqkv; soff = j & (NWt-1); doff = j; }
      else { j -= 3*NWt;
        if (j < NWt){ src=wo; dst=wob; soff=j; doff=j; }
        else { j -= NWt;
          if (j < NX){ src=wup; dst=wupb; soff=j; doff=j; }
          else { j -= NX; src=wdn; dst=wdnb; soff=j; doff=j; }
        }
      }
    }
    const float4 v = *(const float4*)(src + soff);
    ushort4 o;
    o.x = f2bs(v.x); o.y = f2bs(v.y); o.z = f2bs(v.z); o.w = f2bs(v.w);
    *(ushort4*)(dst + doff) = o;
  }
}

// ---- small conversions: bias concat, lb^T tiles ([N][64], cols 16..63 zero), la^T ----
__global__ __launch_bounds__(256) void convert_small(
  const float* __restrict__ bq, const float* __restrict__ bk, const float* __restrict__ bv,
  const float* __restrict__ lbq, const float* __restrict__ lbk, const float* __restrict__ lbv,
  const float* __restrict__ lbo, const float* __restrict__ lbup, const float* __restrict__ lbdn,
  const float* __restrict__ laq, const float* __restrict__ lak, const float* __restrict__ lav,
  const float* __restrict__ lao, const float* __restrict__ laup, const float* __restrict__ ladn,
  float* __restrict__ biascat, u16* __restrict__ lbtqkv, u16* __restrict__ lbto,
  u16* __restrict__ lbtup, u16* __restrict__ lbtdn,
  u16* __restrict__ latqkv, u16* __restrict__ lato,
  u16* __restrict__ latup, u16* __restrict__ latdn)
{
  long i = (long)blockIdx.x*256 + threadIdx.x;
  if (i < 3072){ int p=(int)(i>>10); biascat[i] = (p==0?bq:(p==1?bk:bv))[i&1023]; return; }
  i -= 3072;
  if (i < 49152){ int k=(int)(i/3072), n=(int)(i%3072); int p=n>>10;
    const float* l = p==0?lbq:(p==1?lbk:lbv);
    u16* d = lbtqkv + (long)n*64 + k;
    d[0] = f2bs(l[k*1024 + (n&1023)]); d[16]=0; d[32]=0; d[48]=0; return; }
  i -= 49152;
  if (i < 16384){ int k=(int)(i>>10), n=(int)(i&1023);
    u16* d = lbto + (long)n*64 + k;
    d[0] = f2bs(lbo[k*1024+n]); d[16]=0; d[32]=0; d[48]=0; return; }
  i -= 16384;
  if (i < 65536){ int k=(int)(i>>12), n=(int)(i&4095);
    u16* d = lbtup + (long)n*64 + k;
    d[0] = f2bs(lbup[k*4096+n]); d[16]=0; d[32]=0; d[48]=0; return; }
  i -= 65536;
  if (i < 16384){ int k=(int)(i>>10), n=(int)(i&1023);
    u16* d = lbtdn + (long)n*64 + k;
    d[0] = f2bs(lbdn[k*1024+n]); d[16]=0; d[32]=0; d[48]=0; return; }
  i -= 16384;
  if (i < 49152){ int r=(int)(i>>10), k=(int)(i&1023);
    const float* l = r<16 ? laq : (r<32 ? lak : lav);
    latqkv[i] = f2bs(l[k*16 + (r&15)]); return; }
  i -= 49152;
  if (i < 16384){ int r=(int)(i>>10), k=(int)(i&1023);
    lato[i] = f2bs(lao[k*16+r]); return; }
  i -= 16384;
  if (i < 16384){ int r=(int)(i>>10), k=(int)(i&1023);
    latup[i] = f2bs(laup[k*16+r]); return; }
  i -= 16384;
  if (i < 65536){ int r=(int)(i>>12), k=(int)(i&4095);
    latdn[i] = f2bs(ladn[k*16+r]); }
}

// ---- V transpose ----
__global__ __launch_bounds__(256) void transpose_v(const u16* __restrict__ qkv, u16* __restrict__ vt){
  const int st = blockIdx.x;     // s tile (0..7)
  const int z = blockIdx.y;      // b*16+h
  const int b = z >> 4, h = z & 15;
  __shared__ u16 tile[64][68];
  const int t = threadIdx.x;
  const int q16 = t & 15, g16 = t >> 4;
  const u16* src = qkv + ((long)(b*512 + st*64))*3072 + 2048 + h*64;
  #pragma unroll
  for (int i=0;i<4;i++){
    int s_l = i*16 + g16;
    const u16* pp = src + (long)s_l*3072 + q16*4;
    #pragma unroll
    for (int jj=0;jj<4;jj++) tile[s_l][q16*4+jj] = pp[jj];
  }
  __syncthreads();
  u16* dst = vt + (long)z*64*512 + st*64;
  #pragma unroll
  for (int i=0;i<4;i++){
    int d_l = i*16 + g16;
    int s_l = q16*4;
    unsigned long long v = (unsigned long long)tile[s_l][d_l]
      | ((unsigned long long)tile[s_l+1][d_l] << 16)
      | ((unsigned long long)tile[s_l+2][d_l] << 32)
      | ((unsigned long long)tile[s_l+3][d_l] << 48);
    *(unsigned long long*)(dst + (long)d_l*512 + s_l) = v;
  }
}

// ---- LayerNorm over rows of 1024 fp32; optional fp32 + bf16 outputs ----
__global__ __launch_bounds__(256) void ln_k(
    const float* __restrict__ in, float* __restrict__ outf, u16* __restrict__ outb,
    const float* __restrict__ gam, const float* __restrict__ bet)
{
  const long row = blockIdx.x;
  const float4 v = ((const float4*)(in + row*1024))[threadIdx.x];
  float s = v.x+v.y+v.z+v.w;
  float q = v.x*v.x + v.y*v.y + v.z*v.z + v.w*v.w;
  const int lane = threadIdx.x & 63, w = threadIdx.x >> 6;
  __shared__ float rs[4], rq[4];
  #pragma unroll
  for (int o=32;o;o>>=1){ s += __shfl_down(s,o); q += __shfl_down(q,o); }
  if (!lane){ rs[w]=s; rq[w]=q; }
  __syncthreads();
  const float S = rs[0]+rs[1]+rs[2]+rs[3];
  const float Q = rq[0]+rq[1]+rq[2]+rq[3];
  const float mu = S*(1.f/1024.f);
  const float var = Q*(1.f/1024.f) - mu*mu;
  const float rstd = rsqrtf(var + 1e-5f);
  const float4 g = ((const float4*)gam)[threadIdx.x];
  const float4 b = ((const float4*)bet)[threadIdx.x];
  float4 o;
  o.x = (v.x-mu)*rstd*g.x + b.x;
  o.y = (v.y-mu)*rstd*g.y + b.y;
  o.z = (v.z-mu)*rstd*g.z + b.z;
  o.w = (v.w-mu)*rstd*g.w + b.w;
  if (outf) ((float4*)(outf + row*1024))[threadIdx.x] = o;
  if (outb){
    uint2 u;
    u.x = (unsigned)f2bs(o.x) | ((unsigned)f2bs(o.y) << 16);
    u.y = (unsigned)f2bs(o.z) | ((unsigned)f2bs(o.w) << 16);
    ((uint2*)(outb + row*1024))[threadIdx.x] = u;
  }
}

extern "C" void kernel_launch(void* const* d_in, const int* in_sizes, int n_in,
                              void* d_out, int out_size, void* d_ws, size_t ws_size,
                              hipStream_t stream) {
  const float* x      = (const float*)d_in[0];
  const float* mask   = (const float*)d_in[1];
  const float* w_q    = (const float*)d_in[2];
  const float* b_q    = (const float*)d_in[3];
  const float* la_q   = (const float*)d_in[4];
  const float* lb_q   = (const float*)d_in[5];
  const float* w_k    = (const float*)d_in[6];
  const float* b_k    = (const float*)d_in[7];
  const float* la_k   = (const float*)d_in[8];
  const float* lb_k   = (const float*)d_in[9];
  const float* w_v    = (const float*)d_in[10];
  const float* b_v    = (const float*)d_in[11];
  const float* la_v   = (const float*)d_in[12];
  const float* lb_v   = (const float*)d_in[13];
  const float* w_o    = (const float*)d_in[14];
  const float* b_o    = (const float*)d_in[15];
  const float* la_o   = (const float*)d_in[16];
  const float* lb_o   = (const float*)d_in[17];
  const float* nw1    = (const float*)d_in[18];
  const float* nb1    = (const float*)d_in[19];
  const float* w_up   = (const float*)d_in[20];
  const float* b_up   = (const float*)d_in[21];
  const float* la_up  = (const float*)d_in[22];
  const float* lb_up  = (const float*)d_in[23];
  const float* w_dn   = (const float*)d_in[24];
  const float* b_dn   = (const float*)d_in[25];
  const float* la_dn  = (const float*)d_in[26];
  const float* lb_dn  = (const float*)d_in[27];
  const float* nw2    = (const float*)d_in[28];
  const float* nb2    = (const float*)d_in[29];
  float* out = (float*)d_out;

  char* ws = (char*)d_ws;
  size_t used = 0;
  auto alloc = [&](size_t bytes) -> char* {
    char* p = ws + used;
    used += (bytes + 255) & ~(size_t)255;
    return p;
  };
  u16*   xb      = (u16*)  alloc(4194304*2);
  u16*   wqkv    = (u16*)  alloc(3145728*2);
  u16*   wob     = (u16*)  alloc(1048576*2);
  u16*   wupb    = (u16*)  alloc(4194304*2);
  u16*   wdnb    = (u16*)  alloc(4194304*2);
  float* biascat = (float*)alloc(3072*4);
  u16*   lbtqkv  = (u16*)  alloc((size_t)3072*64*2);
  u16*   lbto    = (u16*)  alloc((size_t)1024*64*2);
  u16*   lbtup   = (u16*)  alloc((size_t)4096*64*2);
  u16*   lbtdn   = (u16*)  alloc((size_t)1024*64*2);
  u16*   latqkv  = (u16*)  alloc(48*1024*2);
  u16*   lato    = (u16*)  alloc(16*1024*2);
  u16*   latup   = (u16*)  alloc(16*1024*2);
  u16*   latdn   = (u16*)  alloc(16*4096*2);
  u16*   t_all   = (u16*)  alloc((size_t)4096*192*2);
  u16*   t_o     = (u16*)  alloc((size_t)4096*64*2);
  u16*   t_up    = (u16*)  alloc((size_t)4096*64*2);
  u16*   t_dn    = (u16*)  alloc((size_t)4096*64*2);
  u16*   qkv     = (u16*)  alloc((size_t)4096*3072*2);
  u16*   vt      = (u16*)  alloc((size_t)128*64*512*2);
  u16*   attn_o  = (u16*)  alloc(4194304*2);
  float* o_final = (float*)alloc((size_t)4194304*4);
  float* x_med   = (float*)alloc((size_t)4194304*4);
  u16*   x_med_b = (u16*)  alloc(4194304*2);
  u16*   fn      = (u16*)  alloc((size_t)4096*4096*2);
  if (used > ws_size) return;  // workspace too small -> clean validation failure

  // 1. convert
  convert_bulk<<<2048, 256, 0, stream>>>(x, w_q, w_k, w_v, w_o, w_up, w_dn,
                                         xb, wqkv, wob, wupb, wdnb);
  convert_small<<<1164, 256, 0, stream>>>(b_q, b_k, b_v, lb_q, lb_k, lb_v,
                                          lb_o, lb_up, lb_dn,
                                          la_q, la_k, la_v, la_o, la_up, la_dn,
                                          biascat, lbtqkv, lbto, lbtup, lbtdn,
                                          latqkv, lato, latup, latdn);
  // 2. LoRA stage-1 q,k,v fused (A = xb bf16, shared A-read)
  lora_mfma<3><<<256, 64, 0, stream>>>(xb, 1024, latqkv, t_all, 192);
  // 3. fused QKV GEMM -> qkv [4096, 3072] bf16
  gemm_bt<128,128,64,64,EP_BF16,true,true><<<dim3(24,32,1), 256, 0, stream>>>(
      xb, 1024, wqkv, 1024, 1024, qkv, nullptr, 3072,
      biascat, t_all, 192, lbtqkv, nullptr);
  // 4. V transpose -> vt [128][64][512]
  transpose_v<<<dim3(8,128), 256, 0, stream>>>(qkv, vt);
  // 5. fused flash attention -> attn_o bf16 [4096][1024]
  flash_attn<<<dim3(4,128), 256, 0, stream>>>(qkv, vt, mask, attn_o);
  // 6. LoRA stage-1 for O
  lora_mfma<1><<<256, 64, 0, stream>>>(attn_o, 1024, lato, t_o, 64);
  // 7. O projection + bias + lora + residual(x) -> o_final fp32
  gemm_bt<64,128,32,64,EP_F32RES,true,true><<<dim3(8,64,1), 256, 0, stream>>>(
      attn_o, 1024, wob, 1024, 1024, nullptr, o_final, 1024,
      b_o, t_o, 64, lbto, x);
  // 8. LN1 -> x_med fp32 + bf16
  ln_k<<<4096, 256, 0, stream>>>(o_final, x_med, x_med_b, nw1, nb1);
  // 9. LoRA stage-1 for up (A = x_med_b bf16)
  lora_mfma<1><<<256, 64, 0, stream>>>(x_med_b, 1024, latup, t_up, 64);
  // 10. up GEMM + bias + lora + GELU -> fn bf16 [4096,4096]
  gemm_bt<128,128,64,64,EP_GELU,true,true><<<dim3(32,32,1), 256, 0, stream>>>(
      x_med_b, 1024, wupb, 1024, 1024, fn, nullptr, 4096,
      b_up, t_up, 64, lbtup, nullptr);
  // 11. LoRA stage-1 for down (A = fn bf16, K=4096)
  lora_mfma<1><<<256, 64, 0, stream>>>(fn, 4096, latdn, t_dn, 64);
  // 12. down GEMM + bias + lora + residual(x_med) -> d_out fp32
  gemm_bt<64,128,32,64,EP_F32RES,true,true><<<dim3(8,64,1), 256, 0, stream>>>(
      fn, 4096, wdnb, 4096, 4096, nullptr, out, 1024,
      b_dn, t_dn, 64, lbtdn, x_med);
  // 13. LN2 in place on d_out
  ln_k<<<4096, 256, 0, stream>>>(out, out, nullptr, nw2, nb2);
}